// Round 14
// baseline (720.517 us; speedup 1.0000x reference)
//
#include <hip/hip_runtime.h>
#include <math.h>

#define BATCH 8
typedef unsigned short US;

typedef __attribute__((ext_vector_type(8))) short short8;
typedef __attribute__((ext_vector_type(4))) float f32x4;

__device__ __forceinline__ US f2b(float f) {
  union { float f; unsigned u; } v; v.f = f;
  unsigned r = v.u + 0x7fffu + ((v.u >> 16) & 1u);
  return (US)(r >> 16);
}
__device__ __forceinline__ float b2f(US h) {
  union { unsigned u; float f; } v; v.u = ((unsigned)h) << 16;
  return v.f;
}

__device__ __forceinline__ void gload16(const US* g, US* l) {
  __builtin_amdgcn_global_load_lds(
      (const __attribute__((address_space(1))) unsigned int*)g,
      (__attribute__((address_space(3))) unsigned int*)l, 16, 0, 0);
}

// LDS tile [rows][64] linear, XOR swizzle: 16B-cell index ^= (row&7).
__device__ __forceinline__ int lidx2(int r, int ko) {
  return r * 64 + ((((ko >> 3) ^ (r & 7)) << 3));
}

// ================= 128^2 1-phase MFMA GEMM (verified r3-r7) ==================
// C = act(A@B + bias). A bf16 phys [M][lda], B bf16 phys [N][K].
// OUT: 0=bf16 [M][N], 1=bf16 [N][M], 2=f32 [M][N], 3=dual bf16 [M][N]+[N][M].
template <int TN, int ACT, int OUT, bool HASBIAS>
__global__ __launch_bounds__(256) void mm_k(
    const US* __restrict__ A, const US* __restrict__ B,
    const float* __restrict__ bias, void* __restrict__ Cv, void* __restrict__ Cv2,
    int M, int N, int K, int lda, long long sA, long long sB, long long sC,
    long long sC2, int gx, int gy) {
  constexpr int JF = TN / 32;
  __shared__ US As[128 * 64];
  __shared__ US Bs[TN * 64];

  const int nb = blockIdx.x;
  const int nb2 = (nb & 7) * (gx * gy) + (nb >> 3);
  const int bx = nb2 % gx;
  const int by = (nb2 / gx) % gy;
  const int b = nb2 / (gx * gy);

  A += (long long)b * sA;
  B += (long long)b * sB;
  const int m0 = by * 128, n0 = bx * TN;
  const int t = threadIdx.x, lane = t & 63, w = t >> 6;
  const int wm = (w >> 1) * 64, wn = (w & 1) * (TN / 2);
  const int l15 = lane & 15, lg = lane >> 4;
  const int lrow = lane >> 3;
  const int gcell = (((lane & 7) ^ lrow) << 3);

  f32x4 acc[4][JF];
#pragma unroll
  for (int i = 0; i < 4; ++i)
#pragma unroll
    for (int j = 0; j < JF; ++j) acc[i][j] = (f32x4){0.f, 0.f, 0.f, 0.f};

  for (int k0 = 0; k0 < K; k0 += 64) {
#pragma unroll
    for (int i = 0; i < 4; ++i) {
      const int g = w * 4 + i;
      gload16(A + (long long)(m0 + g * 8 + lrow) * lda + k0 + gcell, &As[g * 512]);
    }
#pragma unroll
    for (int i = 0; i < TN / 32; ++i) {
      const int g = w * (TN / 32) + i;
      gload16(B + (long long)(n0 + g * 8 + lrow) * K + k0 + gcell, &Bs[g * 512]);
    }
    __syncthreads();

#pragma unroll
    for (int kk = 0; kk < 2; ++kk) {
      const int ko = kk * 32 + lg * 8;
      short8 af[4], bf[JF];
#pragma unroll
      for (int i = 0; i < 4; ++i)
        af[i] = *(const short8*)&As[lidx2(wm + i * 16 + l15, ko)];
#pragma unroll
      for (int j = 0; j < JF; ++j)
        bf[j] = *(const short8*)&Bs[lidx2(wn + j * 16 + l15, ko)];
#pragma unroll
      for (int i = 0; i < 4; ++i)
#pragma unroll
        for (int j = 0; j < JF; ++j)
          acc[i][j] = __builtin_amdgcn_mfma_f32_16x16x32_bf16(af[i], bf[j],
                                                              acc[i][j], 0, 0, 0);
    }
    __syncthreads();
  }

  const long long cb = (long long)b * sC;
  const long long cb2 = (long long)b * sC2;
#pragma unroll
  for (int fj = 0; fj < JF; ++fj) {
    const int col = n0 + wn + fj * 16 + l15;
    const float bsv = HASBIAS ? bias[col] : 0.0f;
#pragma unroll
    for (int fi = 0; fi < 4; ++fi) {
      const int row0 = m0 + wm + fi * 16 + lg * 4;
      float v[4];
#pragma unroll
      for (int e = 0; e < 4; ++e) {
        float x = acc[fi][fj][e] + bsv;
        if (ACT == 1) x = fmaxf(x, 0.0f);
        if (ACT == 2) x = (x > 20.0f) ? x : log1pf(expf(x));
        v[e] = x;
      }
      if (OUT == 1 || OUT == 3) {
        ushort4 pk;
        pk.x = f2b(v[0]); pk.y = f2b(v[1]); pk.z = f2b(v[2]); pk.w = f2b(v[3]);
        US* c2 = (OUT == 3) ? (US*)Cv2 : (US*)Cv;
        *(ushort4*)&c2[cb2 + (long long)col * M + row0] = pk;
      }
      if (OUT == 0 || OUT == 3) {
#pragma unroll
        for (int e = 0; e < 4; ++e)
          ((US*)Cv)[cb + (long long)(row0 + e) * N + col] = f2b(v[e]);
      }
      if (OUT == 2) {
#pragma unroll
        for (int e = 0; e < 4; ++e)
          ((float*)Cv)[cb + (long long)(row0 + e) * N + col] = v[e];
      }
    }
  }
}

// ================= 256^2 deep-pipelined MFMA GEMM (r7-exact) =================
template <int OUT>
__global__ __launch_bounds__(512, 1) void mm256_k(
    const US* __restrict__ A, const US* __restrict__ B, void* __restrict__ Cv,
    void* __restrict__ Cv2, int M, int N, int K, int lda, long long sA,
    long long sB, long long sC, long long sC2, int gx, int gy) {
  __shared__ US lds[8][8192];

  const int nb = blockIdx.x;
  const int chunk = gx * gy;
  const int nb2 = (nb & 7) * chunk + (nb >> 3);
  const int bx = nb2 % gx;
  const int by = (nb2 / gx) % gy;
  const int b = nb2 / chunk;

  const int m0 = by * 256, n0 = bx * 256;
  const int tid = threadIdx.x;
  const int lane = tid & 63, w = tid >> 6;
  const int wr = w >> 2, wc = w & 3;
  const int l15 = lane & 15, lg = lane >> 4;

  const US* Ab = A + (long long)b * sA + (long long)m0 * lda;
  const US* Bb = B + (long long)b * sB + (long long)n0 * K;
  const int NT = K >> 6;

  auto stageH = [&](int H) {
    const int s = H >> 2, h = H & 3;
    const int ab = h & 1, kk = h >> 1;
    US* reg = &lds[ab * 4 + (s & 1) * 2 + kk][0];
    const US* src = ab ? Bb : Ab;
    const int ld = ab ? K : lda;
#pragma unroll
    for (int i = 0; i < 2; ++i) {
      const int rbase = (w * 2 + i) * 16;
      const int r = rbase + (lane >> 2);
      const int csrc = (lane & 3) ^ ((r >> 1) & 3);
      gload16(src + (long long)r * ld + s * 64 + kk * 32 + csrc * 8,
              reg + rbase * 32);
    }
  };

  f32x4 acc[8][4];
#pragma unroll
  for (int m = 0; m < 8; ++m)
#pragma unroll
    for (int j = 0; j < 4; ++j) acc[m][j] = (f32x4){0.f, 0.f, 0.f, 0.f};
  short8 a4[4], b4[4];

  for (int H = 0; H < 6; ++H) stageH(H);
  asm volatile("s_waitcnt vmcnt(4)" ::: "memory");
  __builtin_amdgcn_s_barrier();

#define PH(kk_, mh_, DOH, HV, VM, tt)                                          \
  {                                                                            \
    const US* Ar = &lds[((tt) & 1) * 2 + (kk_)][0];                            \
    const US* Br = &lds[4 + ((tt) & 1) * 2 + (kk_)][0];                        \
    _Pragma("unroll") for (int i = 0; i < 4; ++i) {                            \
      const int r = wr * 128 + (mh_) * 64 + i * 16 + l15;                      \
      a4[i] = *(const short8*)&Ar[r * 32 + ((lg ^ ((r >> 1) & 3)) << 3)];      \
    }                                                                          \
    if ((mh_) == 0) {                                                          \
      _Pragma("unroll") for (int j = 0; j < 4; ++j) {                          \
        const int rr = wc * 64 + j * 16 + l15;                                 \
        b4[j] = *(const short8*)&Br[rr * 32 + ((lg ^ ((rr >> 1) & 3)) << 3)];  \
      }                                                                        \
    }                                                                          \
    if (DOH) stageH(HV);                                                       \
    if ((VM) == 1) asm volatile("s_waitcnt vmcnt(4)" ::: "memory");            \
    if ((VM) == 2) asm volatile("s_waitcnt vmcnt(0)" ::: "memory");            \
    __builtin_amdgcn_s_barrier();                                              \
    __builtin_amdgcn_s_setprio(1);                                             \
    _Pragma("unroll") for (int i = 0; i < 4; ++i)                              \
      _Pragma("unroll") for (int j = 0; j < 4; ++j)                            \
        acc[(mh_) * 4 + i][j] = __builtin_amdgcn_mfma_f32_16x16x32_bf16(       \
            a4[i], b4[j], acc[(mh_) * 4 + i][j], 0, 0, 0);                     \
    __builtin_amdgcn_s_setprio(0);                                             \
    __builtin_amdgcn_s_barrier();                                              \
  }

  int t2 = 0;
  for (; t2 < NT - 2; ++t2) {
    PH(0, 0, true, 4 * t2 + 6, 0, t2)
    PH(0, 1, true, 4 * t2 + 7, 0, t2)
    PH(1, 0, true, 4 * t2 + 8, 0, t2)
    PH(1, 1, true, 4 * t2 + 9, 1, t2)
  }
  PH(0, 0, true, 4 * (NT - 2) + 6, 0, NT - 2)
  PH(0, 1, true, 4 * (NT - 2) + 7, 0, NT - 2)
  PH(1, 0, false, 0, 0, NT - 2)
  PH(1, 1, false, 0, 2, NT - 2)
  PH(0, 0, false, 0, 0, NT - 1)
  PH(0, 1, false, 0, 0, NT - 1)
  PH(1, 0, false, 0, 0, NT - 1)
  PH(1, 1, false, 0, 0, NT - 1)
#undef PH

  const long long cb = (long long)b * sC;
  const long long cb2 = (long long)b * sC2;
#pragma unroll
  for (int j = 0; j < 4; ++j) {
    const int col = n0 + wc * 64 + j * 16 + l15;
#pragma unroll
    for (int m = 0; m < 8; ++m) {
      const int row0 = m0 + wr * 128 + m * 16 + lg * 4;
      if (OUT == 1 || OUT == 3) {
        ushort4 pk;
        pk.x = f2b(acc[m][j][0]); pk.y = f2b(acc[m][j][1]);
        pk.z = f2b(acc[m][j][2]); pk.w = f2b(acc[m][j][3]);
        US* c2 = (OUT == 3) ? (US*)Cv2 : (US*)Cv;
        *(ushort4*)&c2[cb2 + (long long)col * M + row0] = pk;
      }
      if (OUT == 0 || OUT == 3) {
#pragma unroll
        for (int e = 0; e < 4; ++e)
          ((US*)Cv)[cb + (long long)(row0 + e) * N + col] = f2b(acc[m][j][e]);
      }
    }
  }
}

// ================= 64x64 4-deep pipelined MFMA GEMM (skinny N) ===============
template <int ACT, int OUT, bool HASBIAS>
__global__ __launch_bounds__(256) void mm64_k(
    const US* __restrict__ A, const US* __restrict__ B,
    const float* __restrict__ bias, void* __restrict__ Cv,
    int M, int N, int K, int lda, long long sA, long long sB, long long sC,
    int gx, int gy) {
  __shared__ US As[4][4096];
  __shared__ US Bs[4][4096];

  const int nb = blockIdx.x;
  const int chunk = gx * gy;
  const int nb2 = (nb & 7) * chunk + (nb >> 3);
  const int bx = nb2 % gx;
  const int by = (nb2 / gx) % gy;
  const int b = nb2 / chunk;

  const int m0 = by * 64, n0 = bx * 64;
  const int tid = threadIdx.x;
  const int lane = tid & 63, w = tid >> 6;
  const int wr = w >> 1, wc = w & 1;
  const int l15 = lane & 15, lg = lane >> 4;
  const int lrow = lane >> 3;
  const int gcell = (((lane & 7) ^ lrow) << 3);

  const US* Ag = A + (long long)b * sA + (long long)m0 * lda;
  const US* Bg = B + (long long)b * sB + (long long)n0 * K;
  const int NT = K >> 6;

  auto stage = [&](int tt) {
    US* Ad = &As[tt & 3][0];
    US* Bd = &Bs[tt & 3][0];
    const int k0 = tt * 64;
#pragma unroll
    for (int i = 0; i < 2; ++i) {
      const int g = w * 2 + i;
      const int r = g * 8 + lrow;
      gload16(Ag + (long long)r * lda + k0 + gcell, Ad + g * 512);
      gload16(Bg + (long long)r * K + k0 + gcell, Bd + g * 512);
    }
  };

  f32x4 acc[2][2];
#pragma unroll
  for (int i = 0; i < 2; ++i)
#pragma unroll
    for (int j = 0; j < 2; ++j) acc[i][j] = (f32x4){0.f, 0.f, 0.f, 0.f};

  for (int i = 0; i < 3 && i < NT; ++i) stage(i);

  for (int t = 0; t < NT; ++t) {
    if (t + 3 < NT) stage(t + 3);
    const int rem = NT - 1 - t;
    if (rem >= 3) asm volatile("s_waitcnt vmcnt(12)" ::: "memory");
    else if (rem == 2) asm volatile("s_waitcnt vmcnt(8)" ::: "memory");
    else if (rem == 1) asm volatile("s_waitcnt vmcnt(4)" ::: "memory");
    else asm volatile("s_waitcnt vmcnt(0)" ::: "memory");
    asm volatile("s_barrier" ::: "memory");
    const US* Ad = &As[t & 3][0];
    const US* Bd = &Bs[t & 3][0];
#pragma unroll
    for (int kk = 0; kk < 2; ++kk) {
      const int ko = kk * 32 + lg * 8;
      short8 af[2], bf[2];
      af[0] = *(const short8*)&Ad[lidx2(wr * 32 + l15, ko)];
      af[1] = *(const short8*)&Ad[lidx2(wr * 32 + 16 + l15, ko)];
      bf[0] = *(const short8*)&Bd[lidx2(wc * 32 + l15, ko)];
      bf[1] = *(const short8*)&Bd[lidx2(wc * 32 + 16 + l15, ko)];
#pragma unroll
      for (int i = 0; i < 2; ++i)
#pragma unroll
        for (int j = 0; j < 2; ++j)
          acc[i][j] = __builtin_amdgcn_mfma_f32_16x16x32_bf16(af[i], bf[j],
                                                              acc[i][j], 0, 0, 0);
    }
    asm volatile("s_barrier" ::: "memory");
  }

  const long long cb = (long long)b * sC;
#pragma unroll
  for (int fj = 0; fj < 2; ++fj) {
    const int col = n0 + wc * 32 + fj * 16 + l15;
    const float bsv = HASBIAS ? bias[col] : 0.0f;
#pragma unroll
    for (int fi = 0; fi < 2; ++fi) {
      const int row0 = m0 + wr * 32 + fi * 16 + lg * 4;
      float v[4];
#pragma unroll
      for (int e = 0; e < 4; ++e) {
        float x = acc[fi][fj][e] + bsv;
        if (ACT == 1) x = fmaxf(x, 0.0f);
        if (ACT == 2) x = (x > 20.0f) ? x : log1pf(expf(x));
        v[e] = x;
      }
      if (OUT == 1) {
        ushort4 pk;
        pk.x = f2b(v[0]); pk.y = f2b(v[1]); pk.z = f2b(v[2]); pk.w = f2b(v[3]);
        *(ushort4*)&((US*)Cv)[cb + (long long)col * M + row0] = pk;
      } else if (OUT == 0) {
#pragma unroll
        for (int e = 0; e < 4; ++e)
          ((US*)Cv)[cb + (long long)(row0 + e) * N + col] = f2b(v[e]);
      } else {
#pragma unroll
        for (int e = 0; e < 4; ++e)
          ((float*)Cv)[cb + (long long)(row0 + e) * N + col] = v[e];
      }
    }
  }
}

// ================= CSR build (deterministic, no global atomics) ==============
__global__ __launch_bounds__(256) void csr_count_k(const float* __restrict__ adj,
                                                   int* __restrict__ rowcnt) {
  const int row = blockIdx.x, t = threadIdx.x;
  const float* p = adj + (long long)row * 2048;
  int c = 0;
  for (int j = t; j < 2048; j += 256) c += (p[j] != 0.0f);
  __shared__ int red[256];
  red[t] = c;
  __syncthreads();
  for (int s = 128; s; s >>= 1) {
    if (t < s) red[t] += red[t + s];
    __syncthreads();
  }
  if (t == 0) rowcnt[row] = red[0];
}

__global__ __launch_bounds__(256) void csr_scan_k(const int* __restrict__ rowcnt,
                                                  int* __restrict__ rowptr) {
  __shared__ int red[256];
  const int t = threadIdx.x;
  int base = 0;
  for (int ch = 0; ch < 8; ++ch) {
    const int v = rowcnt[ch * 256 + t];
    red[t] = v;
    __syncthreads();
    for (int s = 1; s < 256; s <<= 1) {
      const int add = (t >= s) ? red[t - s] : 0;
      __syncthreads();
      red[t] += add;
      __syncthreads();
    }
    rowptr[ch * 256 + t] = base + red[t] - v;
    const int tot = red[255];
    __syncthreads();
    base += tot;
  }
  if (t == 0) rowptr[2048] = base;
}

__global__ __launch_bounds__(256) void csr_fill_k(const float* __restrict__ adj,
                                                  const int* __restrict__ rowptr,
                                                  int* __restrict__ colidx,
                                                  float* __restrict__ vals) {
  const int row = blockIdx.x, t = threadIdx.x;
  const float* p = adj + (long long)row * 2048;
  int cnt = 0;
  for (int j = t; j < 2048; j += 256) cnt += (p[j] != 0.0f);
  __shared__ int red[256];
  red[t] = cnt;
  __syncthreads();
  for (int s = 1; s < 256; s <<= 1) {
    const int add = (t >= s) ? red[t - s] : 0;
    __syncthreads();
    red[t] += add;
    __syncthreads();
  }
  int off = rowptr[row] + red[t] - cnt;
  for (int j = t; j < 2048; j += 256) {
    const float a = p[j];
    if (a != 0.0f) {
      colidx[off] = j;
      vals[off] = a;
      ++off;
    }
  }
}

// ================= SpMM narrow: Y[b][row][c] = act(sum_j a_rj X[b][j][c]+bias)
template <int COLS, bool INF32, int ACT, bool OUTF32, bool HASBIAS>
__global__ __launch_bounds__(256) void spmm_k(
    const int* __restrict__ rowptr, const int* __restrict__ colidx,
    const float* __restrict__ vals, const void* __restrict__ Xv,
    const float* __restrict__ bias, void* __restrict__ Yv) {
  constexpr int BP = 256 / COLS;
  constexpr int NP = BATCH / BP;
  const int row = blockIdx.x;
  const int t = threadIdx.x;
  const int c = t & (COLS - 1);
  const int bsub = t / COLS;
  const int e0 = rowptr[row], e1 = rowptr[row + 1];
  float acc[NP];
#pragma unroll
  for (int p = 0; p < NP; ++p) acc[p] = 0.0f;
  for (int e = e0; e < e1; ++e) {
    const int j = colidx[e];
    const float a = vals[e];
#pragma unroll
    for (int p = 0; p < NP; ++p) {
      const int b = p * BP + bsub;
      const long long idx = ((long long)b * 2048 + j) * COLS + c;
      const float xv = INF32 ? ((const float*)Xv)[idx] : b2f(((const US*)Xv)[idx]);
      acc[p] += a * xv;
    }
  }
#pragma unroll
  for (int p = 0; p < NP; ++p) {
    const int b = p * BP + bsub;
    float v = acc[p] + (HASBIAS ? bias[c] : 0.0f);
    if (ACT == 2) v = (v > 20.0f) ? v : log1pf(expf(v));
    const long long idx = ((long long)b * 2048 + row) * COLS + c;
    if (OUTF32) ((float*)Yv)[idx] = v;
    else ((US*)Yv)[idx] = f2b(v);
  }
}

// ================= SpMM 256-col, XCD-batch-owned =============================
// Y[b][row][0..256) = sum_j a_rj X[b][j][0..256). Grid 4096: logical
// L=(nb&7)*512+(nb>>3); b=L>>9, rowgrp=L&511; 4 rows/block, lane covers 4 cols.
__global__ __launch_bounds__(256) void spmm256_k(
    const int* __restrict__ rowptr, const int* __restrict__ colidx,
    const float* __restrict__ vals, const US* __restrict__ X,
    US* __restrict__ Y) {
  const int nb = blockIdx.x;
  const int L = (nb & 7) * 512 + (nb >> 3);
  const int b = L >> 9;
  const int rowgrp = L & 511;
  const int tid = threadIdx.x;
  const int r = tid >> 6, lane = tid & 63;
  const int row = rowgrp * 4 + r;
  const int c0 = lane * 4;
  const US* Xb = X + (long long)b * 2048 * 256;
  const int e0 = rowptr[row], e1 = rowptr[row + 1];
  float acc[4] = {0.f, 0.f, 0.f, 0.f};
  for (int e = e0; e < e1; ++e) {
    const int j = colidx[e];
    const float a = vals[e];
    const ushort4 xv = *(const ushort4*)&Xb[(long long)j * 256 + c0];
    acc[0] += a * b2f(xv.x);
    acc[1] += a * b2f(xv.y);
    acc[2] += a * b2f(xv.z);
    acc[3] += a * b2f(xv.w);
  }
  ushort4 o;
  o.x = f2b(acc[0]); o.y = f2b(acc[1]); o.z = f2b(acc[2]); o.w = f2b(acc[3]);
  *(ushort4*)&Y[((long long)b * 2048 + row) * 256 + c0] = o;
}

// ================= SpMM wide (1024 cols), col-chunked, XCD-panel-owned =======
// Y[b][row][0..1024) = sum_j a_rj X[b][j][0..1024); X row stride ldx.
// Grid 16384: L=(nb&7)*2048+(nb>>3); pair=L>>9 (=b*4+chunk), rowgrp=L&511.
// XCD k owns batch k; sequential chunks keep a 1MB panel slice L2-resident.
__global__ __launch_bounds__(256) void spmm1024_k(
    const int* __restrict__ rowptr, const int* __restrict__ colidx,
    const float* __restrict__ vals, const US* __restrict__ X, int ldx,
    long long sX, US* __restrict__ Y) {
  const int nb = blockIdx.x;
  const int L = (nb & 7) * 2048 + (nb >> 3);
  const int pair = L >> 9;
  const int rowgrp = L & 511;
  const int b = pair >> 2;
  const int chunk = pair & 3;
  const int tid = threadIdx.x;
  const int r = tid >> 6, lane = tid & 63;
  const int row = rowgrp * 4 + r;
  const int c0 = chunk * 256 + lane * 4;
  const US* Xb = X + (long long)b * sX;
  const int e0 = rowptr[row], e1 = rowptr[row + 1];
  float acc[4] = {0.f, 0.f, 0.f, 0.f};
  for (int e = e0; e < e1; ++e) {
    const int j = colidx[e];
    const float a = vals[e];
    const ushort4 xv = *(const ushort4*)&Xb[(long long)j * ldx + c0];
    acc[0] += a * b2f(xv.x);
    acc[1] += a * b2f(xv.y);
    acc[2] += a * b2f(xv.z);
    acc[3] += a * b2f(xv.w);
  }
  ushort4 o;
  o.x = f2b(acc[0]); o.y = f2b(acc[1]); o.z = f2b(acc[2]); o.w = f2b(acc[3]);
  *(ushort4*)&Y[((long long)b * 2048 + row) * 1024 + c0] = o;
}

// ================= row softmax over cols [0,1024) of x [B][2048][ldx] ========
__global__ __launch_bounds__(256) void rowsm_k(US* __restrict__ x, int ldx,
                                               long long sB) {
  __shared__ float red[256];
  const int bid = blockIdx.x;
  const int b = bid & 7;
  const int row = bid >> 3;
  const int t = threadIdx.x;
  US* p = x + (long long)b * sB + (long long)row * ldx + t * 4;
  union { ushort4 v; US s[4]; } buf;
  buf.v = *(const ushort4*)p;
  float v[4];
#pragma unroll
  for (int i = 0; i < 4; ++i) v[i] = b2f(buf.s[i]);
  float mx = fmaxf(fmaxf(v[0], v[1]), fmaxf(v[2], v[3]));
  red[t] = mx;
  __syncthreads();
  for (int s = 128; s; s >>= 1) {
    if (t < s) red[t] = fmaxf(red[t], red[t + s]);
    __syncthreads();
  }
  mx = red[0];
  __syncthreads();
  float sum = 0.f;
#pragma unroll
  for (int i = 0; i < 4; ++i) {
    v[i] = __expf(v[i] - mx);
    sum += v[i];
  }
  red[t] = sum;
  __syncthreads();
  for (int s = 128; s; s >>= 1) {
    if (t < s) red[t] += red[t + s];
    __syncthreads();
  }
  const float inv = 1.0f / red[0];
#pragma unroll
  for (int i = 0; i < 4; ++i) buf.s[i] = f2b(v[i] * inv);
  *(ushort4*)p = buf.v;
}

// ---------------- split column softmax over R of x [B][R][C] (stage 2) -------
template <int RPT>
__global__ __launch_bounds__(256) void sm_partial_k(
    const US* __restrict__ x, float* __restrict__ pm, float* __restrict__ ps,
    int R, int C, long long sB, int NS) {
  const int b = blockIdx.y, blk = blockIdx.x;
  const int cpr = C >> 3;
  const int t = threadIdx.x;
  const int cslot = t & (cpr - 1);
  const int rsub = t / cpr;
  const int nsub = 256 / cpr;
  const int rowsPerBlock = R / NS;
  const int r0 = blk * rowsPerBlock + rsub * RPT;
  const US* p = x + (long long)b * sB + (long long)r0 * C + cslot * 8;
  union { uint4 v; US s[8]; } buf[RPT];
#pragma unroll
  for (int i = 0; i < RPT; ++i) buf[i].v = *(const uint4*)(p + (long long)i * C);
  float M[8], S[8];
#pragma unroll
  for (int j = 0; j < 8; ++j) M[j] = b2f(buf[0].s[j]);
#pragma unroll
  for (int i = 1; i < RPT; ++i)
#pragma unroll
    for (int j = 0; j < 8; ++j) M[j] = fmaxf(M[j], b2f(buf[i].s[j]));
#pragma unroll
  for (int j = 0; j < 8; ++j) S[j] = 0.f;
#pragma unroll
  for (int i = 0; i < RPT; ++i)
#pragma unroll
    for (int j = 0; j < 8; ++j) S[j] += __expf(b2f(buf[i].s[j]) - M[j]);
  const long long pi = (long long)(b * NS + blk) * nsub + rsub;
  float* pmo = pm + pi * C + cslot * 8;
  float* pso = ps + pi * C + cslot * 8;
  *(float4*)pmo = make_float4(M[0], M[1], M[2], M[3]);
  *(float4*)(pmo + 4) = make_float4(M[4], M[5], M[6], M[7]);
  *(float4*)pso = make_float4(S[0], S[1], S[2], S[3]);
  *(float4*)(pso + 4) = make_float4(S[4], S[5], S[6], S[7]);
}

__global__ __launch_bounds__(256) void sm_combine_k(
    const float* __restrict__ pm, const float* __restrict__ ps,
    float* __restrict__ Mf, float* __restrict__ Sinv, int C, int NP) {
  const int b = blockIdx.x, t = threadIdx.x;
  const int cpr = C >> 3;
  if (t >= cpr) return;
  const int c = t * 8;
  const float* pmB = pm + (long long)b * NP * C + c;
  const float* psB = ps + (long long)b * NP * C + c;
  float M[8], S[8];
#pragma unroll
  for (int j = 0; j < 8; ++j) { M[j] = pmB[j]; S[j] = psB[j]; }
  for (int e = 1; e < NP; ++e) {
    const float* pme = pmB + (long long)e * C;
    const float* pse = psB + (long long)e * C;
#pragma unroll
    for (int j = 0; j < 8; ++j) {
      const float m2 = pme[j], s2 = pse[j];
      const float nm = fmaxf(M[j], m2);
      S[j] = S[j] * __expf(M[j] - nm) + s2 * __expf(m2 - nm);
      M[j] = nm;
    }
  }
#pragma unroll
  for (int j = 0; j < 8; ++j) {
    Mf[(long long)b * C + c + j] = M[j];
    Sinv[(long long)b * C + c + j] = 1.0f / S[j];
  }
}

template <int RPT>
__global__ __launch_bounds__(256) void sm_norm_k(
    US* __restrict__ x, const float* __restrict__ Mf,
    const float* __restrict__ Sinv, int R, int C, long long sB, int NS) {
  const int b = blockIdx.y, blk = blockIdx.x;
  const int cpr = C >> 3;
  const int t = threadIdx.x;
  const int cslot = t & (cpr - 1);
  const int rsub = t / cpr;
  const int rowsPerBlock = R / NS;
  const int r0 = blk * rowsPerBlock + rsub * RPT;
  US* p = x + (long long)b * sB + (long long)r0 * C + cslot * 8;
  float M[8], Si[8];
#pragma unroll
  for (int j = 0; j < 8; ++j) {
    M[j] = Mf[(long long)b * C + cslot * 8 + j];
    Si[j] = Sinv[(long long)b * C + cslot * 8 + j];
  }
#pragma unroll
  for (int i = 0; i < RPT; ++i) {
    union { uint4 v; US s[8]; } buf;
    buf.v = *(const uint4*)(p + (long long)i * C);
#pragma unroll
    for (int j = 0; j < 8; ++j)
      buf.s[j] = f2b(__expf(b2f(buf.s[j]) - M[j]) * Si[j]);
    *(uint4*)(p + (long long)i * C) = buf.v;
  }
}

// ---------------- bf16 transpose: src [B][R][C] -> dst [B][C][R] -------------
__global__ __launch_bounds__(256) void transb_k(const US* __restrict__ src,
                                                US* __restrict__ dst, int R,
                                                int C, long long sIn,
                                                long long sOut) {
  __shared__ US L[64][65];
  const int b = blockIdx.z;
  const int r0 = blockIdx.y * 64, c0 = blockIdx.x * 64;
  const int t = threadIdx.x;
  const int lr = t >> 4, lc = (t & 15) * 4;
  const US* s = src + (long long)b * sIn;
#pragma unroll
  for (int i = 0; i < 4; ++i) {
    const int rr = r0 + lr + 16 * i;
    const ushort4 v = *(const ushort4*)&s[(long long)rr * C + c0 + lc];
    L[lr + 16 * i][lc + 0] = v.x;
    L[lr + 16 * i][lc + 1] = v.y;
    L[lr + 16 * i][lc + 2] = v.z;
    L[lr + 16 * i][lc + 3] = v.w;
  }
  __syncthreads();
#pragma unroll
  for (int i = 0; i < 4; ++i) {
    ushort4 o;
    o.x = L[lc + 0][lr + 16 * i];
    o.y = L[lc + 1][lr + 16 * i];
    o.z = L[lc + 2][lr + 16 * i];
    o.w = L[lc + 3][lr + 16 * i];
    *(ushort4*)&dst[(long long)b * sOut + (long long)(c0 + lr + 16 * i) * R + r0 + lc] = o;
  }
}

// ---------------- fused weight transposes ----------------
struct WT { const float* src; US* dst; int R, C, tileOff; };
struct WTab { WT e[11]; };

__global__ __launch_bounds__(256) void wtrans_k(WTab tab) {
  __shared__ US L[64][65];
  const int tile = blockIdx.x;
  int i = 0;
#pragma unroll
  for (int j = 1; j < 11; ++j)
    if (tab.e[j].tileOff <= tile) i = j;
  const WT w = tab.e[i];
  const int lt = tile - w.tileOff;
  const int tc = w.C / 64;
  const int r0 = (lt / tc) * 64, c0 = (lt % tc) * 64;
  const int t = threadIdx.x;
  const int lr = t >> 4, lc = (t & 15) * 4;
#pragma unroll
  for (int k = 0; k < 4; ++k) {
    const int rr = r0 + lr + 16 * k;
    const float4 v = *(const float4*)&w.src[(long long)rr * w.C + c0 + lc];
    L[lr + 16 * k][lc + 0] = f2b(v.x);
    L[lr + 16 * k][lc + 1] = f2b(v.y);
    L[lr + 16 * k][lc + 2] = f2b(v.z);
    L[lr + 16 * k][lc + 3] = f2b(v.w);
  }
  __syncthreads();
#pragma unroll
  for (int k = 0; k < 4; ++k) {
    ushort4 o;
    o.x = L[lc + 0][lr + 16 * k];
    o.y = L[lc + 1][lr + 16 * k];
    o.z = L[lc + 2][lr + 16 * k];
    o.w = L[lc + 3][lr + 16 * k];
    *(ushort4*)&w.dst[(long long)(c0 + lr + 16 * k) * w.R + r0 + lc] = o;
  }
}

// ---------------- reparameterize ----------------
__global__ __launch_bounds__(256) void reparam_k(
    const float* __restrict__ h3, const float* __restrict__ eps,
    float* __restrict__ om, float* __restrict__ olv, US* __restrict__ z,
    int total) {
  const int i = blockIdx.x * 256 + threadIdx.x;
  if (i >= total) return;
  const int j = i & 63;
  const long long r = i >> 6;
  const float m = h3[r * 128 + j];
  const float lv = h3[r * 128 + 64 + j];
  om[i] = m;
  olv[i] = lv;
  z[i] = f2b(m + expf(0.5f * lv) * eps[i]);
}

// ---------------- host dispatch ----------------
static void mm(hipStream_t st, const US* A, const US* B, const float* bias,
               void* C, void* C2, int M, int N, int K, int lda, long long sA,
               long long sB, long long sC, long long sC2, int act, int outm,
               int tn) {
  const int gx = N / tn, gy = M / 128;
  dim3 g(gx * gy * BATCH), blk(256);
#define L(TN, ACT, OUT, HB) \
  mm_k<TN, ACT, OUT, HB><<<g, blk, 0, st>>>(A, B, bias, C, C2, M, N, K, lda, sA, sB, sC, sC2, gx, gy)
  if (tn == 64) {
    if (outm == 0) L(64, 0, 0, false);
    else if (outm == 1) L(64, 0, 1, false);
    else L(64, 2, 2, true);
  } else {
    if (outm == 0) {
      if (act == 1) L(128, 1, 0, true);
      else L(128, 0, 0, false);
    } else if (outm == 1) {
      if (act == 1) L(128, 1, 1, true);
      else L(128, 0, 1, false);
    } else if (outm == 2) L(128, 0, 2, true);
    else L(128, 0, 3, false);
  }
#undef L
}

static void mm256(hipStream_t st, const US* A, const US* B, void* C, void* C2,
                  int M, int N, int K, int lda, long long sA, long long sB,
                  long long sC, long long sC2, int outm) {
  const int gx = N / 256, gy = M / 256;
  dim3 g(gx * gy * BATCH), blk(512);
  if (outm == 0)
    mm256_k<0><<<g, blk, 0, st>>>(A, B, C, C2, M, N, K, lda, sA, sB, sC, sC2, gx, gy);
  else if (outm == 1)
    mm256_k<1><<<g, blk, 0, st>>>(A, B, C, C2, M, N, K, lda, sA, sB, sC, sC2, gx, gy);
  else
    mm256_k<3><<<g, blk, 0, st>>>(A, B, C, C2, M, N, K, lda, sA, sB, sC, sC2, gx, gy);
}

static void mm64(hipStream_t st, const US* A, const US* B, const float* bias,
                 void* C, int M, int N, int K, int lda, long long sA,
                 long long sB, long long sC, int act, int outm) {
  const int gx = N / 64, gy = M / 64;
  dim3 g(gx * gy * BATCH), blk(256);
  if (outm == 0)
    mm64_k<0, 0, false><<<g, blk, 0, st>>>(A, B, nullptr, C, M, N, K, lda, sA, sB, sC, gx, gy);
  else if (outm == 1)
    mm64_k<0, 1, false><<<g, blk, 0, st>>>(A, B, nullptr, C, M, N, K, lda, sA, sB, sC, gx, gy);
  else
    mm64_k<2, 2, true><<<g, blk, 0, st>>>(A, B, bias, C, M, N, K, lda, sA, sB, sC, gx, gy);
}

extern "C" void kernel_launch(void* const* d_in, const int* in_sizes, int n_in,
                              void* d_out, int out_size, void* d_ws, size_t ws_size,
                              hipStream_t stream) {
  const float* x      = (const float*)d_in[0];
  const float* eps    = (const float*)d_in[1];
  const float* adj    = (const float*)d_in[2];
  const float* We1    = (const float*)d_in[3];
  const float* be1    = (const float*)d_in[4];
  const float* Kemb1  = (const float*)d_in[5];
  const float* Kpool1 = (const float*)d_in[6];
  const float* We2    = (const float*)d_in[7];
  const float* be2    = (const float*)d_in[8];
  const float* Kemb2  = (const float*)d_in[9];
  const float* Kpool2 = (const float*)d_in[10];
  const float* We3    = (const float*)d_in[11];
  const float* be3    = (const float*)d_in[12];
  const float* Wd0    = (const float*)d_in[13];
  const float* bd0    = (const float*)d_in[14];
  const float* Wd1    = (const float*)d_in[15];
  const float* bd1    = (const float*)d_in[16];
  const float* Wd2    = (const float*)d_in[17];
  const float* bd2    = (const float*)d_in[18];
  const float* Wdf    = (const float*)d_in[19];
  const float* bdf    = (const float*)d_in[20];
  (void)in_sizes; (void)n_in; (void)ws_size; (void)out_size;

  float* out = (float*)d_out;
  float* out_mean = out + (long long)8 * 2048 * 64;
  float* out_lv = out_mean + (long long)8 * 512 * 64;

  char* base = (char*)d_ws;
  size_t off = 0;
  auto alloc = [&](size_t bytes) {
    char* p = base + off;
    off += (bytes + 255) & ~(size_t)255;
    return p;
  };
  US* Y0   = (US*)alloc(8LL * 2048 * 64 * 2);
  US* h1b  = (US*)alloc(8LL * 2048 * 256 * 2);   // h1 natural [2048][256]
  US* g1   = (US*)alloc(8LL * 2048 * 256 * 2);
  // R1n [8][2048][1280] natural [s1|z1] — dead after transb+spmm1024; its
  // 41,943,040 B are overlaid with pm/ps (stage-2 softmax) + decode temps.
  US* R1n  = (US*)alloc(8LL * 2048 * 1280 * 2);
  float* pm = (float*)R1n;                         //  8 MB
  float* ps = pm + 8LL * 128 * 2048;               //  8 MB
  US* d4    = (US*)(ps + 8LL * 128 * 2048);        //  8 MB [8][2048][256]
  US* t5T   = d4 + 8LL * 2048 * 256;               //  4 MB
  US* d2    = t5T + 8LL * 256 * 1024;              //  4 MB
  US* t3T   = d2 + 8LL * 1024 * 256;               //  2 MB
  US* t4T   = t3T + 8LL * 256 * 512;               //  2 MB
  US* d0    = t4T + 8LL * 256 * 512;               //  2 MB
  US* t6    = d0 + 8LL * 512 * 256;                //  2 MB  (sum = 41,943,040)
  US* R1   = (US*)alloc(8LL * 2304 * 2048 * 2);  // rows [s1T|z1T|AS1T]
  US* AS1  = (US*)alloc(8LL * 2048 * 1024 * 2);
  US* P1o  = (US*)alloc(8LL * 1024 * 1280 * 2);
  US* t1T  = (US*)alloc(8LL * 256 * 1024 * 2);
  US* h2T  = (US*)alloc(8LL * 256 * 1024 * 2);
  US* g2   = (US*)alloc(8LL * 1024 * 256 * 2);
  US* R2   = (US*)alloc(8LL * 1280 * 1024 * 2);
  US* AS2  = (US*)alloc(8LL * 1024 * 512 * 2);
  US* P2o  = (US*)alloc(8LL * 512 * 768 * 2);
  US* t2T  = (US*)alloc(8LL * 128 * 512 * 2);
  float* h3f = (float*)alloc(8LL * 512 * 128 * 4);
  US* zlb  = (US*)alloc(8LL * 512 * 64 * 2);
  float* Mf   = (float*)alloc(8LL * 2048 * 4);
  float* Sinv = (float*)alloc(8LL * 2048 * 4);
  int* rowcnt = (int*)alloc(2048 * 4);
  int* rowptr = (int*)alloc(2049 * 4);
  int* colidx = (int*)alloc(2048LL * 256 * 4);
  float* vals = (float*)alloc(2048LL * 256 * 4);
  US* We1T  = (US*)alloc(256 * 64 * 2);
  US* KpKe1 = (US*)alloc(1280 * 256 * 2);
  US* We2T  = (US*)alloc(256 * 256 * 2);
  US* KpKe2 = (US*)alloc(768 * 256 * 2);
  US* We3T  = (US*)alloc(128 * 256 * 2);
  US* Wd0T  = (US*)alloc(256 * 64 * 2);
  US* Wd1T  = (US*)alloc(256 * 256 * 2);
  US* Wd2T  = (US*)alloc(256 * 256 * 2);
  US* WdfT  = (US*)alloc(64 * 256 * 2);

  // ---- weight conversions + CSR build ----
  {
    WTab tab;
    int toff = 0, i = 0;
    auto add = [&](const float* s, US* d, int R, int C) {
      tab.e[i++] = WT{s, d, R, C, toff};
      toff += (R / 64) * (C / 64);
    };
    add(We1, We1T, 64, 256);
    add(Kpool1, KpKe1, 256, 1024);
    add(Kemb1, KpKe1 + 1024 * 256, 256, 256);
    add(We2, We2T, 256, 256);
    add(Kpool2, KpKe2, 256, 512);
    add(Kemb2, KpKe2 + 512 * 256, 256, 256);
    add(We3, We3T, 256, 128);
    add(Wd0, Wd0T, 64, 256);
    add(Wd1, Wd1T, 256, 256);
    add(Wd2, Wd2T, 256, 256);
    add(Wdf, WdfT, 256, 64);
    wtrans_k<<<dim3(toff), dim3(256), 0, stream>>>(tab);
  }
  csr_count_k<<<dim3(2048), dim3(256), 0, stream>>>(adj, rowcnt);
  csr_scan_k<<<dim3(1), dim3(256), 0, stream>>>(rowcnt, rowptr);
  csr_fill_k<<<dim3(2048), dim3(256), 0, stream>>>(adj, rowptr, colidx, vals);

  const long long SR1 = 2304LL * 2048, SR2 = 1280LL * 1024;
  const long long SR1n = 2048LL * 1280;
  US* s1T  = R1;
  US* B1   = R1 + 1024 * 2048;           // rows [z1T(256) | AS1T(1024)]
  US* AS1T = R1 + 1280 * 2048;
  US* s2T  = R2;
  US* B2   = R2 + 512 * 1024;
  US* AS2T = R2 + 768 * 1024;
  US* A1c  = P1o + 256;
  US* A2c  = P2o + 256;

  // ---------------- encode ----------------
  // Y0 = adj @ x  (SpMM from f32 x)
  spmm_k<64, true, 0, false, false><<<dim3(2048), dim3(256), 0, stream>>>(
      rowptr, colidx, vals, x, nullptr, Y0);
  // h1 = relu(Y0@We1+b)
  mm(stream, Y0, We1T, be1, h1b, nullptr, 2048, 256, 64, 64, 2048LL * 64, 0,
     2048LL * 256, 0, 1, 0, 128);
  // g1 = adj @ h1  (SpMM, XCD-batch-owned)
  spmm256_k<<<dim3(4096), dim3(256), 0, stream>>>(rowptr, colidx, vals, h1b, g1);
  // R1n = g1 @ [Kp1|Ke1]  (natural [2048][1280]: cols [s1 logits | z1])
  mm256(stream, g1, KpKe1, R1n, nullptr, 2048, 1280, 256, 256, 2048LL * 256, 0,
        SR1n, 0, 0);
  // row softmax over s1 logits (cols 0..1024)
  rowsm_k<<<dim3(16384), dim3(256), 0, stream>>>(R1n, 1280, SR1n);
  // R1 = R1n^T  ([1280][2048]: rows [s1T | z1T])
  transb_k<<<dim3(20, 32, 8), dim3(256), 0, stream>>>(R1n, R1, 2048, 1280,
                                                      SR1n, SR1);
  // AS1 = adj @ s1  (col-chunked SpMM wide)
  spmm1024_k<<<dim3(16384), dim3(256), 0, stream>>>(rowptr, colidx, vals, R1n,
                                                    1280, SR1n, AS1);
  // AS1T into B1 region  (R1n now dead — overlay region reusable)
  transb_k<<<dim3(16, 32, 8), dim3(256), 0, stream>>>(AS1, AS1T, 2048, 1024,
                                                      2048LL * 1024, SR1);
  // P1 = s1^T @ [z1 | AS1] -> [xp1 | A1]   (256^2)
  mm256(stream, s1T, B1, P1o, nullptr, 1024, 1280, 2048, 2048, SR1, SR1,
        1024LL * 1280, 0, 0);
  mm(stream, P1o, We2T, nullptr, t1T, nullptr, 1024, 256, 256, 1280, 1024LL * 1280,
     0, 0, 256LL * 1024, 0, 1, 128);
  mm(stream, A1c, t1T, be2, h2T, nullptr, 1024, 256, 1024, 1280, 1024LL * 1280,
     256LL * 1024, 0, 256LL * 1024, 1, 1, 128);
  mm(stream, A1c, h2T, nullptr, g2, nullptr, 1024, 256, 1024, 1280, 1024LL * 1280,
     256LL * 1024, 1024LL * 256, 0, 0, 0, 128);
  mm(stream, g2, KpKe2, nullptr, R2, nullptr, 1024, 768, 256, 256, 1024LL * 256,
     0, 0, SR2, 0, 1, 128);
  sm_partial_k<4><<<dim3(64, 8), dim3(256), 0, stream>>>(s2T, pm, ps, 512, 1024, SR2, 64);
  sm_combine_k<<<dim3(8), dim3(256), 0, stream>>>(pm, ps, Mf, Sinv, 1024, 128);
  sm_norm_k<4><<<dim3(64, 8), dim3(256), 0, stream>>>(s2T, Mf, Sinv, 512, 1024, SR2, 64);
  mm(stream, A1c, s2T, nullptr, AS2, AS2T, 1024, 512, 1024, 1280, 1024LL * 1280,
     SR2, 1024LL * 512, SR2, 0, 3, 128);
  mm(stream, s2T, B2, nullptr, P2o, nullptr, 512, 768, 1024, 1024, SR2, SR2,
     512LL * 768, 0, 0, 0, 128);
  mm(stream, P2o, We3T, nullptr, t2T, nullptr, 512, 128, 256, 768, 512LL * 768,
     0, 0, 128LL * 512, 0, 1, 128);
  mm(stream, A2c, t2T, be3, h3f, nullptr, 512, 128, 512, 768, 512LL * 768,
     128LL * 512, 512LL * 128, 0, 0, 2, 128);
  reparam_k<<<dim3(8 * 512 * 64 / 256), dim3(256), 0, stream>>>(h3f, eps, out_mean,
                                                                out_lv, zlb, 8 * 512 * 64);

  // ---------------- decode ----------------
  mm(stream, zlb, Wd0T, nullptr, t3T, nullptr, 512, 256, 64, 64, 512LL * 64, 0, 0,
     256LL * 512, 0, 1, 128);
  mm(stream, A2c, t3T, bd0, d0, nullptr, 512, 256, 512, 768, 512LL * 768,
     256LL * 512, 512LL * 256, 0, 1, 0, 128);
  mm(stream, d0, Wd1T, nullptr, t4T, nullptr, 512, 256, 256, 256, 512LL * 256, 0,
     0, 256LL * 512, 0, 1, 128);
  mm(stream, AS2, t4T, bd1, d2, nullptr, 1024, 256, 512, 512, 1024LL * 512,
     256LL * 512, 1024LL * 256, 0, 1, 0, 128);
  mm(stream, d2, Wd2T, nullptr, t5T, nullptr, 1024, 256, 256, 256, 1024LL * 256, 0,
     0, 256LL * 1024, 0, 1, 128);
  mm(stream, AS1, t5T, bd2, d4, nullptr, 2048, 256, 1024, 1024, 2048LL * 1024,
     256LL * 1024, 2048LL * 256, 0, 1, 0, 128);
  mm64(stream, d4, WdfT, nullptr, t6, 2048, 64, 256, 256, 2048LL * 256, 0,
       2048LL * 64, 0, 0);
  spmm_k<64, false, 2, true, true><<<dim3(2048), dim3(256), 0, stream>>>(
      rowptr, colidx, vals, t6, bdf, out);
}

// Round 15
// 632.817 us; speedup vs baseline: 1.1386x; 1.1386x over previous
//
#include <hip/hip_runtime.h>
#include <math.h>

#define BATCH 8
typedef unsigned short US;

typedef __attribute__((ext_vector_type(8))) short short8;
typedef __attribute__((ext_vector_type(4))) float f32x4;

__device__ __forceinline__ US f2b(float f) {
  union { float f; unsigned u; } v; v.f = f;
  unsigned r = v.u + 0x7fffu + ((v.u >> 16) & 1u);
  return (US)(r >> 16);
}
__device__ __forceinline__ float b2f(US h) {
  union { unsigned u; float f; } v; v.u = ((unsigned)h) << 16;
  return v.f;
}

__device__ __forceinline__ void gload16(const US* g, US* l) {
  __builtin_amdgcn_global_load_lds(
      (const __attribute__((address_space(1))) unsigned int*)g,
      (__attribute__((address_space(3))) unsigned int*)l, 16, 0, 0);
}

// LDS tile [rows][64] linear, XOR swizzle: 16B-cell index ^= (row&7).
__device__ __forceinline__ int lidx2(int r, int ko) {
  return r * 64 + ((((ko >> 3) ^ (r & 7)) << 3));
}

// ================= 128^2 1-phase MFMA GEMM (verified r3-r7) ==================
// C = act(A@B + bias). A bf16 phys [M][lda], B bf16 phys [N][K].
// OUT: 0=bf16 [M][N], 1=bf16 [N][M], 2=f32 [M][N], 3=dual bf16 [M][N]+[N][M].
template <int TN, int ACT, int OUT, bool HASBIAS>
__global__ __launch_bounds__(256) void mm_k(
    const US* __restrict__ A, const US* __restrict__ B,
    const float* __restrict__ bias, void* __restrict__ Cv, void* __restrict__ Cv2,
    int M, int N, int K, int lda, long long sA, long long sB, long long sC,
    long long sC2, int gx, int gy) {
  constexpr int JF = TN / 32;
  __shared__ US As[128 * 64];
  __shared__ US Bs[TN * 64];

  const int nb = blockIdx.x;
  const int nb2 = (nb & 7) * (gx * gy) + (nb >> 3);
  const int bx = nb2 % gx;
  const int by = (nb2 / gx) % gy;
  const int b = nb2 / (gx * gy);

  A += (long long)b * sA;
  B += (long long)b * sB;
  const int m0 = by * 128, n0 = bx * TN;
  const int t = threadIdx.x, lane = t & 63, w = t >> 6;
  const int wm = (w >> 1) * 64, wn = (w & 1) * (TN / 2);
  const int l15 = lane & 15, lg = lane >> 4;
  const int lrow = lane >> 3;
  const int gcell = (((lane & 7) ^ lrow) << 3);

  f32x4 acc[4][JF];
#pragma unroll
  for (int i = 0; i < 4; ++i)
#pragma unroll
    for (int j = 0; j < JF; ++j) acc[i][j] = (f32x4){0.f, 0.f, 0.f, 0.f};

  for (int k0 = 0; k0 < K; k0 += 64) {
#pragma unroll
    for (int i = 0; i < 4; ++i) {
      const int g = w * 4 + i;
      gload16(A + (long long)(m0 + g * 8 + lrow) * lda + k0 + gcell, &As[g * 512]);
    }
#pragma unroll
    for (int i = 0; i < TN / 32; ++i) {
      const int g = w * (TN / 32) + i;
      gload16(B + (long long)(n0 + g * 8 + lrow) * K + k0 + gcell, &Bs[g * 512]);
    }
    __syncthreads();

#pragma unroll
    for (int kk = 0; kk < 2; ++kk) {
      const int ko = kk * 32 + lg * 8;
      short8 af[4], bf[JF];
#pragma unroll
      for (int i = 0; i < 4; ++i)
        af[i] = *(const short8*)&As[lidx2(wm + i * 16 + l15, ko)];
#pragma unroll
      for (int j = 0; j < JF; ++j)
        bf[j] = *(const short8*)&Bs[lidx2(wn + j * 16 + l15, ko)];
#pragma unroll
      for (int i = 0; i < 4; ++i)
#pragma unroll
        for (int j = 0; j < JF; ++j)
          acc[i][j] = __builtin_amdgcn_mfma_f32_16x16x32_bf16(af[i], bf[j],
                                                              acc[i][j], 0, 0, 0);
    }
    __syncthreads();
  }

  const long long cb = (long long)b * sC;
  const long long cb2 = (long long)b * sC2;
#pragma unroll
  for (int fj = 0; fj < JF; ++fj) {
    const int col = n0 + wn + fj * 16 + l15;
    const float bsv = HASBIAS ? bias[col] : 0.0f;
#pragma unroll
    for (int fi = 0; fi < 4; ++fi) {
      const int row0 = m0 + wm + fi * 16 + lg * 4;
      float v[4];
#pragma unroll
      for (int e = 0; e < 4; ++e) {
        float x = acc[fi][fj][e] + bsv;
        if (ACT == 1) x = fmaxf(x, 0.0f);
        if (ACT == 2) x = (x > 20.0f) ? x : log1pf(expf(x));
        v[e] = x;
      }
      if (OUT == 1 || OUT == 3) {
        ushort4 pk;
        pk.x = f2b(v[0]); pk.y = f2b(v[1]); pk.z = f2b(v[2]); pk.w = f2b(v[3]);
        US* c2 = (OUT == 3) ? (US*)Cv2 : (US*)Cv;
        *(ushort4*)&c2[cb2 + (long long)col * M + row0] = pk;
      }
      if (OUT == 0 || OUT == 3) {
#pragma unroll
        for (int e = 0; e < 4; ++e)
          ((US*)Cv)[cb + (long long)(row0 + e) * N + col] = f2b(v[e]);
      }
      if (OUT == 2) {
#pragma unroll
        for (int e = 0; e < 4; ++e)
          ((float*)Cv)[cb + (long long)(row0 + e) * N + col] = v[e];
      }
    }
  }
}

// ================= 256^2 deep-pipelined MFMA GEMM (r7-exact) =================
template <int OUT>
__global__ __launch_bounds__(512, 1) void mm256_k(
    const US* __restrict__ A, const US* __restrict__ B, void* __restrict__ Cv,
    void* __restrict__ Cv2, int M, int N, int K, int lda, long long sA,
    long long sB, long long sC, long long sC2, int gx, int gy) {
  __shared__ US lds[8][8192];

  const int nb = blockIdx.x;
  const int chunk = gx * gy;
  const int nb2 = (nb & 7) * chunk + (nb >> 3);
  const int bx = nb2 % gx;
  const int by = (nb2 / gx) % gy;
  const int b = nb2 / chunk;

  const int m0 = by * 256, n0 = bx * 256;
  const int tid = threadIdx.x;
  const int lane = tid & 63, w = tid >> 6;
  const int wr = w >> 2, wc = w & 3;
  const int l15 = lane & 15, lg = lane >> 4;

  const US* Ab = A + (long long)b * sA + (long long)m0 * lda;
  const US* Bb = B + (long long)b * sB + (long long)n0 * K;
  const int NT = K >> 6;

  auto stageH = [&](int H) {
    const int s = H >> 2, h = H & 3;
    const int ab = h & 1, kk = h >> 1;
    US* reg = &lds[ab * 4 + (s & 1) * 2 + kk][0];
    const US* src = ab ? Bb : Ab;
    const int ld = ab ? K : lda;
#pragma unroll
    for (int i = 0; i < 2; ++i) {
      const int rbase = (w * 2 + i) * 16;
      const int r = rbase + (lane >> 2);
      const int csrc = (lane & 3) ^ ((r >> 1) & 3);
      gload16(src + (long long)r * ld + s * 64 + kk * 32 + csrc * 8,
              reg + rbase * 32);
    }
  };

  f32x4 acc[8][4];
#pragma unroll
  for (int m = 0; m < 8; ++m)
#pragma unroll
    for (int j = 0; j < 4; ++j) acc[m][j] = (f32x4){0.f, 0.f, 0.f, 0.f};
  short8 a4[4], b4[4];

  for (int H = 0; H < 6; ++H) stageH(H);
  asm volatile("s_waitcnt vmcnt(4)" ::: "memory");
  __builtin_amdgcn_s_barrier();

#define PH(kk_, mh_, DOH, HV, VM, tt)                                          \
  {                                                                            \
    const US* Ar = &lds[((tt) & 1) * 2 + (kk_)][0];                            \
    const US* Br = &lds[4 + ((tt) & 1) * 2 + (kk_)][0];                        \
    _Pragma("unroll") for (int i = 0; i < 4; ++i) {                            \
      const int r = wr * 128 + (mh_) * 64 + i * 16 + l15;                      \
      a4[i] = *(const short8*)&Ar[r * 32 + ((lg ^ ((r >> 1) & 3)) << 3)];      \
    }                                                                          \
    if ((mh_) == 0) {                                                          \
      _Pragma("unroll") for (int j = 0; j < 4; ++j) {                          \
        const int rr = wc * 64 + j * 16 + l15;                                 \
        b4[j] = *(const short8*)&Br[rr * 32 + ((lg ^ ((rr >> 1) & 3)) << 3)];  \
      }                                                                        \
    }                                                                          \
    if (DOH) stageH(HV);                                                       \
    if ((VM) == 1) asm volatile("s_waitcnt vmcnt(4)" ::: "memory");            \
    if ((VM) == 2) asm volatile("s_waitcnt vmcnt(0)" ::: "memory");            \
    __builtin_amdgcn_s_barrier();                                              \
    __builtin_amdgcn_s_setprio(1);                                             \
    _Pragma("unroll") for (int i = 0; i < 4; ++i)                              \
      _Pragma("unroll") for (int j = 0; j < 4; ++j)                            \
        acc[(mh_) * 4 + i][j] = __builtin_amdgcn_mfma_f32_16x16x32_bf16(       \
            a4[i], b4[j], acc[(mh_) * 4 + i][j], 0, 0, 0);                     \
    __builtin_amdgcn_s_setprio(0);                                             \
    __builtin_amdgcn_s_barrier();                                              \
  }

  int t2 = 0;
  for (; t2 < NT - 2; ++t2) {
    PH(0, 0, true, 4 * t2 + 6, 0, t2)
    PH(0, 1, true, 4 * t2 + 7, 0, t2)
    PH(1, 0, true, 4 * t2 + 8, 0, t2)
    PH(1, 1, true, 4 * t2 + 9, 1, t2)
  }
  PH(0, 0, true, 4 * (NT - 2) + 6, 0, NT - 2)
  PH(0, 1, true, 4 * (NT - 2) + 7, 0, NT - 2)
  PH(1, 0, false, 0, 0, NT - 2)
  PH(1, 1, false, 0, 2, NT - 2)
  PH(0, 0, false, 0, 0, NT - 1)
  PH(0, 1, false, 0, 0, NT - 1)
  PH(1, 0, false, 0, 0, NT - 1)
  PH(1, 1, false, 0, 0, NT - 1)
#undef PH

  const long long cb = (long long)b * sC;
  const long long cb2 = (long long)b * sC2;
#pragma unroll
  for (int j = 0; j < 4; ++j) {
    const int col = n0 + wc * 64 + j * 16 + l15;
#pragma unroll
    for (int m = 0; m < 8; ++m) {
      const int row0 = m0 + wr * 128 + m * 16 + lg * 4;
      if (OUT == 1 || OUT == 3) {
        ushort4 pk;
        pk.x = f2b(acc[m][j][0]); pk.y = f2b(acc[m][j][1]);
        pk.z = f2b(acc[m][j][2]); pk.w = f2b(acc[m][j][3]);
        US* c2 = (OUT == 3) ? (US*)Cv2 : (US*)Cv;
        *(ushort4*)&c2[cb2 + (long long)col * M + row0] = pk;
      }
      if (OUT == 0 || OUT == 3) {
#pragma unroll
        for (int e = 0; e < 4; ++e)
          ((US*)Cv)[cb + (long long)(row0 + e) * N + col] = f2b(acc[m][j][e]);
      }
    }
  }
}

// ================= 64x64 4-deep pipelined MFMA GEMM (skinny N) ===============
template <int ACT, int OUT, bool HASBIAS>
__global__ __launch_bounds__(256) void mm64_k(
    const US* __restrict__ A, const US* __restrict__ B,
    const float* __restrict__ bias, void* __restrict__ Cv,
    int M, int N, int K, int lda, long long sA, long long sB, long long sC,
    int gx, int gy) {
  __shared__ US As[4][4096];
  __shared__ US Bs[4][4096];

  const int nb = blockIdx.x;
  const int chunk = gx * gy;
  const int nb2 = (nb & 7) * chunk + (nb >> 3);
  const int bx = nb2 % gx;
  const int by = (nb2 / gx) % gy;
  const int b = nb2 / chunk;

  const int m0 = by * 64, n0 = bx * 64;
  const int tid = threadIdx.x;
  const int lane = tid & 63, w = tid >> 6;
  const int wr = w >> 1, wc = w & 1;
  const int l15 = lane & 15, lg = lane >> 4;
  const int lrow = lane >> 3;
  const int gcell = (((lane & 7) ^ lrow) << 3);

  const US* Ag = A + (long long)b * sA + (long long)m0 * lda;
  const US* Bg = B + (long long)b * sB + (long long)n0 * K;
  const int NT = K >> 6;

  auto stage = [&](int tt) {
    US* Ad = &As[tt & 3][0];
    US* Bd = &Bs[tt & 3][0];
    const int k0 = tt * 64;
#pragma unroll
    for (int i = 0; i < 2; ++i) {
      const int g = w * 2 + i;
      const int r = g * 8 + lrow;
      gload16(Ag + (long long)r * lda + k0 + gcell, Ad + g * 512);
      gload16(Bg + (long long)r * K + k0 + gcell, Bd + g * 512);
    }
  };

  f32x4 acc[2][2];
#pragma unroll
  for (int i = 0; i < 2; ++i)
#pragma unroll
    for (int j = 0; j < 2; ++j) acc[i][j] = (f32x4){0.f, 0.f, 0.f, 0.f};

  for (int i = 0; i < 3 && i < NT; ++i) stage(i);

  for (int t = 0; t < NT; ++t) {
    if (t + 3 < NT) stage(t + 3);
    const int rem = NT - 1 - t;
    if (rem >= 3) asm volatile("s_waitcnt vmcnt(12)" ::: "memory");
    else if (rem == 2) asm volatile("s_waitcnt vmcnt(8)" ::: "memory");
    else if (rem == 1) asm volatile("s_waitcnt vmcnt(4)" ::: "memory");
    else asm volatile("s_waitcnt vmcnt(0)" ::: "memory");
    asm volatile("s_barrier" ::: "memory");
    const US* Ad = &As[t & 3][0];
    const US* Bd = &Bs[t & 3][0];
#pragma unroll
    for (int kk = 0; kk < 2; ++kk) {
      const int ko = kk * 32 + lg * 8;
      short8 af[2], bf[2];
      af[0] = *(const short8*)&Ad[lidx2(wr * 32 + l15, ko)];
      af[1] = *(const short8*)&Ad[lidx2(wr * 32 + 16 + l15, ko)];
      bf[0] = *(const short8*)&Bd[lidx2(wc * 32 + l15, ko)];
      bf[1] = *(const short8*)&Bd[lidx2(wc * 32 + 16 + l15, ko)];
#pragma unroll
      for (int i = 0; i < 2; ++i)
#pragma unroll
        for (int j = 0; j < 2; ++j)
          acc[i][j] = __builtin_amdgcn_mfma_f32_16x16x32_bf16(af[i], bf[j],
                                                              acc[i][j], 0, 0, 0);
    }
    asm volatile("s_barrier" ::: "memory");
  }

  const long long cb = (long long)b * sC;
#pragma unroll
  for (int fj = 0; fj < 2; ++fj) {
    const int col = n0 + wc * 32 + fj * 16 + l15;
    const float bsv = HASBIAS ? bias[col] : 0.0f;
#pragma unroll
    for (int fi = 0; fi < 2; ++fi) {
      const int row0 = m0 + wr * 32 + fi * 16 + lg * 4;
      float v[4];
#pragma unroll
      for (int e = 0; e < 4; ++e) {
        float x = acc[fi][fj][e] + bsv;
        if (ACT == 1) x = fmaxf(x, 0.0f);
        if (ACT == 2) x = (x > 20.0f) ? x : log1pf(expf(x));
        v[e] = x;
      }
      if (OUT == 1) {
        ushort4 pk;
        pk.x = f2b(v[0]); pk.y = f2b(v[1]); pk.z = f2b(v[2]); pk.w = f2b(v[3]);
        *(ushort4*)&((US*)Cv)[cb + (long long)col * M + row0] = pk;
      } else if (OUT == 0) {
#pragma unroll
        for (int e = 0; e < 4; ++e)
          ((US*)Cv)[cb + (long long)(row0 + e) * N + col] = f2b(v[e]);
      } else {
#pragma unroll
        for (int e = 0; e < 4; ++e)
          ((float*)Cv)[cb + (long long)(row0 + e) * N + col] = v[e];
      }
    }
  }
}

// ================= CSR build (deterministic, no global atomics) ==============
__global__ __launch_bounds__(256) void csr_count_k(const float* __restrict__ adj,
                                                   int* __restrict__ rowcnt) {
  const int row = blockIdx.x, t = threadIdx.x;
  const float* p = adj + (long long)row * 2048;
  int c = 0;
  for (int j = t; j < 2048; j += 256) c += (p[j] != 0.0f);
  __shared__ int red[256];
  red[t] = c;
  __syncthreads();
  for (int s = 128; s; s >>= 1) {
    if (t < s) red[t] += red[t + s];
    __syncthreads();
  }
  if (t == 0) rowcnt[row] = red[0];
}

__global__ __launch_bounds__(256) void csr_scan_k(const int* __restrict__ rowcnt,
                                                  int* __restrict__ rowptr) {
  __shared__ int red[256];
  const int t = threadIdx.x;
  int base = 0;
  for (int ch = 0; ch < 8; ++ch) {
    const int v = rowcnt[ch * 256 + t];
    red[t] = v;
    __syncthreads();
    for (int s = 1; s < 256; s <<= 1) {
      const int add = (t >= s) ? red[t - s] : 0;
      __syncthreads();
      red[t] += add;
      __syncthreads();
    }
    rowptr[ch * 256 + t] = base + red[t] - v;
    const int tot = red[255];
    __syncthreads();
    base += tot;
  }
  if (t == 0) rowptr[2048] = base;
}

__global__ __launch_bounds__(256) void csr_fill_k(const float* __restrict__ adj,
                                                  const int* __restrict__ rowptr,
                                                  int* __restrict__ colidx,
                                                  float* __restrict__ vals) {
  const int row = blockIdx.x, t = threadIdx.x;
  const float* p = adj + (long long)row * 2048;
  int cnt = 0;
  for (int j = t; j < 2048; j += 256) cnt += (p[j] != 0.0f);
  __shared__ int red[256];
  red[t] = cnt;
  __syncthreads();
  for (int s = 1; s < 256; s <<= 1) {
    const int add = (t >= s) ? red[t - s] : 0;
    __syncthreads();
    red[t] += add;
    __syncthreads();
  }
  int off = rowptr[row] + red[t] - cnt;
  for (int j = t; j < 2048; j += 256) {
    const float a = p[j];
    if (a != 0.0f) {
      colidx[off] = j;
      vals[off] = a;
      ++off;
    }
  }
}

// ================= SpMM narrow: Y[b][row][c] = act(sum_j a_rj X[b][j][c]+bias)
template <int COLS, bool INF32, int ACT, bool OUTF32, bool HASBIAS>
__global__ __launch_bounds__(256) void spmm_k(
    const int* __restrict__ rowptr, const int* __restrict__ colidx,
    const float* __restrict__ vals, const void* __restrict__ Xv,
    const float* __restrict__ bias, void* __restrict__ Yv) {
  constexpr int BP = 256 / COLS;
  constexpr int NP = BATCH / BP;
  const int row = blockIdx.x;
  const int t = threadIdx.x;
  const int c = t & (COLS - 1);
  const int bsub = t / COLS;
  const int e0 = rowptr[row], e1 = rowptr[row + 1];
  float acc[NP];
#pragma unroll
  for (int p = 0; p < NP; ++p) acc[p] = 0.0f;
  for (int e = e0; e < e1; ++e) {
    const int j = colidx[e];
    const float a = vals[e];
#pragma unroll
    for (int p = 0; p < NP; ++p) {
      const int b = p * BP + bsub;
      const long long idx = ((long long)b * 2048 + j) * COLS + c;
      const float xv = INF32 ? ((const float*)Xv)[idx] : b2f(((const US*)Xv)[idx]);
      acc[p] += a * xv;
    }
  }
#pragma unroll
  for (int p = 0; p < NP; ++p) {
    const int b = p * BP + bsub;
    float v = acc[p] + (HASBIAS ? bias[c] : 0.0f);
    if (ACT == 2) v = (v > 20.0f) ? v : log1pf(expf(v));
    const long long idx = ((long long)b * 2048 + row) * COLS + c;
    if (OUTF32) ((float*)Yv)[idx] = v;
    else ((US*)Yv)[idx] = f2b(v);
  }
}

// ================= SpMM wide (1024 cols), 4-way ILP-unrolled =================
// Y[b][row][0..1024) = sum_j a_rj X[b][j][0..1024); X row stride ldx.
// Grid 16384: b = bid&7 (XCD-local batch), row = bid>>3. Inner e-loop unrolled
// 4x with two accumulator sets: 4 independent vector loads in flight per step.
__global__ __launch_bounds__(256) void spmm1024_k(
    const int* __restrict__ rowptr, const int* __restrict__ colidx,
    const float* __restrict__ vals, const US* __restrict__ X, int ldx,
    long long sX, US* __restrict__ Y) {
  const int bid = blockIdx.x;
  const int b = bid & 7;
  const int row = bid >> 3;
  const int t = threadIdx.x;
  const int c0 = t * 4;
  const US* Xb = X + (long long)b * sX + c0;
  const int e0 = rowptr[row], e1 = rowptr[row + 1];
  float p0[4] = {0.f, 0.f, 0.f, 0.f};
  float p1[4] = {0.f, 0.f, 0.f, 0.f};
  int e = e0;
  for (; e + 4 <= e1; e += 4) {
    const int j0 = colidx[e + 0], j1 = colidx[e + 1];
    const int j2 = colidx[e + 2], j3 = colidx[e + 3];
    const float a0 = vals[e + 0], a1 = vals[e + 1];
    const float a2 = vals[e + 2], a3 = vals[e + 3];
    const ushort4 x0 = *(const ushort4*)&Xb[(long long)j0 * ldx];
    const ushort4 x1 = *(const ushort4*)&Xb[(long long)j1 * ldx];
    const ushort4 x2 = *(const ushort4*)&Xb[(long long)j2 * ldx];
    const ushort4 x3 = *(const ushort4*)&Xb[(long long)j3 * ldx];
    p0[0] += a0 * b2f(x0.x); p0[1] += a0 * b2f(x0.y);
    p0[2] += a0 * b2f(x0.z); p0[3] += a0 * b2f(x0.w);
    p1[0] += a1 * b2f(x1.x); p1[1] += a1 * b2f(x1.y);
    p1[2] += a1 * b2f(x1.z); p1[3] += a1 * b2f(x1.w);
    p0[0] += a2 * b2f(x2.x); p0[1] += a2 * b2f(x2.y);
    p0[2] += a2 * b2f(x2.z); p0[3] += a2 * b2f(x2.w);
    p1[0] += a3 * b2f(x3.x); p1[1] += a3 * b2f(x3.y);
    p1[2] += a3 * b2f(x3.z); p1[3] += a3 * b2f(x3.w);
  }
  for (; e < e1; ++e) {
    const int j = colidx[e];
    const float a = vals[e];
    const ushort4 xv = *(const ushort4*)&Xb[(long long)j * ldx];
    p0[0] += a * b2f(xv.x); p0[1] += a * b2f(xv.y);
    p0[2] += a * b2f(xv.z); p0[3] += a * b2f(xv.w);
  }
  ushort4 o;
  o.x = f2b(p0[0] + p1[0]); o.y = f2b(p0[1] + p1[1]);
  o.z = f2b(p0[2] + p1[2]); o.w = f2b(p0[3] + p1[3]);
  *(ushort4*)&Y[((long long)b * 2048 + row) * 1024 + c0] = o;
}

// ================= row softmax over cols [0,1024) of x [B][2048][ldx] ========
__global__ __launch_bounds__(256) void rowsm_k(US* __restrict__ x, int ldx,
                                               long long sB) {
  __shared__ float red[256];
  const int bid = blockIdx.x;
  const int b = bid & 7;
  const int row = bid >> 3;
  const int t = threadIdx.x;
  US* p = x + (long long)b * sB + (long long)row * ldx + t * 4;
  union { ushort4 v; US s[4]; } buf;
  buf.v = *(const ushort4*)p;
  float v[4];
#pragma unroll
  for (int i = 0; i < 4; ++i) v[i] = b2f(buf.s[i]);
  float mx = fmaxf(fmaxf(v[0], v[1]), fmaxf(v[2], v[3]));
  red[t] = mx;
  __syncthreads();
  for (int s = 128; s; s >>= 1) {
    if (t < s) red[t] = fmaxf(red[t], red[t + s]);
    __syncthreads();
  }
  mx = red[0];
  __syncthreads();
  float sum = 0.f;
#pragma unroll
  for (int i = 0; i < 4; ++i) {
    v[i] = __expf(v[i] - mx);
    sum += v[i];
  }
  red[t] = sum;
  __syncthreads();
  for (int s = 128; s; s >>= 1) {
    if (t < s) red[t] += red[t + s];
    __syncthreads();
  }
  const float inv = 1.0f / red[0];
#pragma unroll
  for (int i = 0; i < 4; ++i) buf.s[i] = f2b(v[i] * inv);
  *(ushort4*)p = buf.v;
}

// ---------------- split column softmax over R of x [B][R][C] (stage 2) -------
template <int RPT>
__global__ __launch_bounds__(256) void sm_partial_k(
    const US* __restrict__ x, float* __restrict__ pm, float* __restrict__ ps,
    int R, int C, long long sB, int NS) {
  const int b = blockIdx.y, blk = blockIdx.x;
  const int cpr = C >> 3;
  const int t = threadIdx.x;
  const int cslot = t & (cpr - 1);
  const int rsub = t / cpr;
  const int nsub = 256 / cpr;
  const int rowsPerBlock = R / NS;
  const int r0 = blk * rowsPerBlock + rsub * RPT;
  const US* p = x + (long long)b * sB + (long long)r0 * C + cslot * 8;
  union { uint4 v; US s[8]; } buf[RPT];
#pragma unroll
  for (int i = 0; i < RPT; ++i) buf[i].v = *(const uint4*)(p + (long long)i * C);
  float M[8], S[8];
#pragma unroll
  for (int j = 0; j < 8; ++j) M[j] = b2f(buf[0].s[j]);
#pragma unroll
  for (int i = 1; i < RPT; ++i)
#pragma unroll
    for (int j = 0; j < 8; ++j) M[j] = fmaxf(M[j], b2f(buf[i].s[j]));
#pragma unroll
  for (int j = 0; j < 8; ++j) S[j] = 0.f;
#pragma unroll
  for (int i = 0; i < RPT; ++i)
#pragma unroll
    for (int j = 0; j < 8; ++j) S[j] += __expf(b2f(buf[i].s[j]) - M[j]);
  const long long pi = (long long)(b * NS + blk) * nsub + rsub;
  float* pmo = pm + pi * C + cslot * 8;
  float* pso = ps + pi * C + cslot * 8;
  *(float4*)pmo = make_float4(M[0], M[1], M[2], M[3]);
  *(float4*)(pmo + 4) = make_float4(M[4], M[5], M[6], M[7]);
  *(float4*)pso = make_float4(S[0], S[1], S[2], S[3]);
  *(float4*)(pso + 4) = make_float4(S[4], S[5], S[6], S[7]);
}

__global__ __launch_bounds__(256) void sm_combine_k(
    const float* __restrict__ pm, const float* __restrict__ ps,
    float* __restrict__ Mf, float* __restrict__ Sinv, int C, int NP) {
  const int b = blockIdx.x, t = threadIdx.x;
  const int cpr = C >> 3;
  if (t >= cpr) return;
  const int c = t * 8;
  const float* pmB = pm + (long long)b * NP * C + c;
  const float* psB = ps + (long long)b * NP * C + c;
  float M[8], S[8];
#pragma unroll
  for (int j = 0; j < 8; ++j) { M[j] = pmB[j]; S[j] = psB[j]; }
  for (int e = 1; e < NP; ++e) {
    const float* pme = pmB + (long long)e * C;
    const float* pse = psB + (long long)e * C;
#pragma unroll
    for (int j = 0; j < 8; ++j) {
      const float m2 = pme[j], s2 = pse[j];
      const float nm = fmaxf(M[j], m2);
      S[j] = S[j] * __expf(M[j] - nm) + s2 * __expf(m2 - nm);
      M[j] = nm;
    }
  }
#pragma unroll
  for (int j = 0; j < 8; ++j) {
    Mf[(long long)b * C + c + j] = M[j];
    Sinv[(long long)b * C + c + j] = 1.0f / S[j];
  }
}

template <int RPT>
__global__ __launch_bounds__(256) void sm_norm_k(
    US* __restrict__ x, const float* __restrict__ Mf,
    const float* __restrict__ Sinv, int R, int C, long long sB, int NS) {
  const int b = blockIdx.y, blk = blockIdx.x;
  const int cpr = C >> 3;
  const int t = threadIdx.x;
  const int cslot = t & (cpr - 1);
  const int rsub = t / cpr;
  const int rowsPerBlock = R / NS;
  const int r0 = blk * rowsPerBlock + rsub * RPT;
  US* p = x + (long long)b * sB + (long long)r0 * C + cslot * 8;
  float M[8], Si[8];
#pragma unroll
  for (int j = 0; j < 8; ++j) {
    M[j] = Mf[(long long)b * C + cslot * 8 + j];
    Si[j] = Sinv[(long long)b * C + cslot * 8 + j];
  }
#pragma unroll
  for (int i = 0; i < RPT; ++i) {
    union { uint4 v; US s[8]; } buf;
    buf.v = *(const uint4*)(p + (long long)i * C);
#pragma unroll
    for (int j = 0; j < 8; ++j)
      buf.s[j] = f2b(__expf(b2f(buf.s[j]) - M[j]) * Si[j]);
    *(uint4*)(p + (long long)i * C) = buf.v;
  }
}

// ---------------- bf16 transpose: src [B][R][C] -> dst [B][C][R] -------------
__global__ __launch_bounds__(256) void transb_k(const US* __restrict__ src,
                                                US* __restrict__ dst, int R,
                                                int C, long long sIn,
                                                long long sOut) {
  __shared__ US L[64][65];
  const int b = blockIdx.z;
  const int r0 = blockIdx.y * 64, c0 = blockIdx.x * 64;
  const int t = threadIdx.x;
  const int lr = t >> 4, lc = (t & 15) * 4;
  const US* s = src + (long long)b * sIn;
#pragma unroll
  for (int i = 0; i < 4; ++i) {
    const int rr = r0 + lr + 16 * i;
    const ushort4 v = *(const ushort4*)&s[(long long)rr * C + c0 + lc];
    L[lr + 16 * i][lc + 0] = v.x;
    L[lr + 16 * i][lc + 1] = v.y;
    L[lr + 16 * i][lc + 2] = v.z;
    L[lr + 16 * i][lc + 3] = v.w;
  }
  __syncthreads();
#pragma unroll
  for (int i = 0; i < 4; ++i) {
    ushort4 o;
    o.x = L[lc + 0][lr + 16 * i];
    o.y = L[lc + 1][lr + 16 * i];
    o.z = L[lc + 2][lr + 16 * i];
    o.w = L[lc + 3][lr + 16 * i];
    *(ushort4*)&dst[(long long)b * sOut + (long long)(c0 + lr + 16 * i) * R + r0 + lc] = o;
  }
}

// ---------------- fused weight transposes ----------------
struct WT { const float* src; US* dst; int R, C, tileOff; };
struct WTab { WT e[11]; };

__global__ __launch_bounds__(256) void wtrans_k(WTab tab) {
  __shared__ US L[64][65];
  const int tile = blockIdx.x;
  int i = 0;
#pragma unroll
  for (int j = 1; j < 11; ++j)
    if (tab.e[j].tileOff <= tile) i = j;
  const WT w = tab.e[i];
  const int lt = tile - w.tileOff;
  const int tc = w.C / 64;
  const int r0 = (lt / tc) * 64, c0 = (lt % tc) * 64;
  const int t = threadIdx.x;
  const int lr = t >> 4, lc = (t & 15) * 4;
#pragma unroll
  for (int k = 0; k < 4; ++k) {
    const int rr = r0 + lr + 16 * k;
    const float4 v = *(const float4*)&w.src[(long long)rr * w.C + c0 + lc];
    L[lr + 16 * k][lc + 0] = f2b(v.x);
    L[lr + 16 * k][lc + 1] = f2b(v.y);
    L[lr + 16 * k][lc + 2] = f2b(v.z);
    L[lr + 16 * k][lc + 3] = f2b(v.w);
  }
  __syncthreads();
#pragma unroll
  for (int k = 0; k < 4; ++k) {
    ushort4 o;
    o.x = L[lc + 0][lr + 16 * k];
    o.y = L[lc + 1][lr + 16 * k];
    o.z = L[lc + 2][lr + 16 * k];
    o.w = L[lc + 3][lr + 16 * k];
    *(ushort4*)&w.dst[(long long)(c0 + lr + 16 * k) * w.R + r0 + lc] = o;
  }
}

// ---------------- reparameterize ----------------
__global__ __launch_bounds__(256) void reparam_k(
    const float* __restrict__ h3, const float* __restrict__ eps,
    float* __restrict__ om, float* __restrict__ olv, US* __restrict__ z,
    int total) {
  const int i = blockIdx.x * 256 + threadIdx.x;
  if (i >= total) return;
  const int j = i & 63;
  const long long r = i >> 6;
  const float m = h3[r * 128 + j];
  const float lv = h3[r * 128 + 64 + j];
  om[i] = m;
  olv[i] = lv;
  z[i] = f2b(m + expf(0.5f * lv) * eps[i]);
}

// ---------------- host dispatch ----------------
static void mm(hipStream_t st, const US* A, const US* B, const float* bias,
               void* C, void* C2, int M, int N, int K, int lda, long long sA,
               long long sB, long long sC, long long sC2, int act, int outm,
               int tn) {
  const int gx = N / tn, gy = M / 128;
  dim3 g(gx * gy * BATCH), blk(256);
#define L(TN, ACT, OUT, HB) \
  mm_k<TN, ACT, OUT, HB><<<g, blk, 0, st>>>(A, B, bias, C, C2, M, N, K, lda, sA, sB, sC, sC2, gx, gy)
  if (tn == 64) {
    if (outm == 0) L(64, 0, 0, false);
    else if (outm == 1) L(64, 0, 1, false);
    else L(64, 2, 2, true);
  } else {
    if (outm == 0) {
      if (act == 1) L(128, 1, 0, true);
      else L(128, 0, 0, false);
    } else if (outm == 1) {
      if (act == 1) L(128, 1, 1, true);
      else L(128, 0, 1, false);
    } else if (outm == 2) L(128, 0, 2, true);
    else L(128, 0, 3, false);
  }
#undef L
}

static void mm256(hipStream_t st, const US* A, const US* B, void* C, void* C2,
                  int M, int N, int K, int lda, long long sA, long long sB,
                  long long sC, long long sC2, int outm) {
  const int gx = N / 256, gy = M / 256;
  dim3 g(gx * gy * BATCH), blk(512);
  if (outm == 0)
    mm256_k<0><<<g, blk, 0, st>>>(A, B, C, C2, M, N, K, lda, sA, sB, sC, sC2, gx, gy);
  else if (outm == 1)
    mm256_k<1><<<g, blk, 0, st>>>(A, B, C, C2, M, N, K, lda, sA, sB, sC, sC2, gx, gy);
  else
    mm256_k<3><<<g, blk, 0, st>>>(A, B, C, C2, M, N, K, lda, sA, sB, sC, sC2, gx, gy);
}

static void mm64(hipStream_t st, const US* A, const US* B, const float* bias,
                 void* C, int M, int N, int K, int lda, long long sA,
                 long long sB, long long sC, int act, int outm) {
  const int gx = N / 64, gy = M / 64;
  dim3 g(gx * gy * BATCH), blk(256);
  if (outm == 0)
    mm64_k<0, 0, false><<<g, blk, 0, st>>>(A, B, nullptr, C, M, N, K, lda, sA, sB, sC, gx, gy);
  else if (outm == 1)
    mm64_k<0, 1, false><<<g, blk, 0, st>>>(A, B, nullptr, C, M, N, K, lda, sA, sB, sC, gx, gy);
  else
    mm64_k<2, 2, true><<<g, blk, 0, st>>>(A, B, bias, C, M, N, K, lda, sA, sB, sC, gx, gy);
}

extern "C" void kernel_launch(void* const* d_in, const int* in_sizes, int n_in,
                              void* d_out, int out_size, void* d_ws, size_t ws_size,
                              hipStream_t stream) {
  const float* x      = (const float*)d_in[0];
  const float* eps    = (const float*)d_in[1];
  const float* adj    = (const float*)d_in[2];
  const float* We1    = (const float*)d_in[3];
  const float* be1    = (const float*)d_in[4];
  const float* Kemb1  = (const float*)d_in[5];
  const float* Kpool1 = (const float*)d_in[6];
  const float* We2    = (const float*)d_in[7];
  const float* be2    = (const float*)d_in[8];
  const float* Kemb2  = (const float*)d_in[9];
  const float* Kpool2 = (const float*)d_in[10];
  const float* We3    = (const float*)d_in[11];
  const float* be3    = (const float*)d_in[12];
  const float* Wd0    = (const float*)d_in[13];
  const float* bd0    = (const float*)d_in[14];
  const float* Wd1    = (const float*)d_in[15];
  const float* bd1    = (const float*)d_in[16];
  const float* Wd2    = (const float*)d_in[17];
  const float* bd2    = (const float*)d_in[18];
  const float* Wdf    = (const float*)d_in[19];
  const float* bdf    = (const float*)d_in[20];
  (void)in_sizes; (void)n_in; (void)ws_size; (void)out_size;

  float* out = (float*)d_out;
  float* out_mean = out + (long long)8 * 2048 * 64;
  float* out_lv = out_mean + (long long)8 * 512 * 64;

  char* base = (char*)d_ws;
  size_t off = 0;
  auto alloc = [&](size_t bytes) {
    char* p = base + off;
    off += (bytes + 255) & ~(size_t)255;
    return p;
  };
  US* Y0   = (US*)alloc(8LL * 2048 * 64 * 2);
  US* h1b  = (US*)alloc(8LL * 2048 * 256 * 2);   // h1 natural [2048][256]
  US* g1   = (US*)alloc(8LL * 2048 * 256 * 2);
  // R1n [8][2048][1280] natural [s1|z1] — dead after transb+spmm1024; its
  // 41,943,040 B are overlaid with pm/ps (stage-2 softmax) + decode temps.
  US* R1n  = (US*)alloc(8LL * 2048 * 1280 * 2);
  float* pm = (float*)R1n;                         //  8 MB
  float* ps = pm + 8LL * 128 * 2048;               //  8 MB
  US* d4    = (US*)(ps + 8LL * 128 * 2048);        //  8 MB [8][2048][256]
  US* t5T   = d4 + 8LL * 2048 * 256;               //  4 MB
  US* d2    = t5T + 8LL * 256 * 1024;              //  4 MB
  US* t3T   = d2 + 8LL * 1024 * 256;               //  2 MB
  US* t4T   = t3T + 8LL * 256 * 512;               //  2 MB
  US* d0    = t4T + 8LL * 256 * 512;               //  2 MB
  US* t6    = d0 + 8LL * 512 * 256;                //  2 MB  (sum = 41,943,040)
  US* R1   = (US*)alloc(8LL * 2304 * 2048 * 2);  // rows [s1T|z1T|AS1T]
  US* AS1  = (US*)alloc(8LL * 2048 * 1024 * 2);
  US* P1o  = (US*)alloc(8LL * 1024 * 1280 * 2);
  US* t1T  = (US*)alloc(8LL * 256 * 1024 * 2);
  US* h2T  = (US*)alloc(8LL * 256 * 1024 * 2);
  US* g2   = (US*)alloc(8LL * 1024 * 256 * 2);
  US* R2   = (US*)alloc(8LL * 1280 * 1024 * 2);
  US* AS2  = (US*)alloc(8LL * 1024 * 512 * 2);
  US* P2o  = (US*)alloc(8LL * 512 * 768 * 2);
  US* t2T  = (US*)alloc(8LL * 128 * 512 * 2);
  float* h3f = (float*)alloc(8LL * 512 * 128 * 4);
  US* zlb  = (US*)alloc(8LL * 512 * 64 * 2);
  float* Mf   = (float*)alloc(8LL * 2048 * 4);
  float* Sinv = (float*)alloc(8LL * 2048 * 4);
  int* rowcnt = (int*)alloc(2048 * 4);
  int* rowptr = (int*)alloc(2049 * 4);
  int* colidx = (int*)alloc(2048LL * 256 * 4);
  float* vals = (float*)alloc(2048LL * 256 * 4);
  US* We1T  = (US*)alloc(256 * 64 * 2);
  US* KpKe1 = (US*)alloc(1280 * 256 * 2);
  US* We2T  = (US*)alloc(256 * 256 * 2);
  US* KpKe2 = (US*)alloc(768 * 256 * 2);
  US* We3T  = (US*)alloc(128 * 256 * 2);
  US* Wd0T  = (US*)alloc(256 * 64 * 2);
  US* Wd1T  = (US*)alloc(256 * 256 * 2);
  US* Wd2T  = (US*)alloc(256 * 256 * 2);
  US* WdfT  = (US*)alloc(64 * 256 * 2);

  // ---- weight conversions + CSR build ----
  {
    WTab tab;
    int toff = 0, i = 0;
    auto add = [&](const float* s, US* d, int R, int C) {
      tab.e[i++] = WT{s, d, R, C, toff};
      toff += (R / 64) * (C / 64);
    };
    add(We1, We1T, 64, 256);
    add(Kpool1, KpKe1, 256, 1024);
    add(Kemb1, KpKe1 + 1024 * 256, 256, 256);
    add(We2, We2T, 256, 256);
    add(Kpool2, KpKe2, 256, 512);
    add(Kemb2, KpKe2 + 512 * 256, 256, 256);
    add(We3, We3T, 256, 128);
    add(Wd0, Wd0T, 64, 256);
    add(Wd1, Wd1T, 256, 256);
    add(Wd2, Wd2T, 256, 256);
    add(Wdf, WdfT, 256, 64);
    wtrans_k<<<dim3(toff), dim3(256), 0, stream>>>(tab);
  }
  csr_count_k<<<dim3(2048), dim3(256), 0, stream>>>(adj, rowcnt);
  csr_scan_k<<<dim3(1), dim3(256), 0, stream>>>(rowcnt, rowptr);
  csr_fill_k<<<dim3(2048), dim3(256), 0, stream>>>(adj, rowptr, colidx, vals);

  const long long SR1 = 2304LL * 2048, SR2 = 1280LL * 1024;
  const long long SR1n = 2048LL * 1280;
  US* s1T  = R1;
  US* B1   = R1 + 1024 * 2048;           // rows [z1T(256) | AS1T(1024)]
  US* AS1T = R1 + 1280 * 2048;
  US* s2T  = R2;
  US* B2   = R2 + 512 * 1024;
  US* AS2T = R2 + 768 * 1024;
  US* A1c  = P1o + 256;
  US* A2c  = P2o + 256;

  // ---------------- encode ----------------
  // Y0 = adj @ x  (SpMM from f32 x)
  spmm_k<64, true, 0, false, false><<<dim3(2048), dim3(256), 0, stream>>>(
      rowptr, colidx, vals, x, nullptr, Y0);
  // h1 = relu(Y0@We1+b)
  mm(stream, Y0, We1T, be1, h1b, nullptr, 2048, 256, 64, 64, 2048LL * 64, 0,
     2048LL * 256, 0, 1, 0, 128);
  // g1 = adj @ h1  (SpMM)
  spmm_k<256, false, 0, false, false><<<dim3(2048), dim3(256), 0, stream>>>(
      rowptr, colidx, vals, h1b, nullptr, g1);
  // R1n = g1 @ [Kp1|Ke1]  (natural [2048][1280]: cols [s1 logits | z1])
  mm256(stream, g1, KpKe1, R1n, nullptr, 2048, 1280, 256, 256, 2048LL * 256, 0,
        SR1n, 0, 0);
  // row softmax over s1 logits (cols 0..1024)
  rowsm_k<<<dim3(16384), dim3(256), 0, stream>>>(R1n, 1280, SR1n);
  // R1 = R1n^T  ([1280][2048]: rows [s1T | z1T])
  transb_k<<<dim3(20, 32, 8), dim3(256), 0, stream>>>(R1n, R1, 2048, 1280,
                                                      SR1n, SR1);
  // AS1 = adj @ s1  (SpMM wide, 4-way ILP)
  spmm1024_k<<<dim3(16384), dim3(256), 0, stream>>>(rowptr, colidx, vals, R1n,
                                                    1280, SR1n, AS1);
  // AS1T into B1 region  (R1n now dead — overlay region reusable)
  transb_k<<<dim3(16, 32, 8), dim3(256), 0, stream>>>(AS1, AS1T, 2048, 1024,
                                                      2048LL * 1024, SR1);
  // P1 = s1^T @ [z1 | AS1] -> [xp1 | A1]   (256^2)
  mm256(stream, s1T, B1, P1o, nullptr, 1024, 1280, 2048, 2048, SR1, SR1,
        1024LL * 1280, 0, 0);
  mm(stream, P1o, We2T, nullptr, t1T, nullptr, 1024, 256, 256, 1280, 1024LL * 1280,
     0, 0, 256LL * 1024, 0, 1, 128);
  mm(stream, A1c, t1T, be2, h2T, nullptr, 1024, 256, 1024, 1280, 1024LL * 1280,
     256LL * 1024, 0, 256LL * 1024, 1, 1, 128);
  mm(stream, A1c, h2T, nullptr, g2, nullptr, 1024, 256, 1024, 1280, 1024LL * 1280,
     256LL * 1024, 1024LL * 256, 0, 0, 0, 128);
  mm(stream, g2, KpKe2, nullptr, R2, nullptr, 1024, 768, 256, 256, 1024LL * 256,
     0, 0, SR2, 0, 1, 128);
  sm_partial_k<4><<<dim3(64, 8), dim3(256), 0, stream>>>(s2T, pm, ps, 512, 1024, SR2, 64);
  sm_combine_k<<<dim3(8), dim3(256), 0, stream>>>(pm, ps, Mf, Sinv, 1024, 128);
  sm_norm_k<4><<<dim3(64, 8), dim3(256), 0, stream>>>(s2T, Mf, Sinv, 512, 1024, SR2, 64);
  mm(stream, A1c, s2T, nullptr, AS2, AS2T, 1024, 512, 1024, 1280, 1024LL * 1280,
     SR2, 1024LL * 512, SR2, 0, 3, 128);
  mm(stream, s2T, B2, nullptr, P2o, nullptr, 512, 768, 1024, 1024, SR2, SR2,
     512LL * 768, 0, 0, 0, 128);
  mm(stream, P2o, We3T, nullptr, t2T, nullptr, 512, 128, 256, 768, 512LL * 768,
     0, 0, 128LL * 512, 0, 1, 128);
  mm(stream, A2c, t2T, be3, h3f, nullptr, 512, 128, 512, 768, 512LL * 768,
     128LL * 512, 512LL * 128, 0, 0, 2, 128);
  reparam_k<<<dim3(8 * 512 * 64 / 256), dim3(256), 0, stream>>>(h3f, eps, out_mean,
                                                                out_lv, zlb, 8 * 512 * 64);

  // ---------------- decode ----------------
  mm(stream, zlb, Wd0T, nullptr, t3T, nullptr, 512, 256, 64, 64, 512LL * 64, 0, 0,
     256LL * 512, 0, 1, 128);
  mm(stream, A2c, t3T, bd0, d0, nullptr, 512, 256, 512, 768, 512LL * 768,
     256LL * 512, 512LL * 256, 0, 1, 0, 128);
  mm(stream, d0, Wd1T, nullptr, t4T, nullptr, 512, 256, 256, 256, 512LL * 256, 0,
     0, 256LL * 512, 0, 1, 128);
  mm(stream, AS2, t4T, bd1, d2, nullptr, 1024, 256, 512, 512, 1024LL * 512,
     256LL * 512, 1024LL * 256, 0, 1, 0, 128);
  mm(stream, d2, Wd2T, nullptr, t5T, nullptr, 1024, 256, 256, 256, 1024LL * 256, 0,
     0, 256LL * 1024, 0, 1, 128);
  mm(stream, AS1, t5T, bd2, d4, nullptr, 2048, 256, 1024, 1024, 2048LL * 1024,
     256LL * 1024, 2048LL * 256, 0, 1, 0, 128);
  mm64(stream, d4, WdfT, nullptr, t6, 2048, 64, 256, 256, 2048LL * 256, 0,
       2048LL * 64, 0, 0);
  spmm_k<64, false, 2, true, true><<<dim3(2048), dim3(256), 0, stream>>>(
      rowptr, colidx, vals, t6, bdf, out);
}

// Round 16
// 629.244 us; speedup vs baseline: 1.1451x; 1.0057x over previous
//
#include <hip/hip_runtime.h>
#include <math.h>

#define BATCH 8
typedef unsigned short US;

typedef __attribute__((ext_vector_type(8))) short short8;
typedef __attribute__((ext_vector_type(4))) float f32x4;

__device__ __forceinline__ US f2b(float f) {
  union { float f; unsigned u; } v; v.f = f;
  unsigned r = v.u + 0x7fffu + ((v.u >> 16) & 1u);
  return (US)(r >> 16);
}
__device__ __forceinline__ float b2f(US h) {
  union { unsigned u; float f; } v; v.u = ((unsigned)h) << 16;
  return v.f;
}

__device__ __forceinline__ void gload16(const US* g, US* l) {
  __builtin_amdgcn_global_load_lds(
      (const __attribute__((address_space(1))) unsigned int*)g,
      (__attribute__((address_space(3))) unsigned int*)l, 16, 0, 0);
}

// LDS tile [rows][64] linear, XOR swizzle: 16B-cell index ^= (row&7).
__device__ __forceinline__ int lidx2(int r, int ko) {
  return r * 64 + ((((ko >> 3) ^ (r & 7)) << 3));
}

// ================= 128^2 1-phase MFMA GEMM (verified r3-r7) ==================
// C = act(A@B + bias). A bf16 phys [M][lda], B bf16 phys [N][K].
// OUT: 0=bf16 [M][N], 1=bf16 [N][M], 2=f32 [M][N], 3=dual bf16 [M][N]+[N][M].
template <int TN, int ACT, int OUT, bool HASBIAS>
__global__ __launch_bounds__(256) void mm_k(
    const US* __restrict__ A, const US* __restrict__ B,
    const float* __restrict__ bias, void* __restrict__ Cv, void* __restrict__ Cv2,
    int M, int N, int K, int lda, long long sA, long long sB, long long sC,
    long long sC2, int gx, int gy) {
  constexpr int JF = TN / 32;
  __shared__ US As[128 * 64];
  __shared__ US Bs[TN * 64];

  const int nb = blockIdx.x;
  const int nb2 = (nb & 7) * (gx * gy) + (nb >> 3);
  const int bx = nb2 % gx;
  const int by = (nb2 / gx) % gy;
  const int b = nb2 / (gx * gy);

  A += (long long)b * sA;
  B += (long long)b * sB;
  const int m0 = by * 128, n0 = bx * TN;
  const int t = threadIdx.x, lane = t & 63, w = t >> 6;
  const int wm = (w >> 1) * 64, wn = (w & 1) * (TN / 2);
  const int l15 = lane & 15, lg = lane >> 4;
  const int lrow = lane >> 3;
  const int gcell = (((lane & 7) ^ lrow) << 3);

  f32x4 acc[4][JF];
#pragma unroll
  for (int i = 0; i < 4; ++i)
#pragma unroll
    for (int j = 0; j < JF; ++j) acc[i][j] = (f32x4){0.f, 0.f, 0.f, 0.f};

  for (int k0 = 0; k0 < K; k0 += 64) {
#pragma unroll
    for (int i = 0; i < 4; ++i) {
      const int g = w * 4 + i;
      gload16(A + (long long)(m0 + g * 8 + lrow) * lda + k0 + gcell, &As[g * 512]);
    }
#pragma unroll
    for (int i = 0; i < TN / 32; ++i) {
      const int g = w * (TN / 32) + i;
      gload16(B + (long long)(n0 + g * 8 + lrow) * K + k0 + gcell, &Bs[g * 512]);
    }
    __syncthreads();

#pragma unroll
    for (int kk = 0; kk < 2; ++kk) {
      const int ko = kk * 32 + lg * 8;
      short8 af[4], bf[JF];
#pragma unroll
      for (int i = 0; i < 4; ++i)
        af[i] = *(const short8*)&As[lidx2(wm + i * 16 + l15, ko)];
#pragma unroll
      for (int j = 0; j < JF; ++j)
        bf[j] = *(const short8*)&Bs[lidx2(wn + j * 16 + l15, ko)];
#pragma unroll
      for (int i = 0; i < 4; ++i)
#pragma unroll
        for (int j = 0; j < JF; ++j)
          acc[i][j] = __builtin_amdgcn_mfma_f32_16x16x32_bf16(af[i], bf[j],
                                                              acc[i][j], 0, 0, 0);
    }
    __syncthreads();
  }

  const long long cb = (long long)b * sC;
  const long long cb2 = (long long)b * sC2;
#pragma unroll
  for (int fj = 0; fj < JF; ++fj) {
    const int col = n0 + wn + fj * 16 + l15;
    const float bsv = HASBIAS ? bias[col] : 0.0f;
#pragma unroll
    for (int fi = 0; fi < 4; ++fi) {
      const int row0 = m0 + wm + fi * 16 + lg * 4;
      float v[4];
#pragma unroll
      for (int e = 0; e < 4; ++e) {
        float x = acc[fi][fj][e] + bsv;
        if (ACT == 1) x = fmaxf(x, 0.0f);
        if (ACT == 2) x = (x > 20.0f) ? x : log1pf(expf(x));
        v[e] = x;
      }
      if (OUT == 1 || OUT == 3) {
        ushort4 pk;
        pk.x = f2b(v[0]); pk.y = f2b(v[1]); pk.z = f2b(v[2]); pk.w = f2b(v[3]);
        US* c2 = (OUT == 3) ? (US*)Cv2 : (US*)Cv;
        *(ushort4*)&c2[cb2 + (long long)col * M + row0] = pk;
      }
      if (OUT == 0 || OUT == 3) {
#pragma unroll
        for (int e = 0; e < 4; ++e)
          ((US*)Cv)[cb + (long long)(row0 + e) * N + col] = f2b(v[e]);
      }
      if (OUT == 2) {
#pragma unroll
        for (int e = 0; e < 4; ++e)
          ((float*)Cv)[cb + (long long)(row0 + e) * N + col] = v[e];
      }
    }
  }
}

// ================= 256^2 deep-pipelined MFMA GEMM (r7-exact) =================
template <int OUT>
__global__ __launch_bounds__(512, 1) void mm256_k(
    const US* __restrict__ A, const US* __restrict__ B, void* __restrict__ Cv,
    void* __restrict__ Cv2, int M, int N, int K, int lda, long long sA,
    long long sB, long long sC, long long sC2, int gx, int gy) {
  __shared__ US lds[8][8192];

  const int nb = blockIdx.x;
  const int chunk = gx * gy;
  const int nb2 = (nb & 7) * chunk + (nb >> 3);
  const int bx = nb2 % gx;
  const int by = (nb2 / gx) % gy;
  const int b = nb2 / chunk;

  const int m0 = by * 256, n0 = bx * 256;
  const int tid = threadIdx.x;
  const int lane = tid & 63, w = tid >> 6;
  const int wr = w >> 2, wc = w & 3;
  const int l15 = lane & 15, lg = lane >> 4;

  const US* Ab = A + (long long)b * sA + (long long)m0 * lda;
  const US* Bb = B + (long long)b * sB + (long long)n0 * K;
  const int NT = K >> 6;

  auto stageH = [&](int H) {
    const int s = H >> 2, h = H & 3;
    const int ab = h & 1, kk = h >> 1;
    US* reg = &lds[ab * 4 + (s & 1) * 2 + kk][0];
    const US* src = ab ? Bb : Ab;
    const int ld = ab ? K : lda;
#pragma unroll
    for (int i = 0; i < 2; ++i) {
      const int rbase = (w * 2 + i) * 16;
      const int r = rbase + (lane >> 2);
      const int csrc = (lane & 3) ^ ((r >> 1) & 3);
      gload16(src + (long long)r * ld + s * 64 + kk * 32 + csrc * 8,
              reg + rbase * 32);
    }
  };

  f32x4 acc[8][4];
#pragma unroll
  for (int m = 0; m < 8; ++m)
#pragma unroll
    for (int j = 0; j < 4; ++j) acc[m][j] = (f32x4){0.f, 0.f, 0.f, 0.f};
  short8 a4[4], b4[4];

  for (int H = 0; H < 6; ++H) stageH(H);
  asm volatile("s_waitcnt vmcnt(4)" ::: "memory");
  __builtin_amdgcn_s_barrier();

#define PH(kk_, mh_, DOH, HV, VM, tt)                                          \
  {                                                                            \
    const US* Ar = &lds[((tt) & 1) * 2 + (kk_)][0];                            \
    const US* Br = &lds[4 + ((tt) & 1) * 2 + (kk_)][0];                        \
    _Pragma("unroll") for (int i = 0; i < 4; ++i) {                            \
      const int r = wr * 128 + (mh_) * 64 + i * 16 + l15;                      \
      a4[i] = *(const short8*)&Ar[r * 32 + ((lg ^ ((r >> 1) & 3)) << 3)];      \
    }                                                                          \
    if ((mh_) == 0) {                                                          \
      _Pragma("unroll") for (int j = 0; j < 4; ++j) {                          \
        const int rr = wc * 64 + j * 16 + l15;                                 \
        b4[j] = *(const short8*)&Br[rr * 32 + ((lg ^ ((rr >> 1) & 3)) << 3)];  \
      }                                                                        \
    }                                                                          \
    if (DOH) stageH(HV);                                                       \
    if ((VM) == 1) asm volatile("s_waitcnt vmcnt(4)" ::: "memory");            \
    if ((VM) == 2) asm volatile("s_waitcnt vmcnt(0)" ::: "memory");            \
    __builtin_amdgcn_s_barrier();                                              \
    __builtin_amdgcn_s_setprio(1);                                             \
    _Pragma("unroll") for (int i = 0; i < 4; ++i)                              \
      _Pragma("unroll") for (int j = 0; j < 4; ++j)                            \
        acc[(mh_) * 4 + i][j] = __builtin_amdgcn_mfma_f32_16x16x32_bf16(       \
            a4[i], b4[j], acc[(mh_) * 4 + i][j], 0, 0, 0);                     \
    __builtin_amdgcn_s_setprio(0);                                             \
    __builtin_amdgcn_s_barrier();                                              \
  }

  int t2 = 0;
  for (; t2 < NT - 2; ++t2) {
    PH(0, 0, true, 4 * t2 + 6, 0, t2)
    PH(0, 1, true, 4 * t2 + 7, 0, t2)
    PH(1, 0, true, 4 * t2 + 8, 0, t2)
    PH(1, 1, true, 4 * t2 + 9, 1, t2)
  }
  PH(0, 0, true, 4 * (NT - 2) + 6, 0, NT - 2)
  PH(0, 1, true, 4 * (NT - 2) + 7, 0, NT - 2)
  PH(1, 0, false, 0, 0, NT - 2)
  PH(1, 1, false, 0, 2, NT - 2)
  PH(0, 0, false, 0, 0, NT - 1)
  PH(0, 1, false, 0, 0, NT - 1)
  PH(1, 0, false, 0, 0, NT - 1)
  PH(1, 1, false, 0, 0, NT - 1)
#undef PH

  const long long cb = (long long)b * sC;
  const long long cb2 = (long long)b * sC2;
#pragma unroll
  for (int j = 0; j < 4; ++j) {
    const int col = n0 + wc * 64 + j * 16 + l15;
#pragma unroll
    for (int m = 0; m < 8; ++m) {
      const int row0 = m0 + wr * 128 + m * 16 + lg * 4;
      if (OUT == 1 || OUT == 3) {
        ushort4 pk;
        pk.x = f2b(acc[m][j][0]); pk.y = f2b(acc[m][j][1]);
        pk.z = f2b(acc[m][j][2]); pk.w = f2b(acc[m][j][3]);
        US* c2 = (OUT == 3) ? (US*)Cv2 : (US*)Cv;
        *(ushort4*)&c2[cb2 + (long long)col * M + row0] = pk;
      }
      if (OUT == 0 || OUT == 3) {
#pragma unroll
        for (int e = 0; e < 4; ++e)
          ((US*)Cv)[cb + (long long)(row0 + e) * N + col] = f2b(acc[m][j][e]);
      }
    }
  }
}

// ================= 64x64 4-deep pipelined MFMA GEMM (skinny N) ===============
template <int ACT, int OUT, bool HASBIAS>
__global__ __launch_bounds__(256) void mm64_k(
    const US* __restrict__ A, const US* __restrict__ B,
    const float* __restrict__ bias, void* __restrict__ Cv,
    int M, int N, int K, int lda, long long sA, long long sB, long long sC,
    int gx, int gy) {
  __shared__ US As[4][4096];
  __shared__ US Bs[4][4096];

  const int nb = blockIdx.x;
  const int chunk = gx * gy;
  const int nb2 = (nb & 7) * chunk + (nb >> 3);
  const int bx = nb2 % gx;
  const int by = (nb2 / gx) % gy;
  const int b = nb2 / chunk;

  const int m0 = by * 64, n0 = bx * 64;
  const int tid = threadIdx.x;
  const int lane = tid & 63, w = tid >> 6;
  const int wr = w >> 1, wc = w & 1;
  const int l15 = lane & 15, lg = lane >> 4;
  const int lrow = lane >> 3;
  const int gcell = (((lane & 7) ^ lrow) << 3);

  const US* Ag = A + (long long)b * sA + (long long)m0 * lda;
  const US* Bg = B + (long long)b * sB + (long long)n0 * K;
  const int NT = K >> 6;

  auto stage = [&](int tt) {
    US* Ad = &As[tt & 3][0];
    US* Bd = &Bs[tt & 3][0];
    const int k0 = tt * 64;
#pragma unroll
    for (int i = 0; i < 2; ++i) {
      const int g = w * 2 + i;
      const int r = g * 8 + lrow;
      gload16(Ag + (long long)r * lda + k0 + gcell, Ad + g * 512);
      gload16(Bg + (long long)r * K + k0 + gcell, Bd + g * 512);
    }
  };

  f32x4 acc[2][2];
#pragma unroll
  for (int i = 0; i < 2; ++i)
#pragma unroll
    for (int j = 0; j < 2; ++j) acc[i][j] = (f32x4){0.f, 0.f, 0.f, 0.f};

  for (int i = 0; i < 3 && i < NT; ++i) stage(i);

  for (int t = 0; t < NT; ++t) {
    if (t + 3 < NT) stage(t + 3);
    const int rem = NT - 1 - t;
    if (rem >= 3) asm volatile("s_waitcnt vmcnt(12)" ::: "memory");
    else if (rem == 2) asm volatile("s_waitcnt vmcnt(8)" ::: "memory");
    else if (rem == 1) asm volatile("s_waitcnt vmcnt(4)" ::: "memory");
    else asm volatile("s_waitcnt vmcnt(0)" ::: "memory");
    asm volatile("s_barrier" ::: "memory");
    const US* Ad = &As[t & 3][0];
    const US* Bd = &Bs[t & 3][0];
#pragma unroll
    for (int kk = 0; kk < 2; ++kk) {
      const int ko = kk * 32 + lg * 8;
      short8 af[2], bf[2];
      af[0] = *(const short8*)&Ad[lidx2(wr * 32 + l15, ko)];
      af[1] = *(const short8*)&Ad[lidx2(wr * 32 + 16 + l15, ko)];
      bf[0] = *(const short8*)&Bd[lidx2(wc * 32 + l15, ko)];
      bf[1] = *(const short8*)&Bd[lidx2(wc * 32 + 16 + l15, ko)];
#pragma unroll
      for (int i = 0; i < 2; ++i)
#pragma unroll
        for (int j = 0; j < 2; ++j)
          acc[i][j] = __builtin_amdgcn_mfma_f32_16x16x32_bf16(af[i], bf[j],
                                                              acc[i][j], 0, 0, 0);
    }
    asm volatile("s_barrier" ::: "memory");
  }

  const long long cb = (long long)b * sC;
#pragma unroll
  for (int fj = 0; fj < 2; ++fj) {
    const int col = n0 + wc * 32 + fj * 16 + l15;
    const float bsv = HASBIAS ? bias[col] : 0.0f;
#pragma unroll
    for (int fi = 0; fi < 2; ++fi) {
      const int row0 = m0 + wr * 32 + fi * 16 + lg * 4;
      float v[4];
#pragma unroll
      for (int e = 0; e < 4; ++e) {
        float x = acc[fi][fj][e] + bsv;
        if (ACT == 1) x = fmaxf(x, 0.0f);
        if (ACT == 2) x = (x > 20.0f) ? x : log1pf(expf(x));
        v[e] = x;
      }
      if (OUT == 1) {
        ushort4 pk;
        pk.x = f2b(v[0]); pk.y = f2b(v[1]); pk.z = f2b(v[2]); pk.w = f2b(v[3]);
        *(ushort4*)&((US*)Cv)[cb + (long long)col * M + row0] = pk;
      } else if (OUT == 0) {
#pragma unroll
        for (int e = 0; e < 4; ++e)
          ((US*)Cv)[cb + (long long)(row0 + e) * N + col] = f2b(v[e]);
      } else {
#pragma unroll
        for (int e = 0; e < 4; ++e)
          ((float*)Cv)[cb + (long long)(row0 + e) * N + col] = v[e];
      }
    }
  }
}

// ================= CSR build (deterministic, no global atomics) ==============
__global__ __launch_bounds__(256) void csr_count_k(const float* __restrict__ adj,
                                                   int* __restrict__ rowcnt) {
  const int row = blockIdx.x, t = threadIdx.x;
  const float* p = adj + (long long)row * 2048;
  int c = 0;
  for (int j = t; j < 2048; j += 256) c += (p[j] != 0.0f);
  __shared__ int red[256];
  red[t] = c;
  __syncthreads();
  for (int s = 128; s; s >>= 1) {
    if (t < s) red[t] += red[t + s];
    __syncthreads();
  }
  if (t == 0) rowcnt[row] = red[0];
}

__global__ __launch_bounds__(256) void csr_scan_k(const int* __restrict__ rowcnt,
                                                  int* __restrict__ rowptr) {
  __shared__ int red[256];
  const int t = threadIdx.x;
  int base = 0;
  for (int ch = 0; ch < 8; ++ch) {
    const int v = rowcnt[ch * 256 + t];
    red[t] = v;
    __syncthreads();
    for (int s = 1; s < 256; s <<= 1) {
      const int add = (t >= s) ? red[t - s] : 0;
      __syncthreads();
      red[t] += add;
      __syncthreads();
    }
    rowptr[ch * 256 + t] = base + red[t] - v;
    const int tot = red[255];
    __syncthreads();
    base += tot;
  }
  if (t == 0) rowptr[2048] = base;
}

__global__ __launch_bounds__(256) void csr_fill_k(const float* __restrict__ adj,
                                                  const int* __restrict__ rowptr,
                                                  int* __restrict__ colidx,
                                                  float* __restrict__ vals) {
  const int row = blockIdx.x, t = threadIdx.x;
  const float* p = adj + (long long)row * 2048;
  int cnt = 0;
  for (int j = t; j < 2048; j += 256) cnt += (p[j] != 0.0f);
  __shared__ int red[256];
  red[t] = cnt;
  __syncthreads();
  for (int s = 1; s < 256; s <<= 1) {
    const int add = (t >= s) ? red[t - s] : 0;
    __syncthreads();
    red[t] += add;
    __syncthreads();
  }
  int off = rowptr[row] + red[t] - cnt;
  for (int j = t; j < 2048; j += 256) {
    const float a = p[j];
    if (a != 0.0f) {
      colidx[off] = j;
      vals[off] = a;
      ++off;
    }
  }
}

// ================= SpMM narrow: Y[b][row][c] = act(sum_j a_rj X[b][j][c]+bias)
template <int COLS, bool INF32, int ACT, bool OUTF32, bool HASBIAS>
__global__ __launch_bounds__(256) void spmm_k(
    const int* __restrict__ rowptr, const int* __restrict__ colidx,
    const float* __restrict__ vals, const void* __restrict__ Xv,
    const float* __restrict__ bias, void* __restrict__ Yv) {
  constexpr int BP = 256 / COLS;
  constexpr int NP = BATCH / BP;
  const int row = blockIdx.x;
  const int t = threadIdx.x;
  const int c = t & (COLS - 1);
  const int bsub = t / COLS;
  const int e0 = rowptr[row], e1 = rowptr[row + 1];
  float acc[NP];
#pragma unroll
  for (int p = 0; p < NP; ++p) acc[p] = 0.0f;
  for (int e = e0; e < e1; ++e) {
    const int j = colidx[e];
    const float a = vals[e];
#pragma unroll
    for (int p = 0; p < NP; ++p) {
      const int b = p * BP + bsub;
      const long long idx = ((long long)b * 2048 + j) * COLS + c;
      const float xv = INF32 ? ((const float*)Xv)[idx] : b2f(((const US*)Xv)[idx]);
      acc[p] += a * xv;
    }
  }
#pragma unroll
  for (int p = 0; p < NP; ++p) {
    const int b = p * BP + bsub;
    float v = acc[p] + (HASBIAS ? bias[c] : 0.0f);
    if (ACT == 2) v = (v > 20.0f) ? v : log1pf(expf(v));
    const long long idx = ((long long)b * 2048 + row) * COLS + c;
    if (OUTF32) ((float*)Yv)[idx] = v;
    else ((US*)Yv)[idx] = f2b(v);
  }
}

// ================= SpMM wide (1024 cols), 8-way ILP-unrolled =================
// Y[b][row][0..1024) = sum_j a_rj X[b][j][0..1024); X row stride ldx.
// Grid 16384: b = bid&7 (XCD-local batch), row = bid>>3. Inner e-loop unrolled
// 8x with four accumulator sets: 8 independent vector loads in flight.
__global__ __launch_bounds__(256) void spmm1024_k(
    const int* __restrict__ rowptr, const int* __restrict__ colidx,
    const float* __restrict__ vals, const US* __restrict__ X, int ldx,
    long long sX, US* __restrict__ Y) {
  const int bid = blockIdx.x;
  const int b = bid & 7;
  const int row = bid >> 3;
  const int t = threadIdx.x;
  const int c0 = t * 4;
  const US* Xb = X + (long long)b * sX + c0;
  const int e0 = rowptr[row], e1 = rowptr[row + 1];
  float p0[4] = {0.f, 0.f, 0.f, 0.f};
  float p1[4] = {0.f, 0.f, 0.f, 0.f};
  float p2[4] = {0.f, 0.f, 0.f, 0.f};
  float p3[4] = {0.f, 0.f, 0.f, 0.f};
  int e = e0;
  for (; e + 8 <= e1; e += 8) {
    const int j0 = colidx[e + 0], j1 = colidx[e + 1];
    const int j2 = colidx[e + 2], j3 = colidx[e + 3];
    const int j4 = colidx[e + 4], j5 = colidx[e + 5];
    const int j6 = colidx[e + 6], j7 = colidx[e + 7];
    const float a0 = vals[e + 0], a1 = vals[e + 1];
    const float a2 = vals[e + 2], a3 = vals[e + 3];
    const float a4 = vals[e + 4], a5 = vals[e + 5];
    const float a6 = vals[e + 6], a7 = vals[e + 7];
    const ushort4 x0 = *(const ushort4*)&Xb[(long long)j0 * ldx];
    const ushort4 x1 = *(const ushort4*)&Xb[(long long)j1 * ldx];
    const ushort4 x2 = *(const ushort4*)&Xb[(long long)j2 * ldx];
    const ushort4 x3 = *(const ushort4*)&Xb[(long long)j3 * ldx];
    const ushort4 x4 = *(const ushort4*)&Xb[(long long)j4 * ldx];
    const ushort4 x5 = *(const ushort4*)&Xb[(long long)j5 * ldx];
    const ushort4 x6 = *(const ushort4*)&Xb[(long long)j6 * ldx];
    const ushort4 x7 = *(const ushort4*)&Xb[(long long)j7 * ldx];
    p0[0] += a0 * b2f(x0.x); p0[1] += a0 * b2f(x0.y);
    p0[2] += a0 * b2f(x0.z); p0[3] += a0 * b2f(x0.w);
    p1[0] += a1 * b2f(x1.x); p1[1] += a1 * b2f(x1.y);
    p1[2] += a1 * b2f(x1.z); p1[3] += a1 * b2f(x1.w);
    p2[0] += a2 * b2f(x2.x); p2[1] += a2 * b2f(x2.y);
    p2[2] += a2 * b2f(x2.z); p2[3] += a2 * b2f(x2.w);
    p3[0] += a3 * b2f(x3.x); p3[1] += a3 * b2f(x3.y);
    p3[2] += a3 * b2f(x3.z); p3[3] += a3 * b2f(x3.w);
    p0[0] += a4 * b2f(x4.x); p0[1] += a4 * b2f(x4.y);
    p0[2] += a4 * b2f(x4.z); p0[3] += a4 * b2f(x4.w);
    p1[0] += a5 * b2f(x5.x); p1[1] += a5 * b2f(x5.y);
    p1[2] += a5 * b2f(x5.z); p1[3] += a5 * b2f(x5.w);
    p2[0] += a6 * b2f(x6.x); p2[1] += a6 * b2f(x6.y);
    p2[2] += a6 * b2f(x6.z); p2[3] += a6 * b2f(x6.w);
    p3[0] += a7 * b2f(x7.x); p3[1] += a7 * b2f(x7.y);
    p3[2] += a7 * b2f(x7.z); p3[3] += a7 * b2f(x7.w);
  }
  for (; e + 2 <= e1; e += 2) {
    const int j0 = colidx[e + 0], j1 = colidx[e + 1];
    const float a0 = vals[e + 0], a1 = vals[e + 1];
    const ushort4 x0 = *(const ushort4*)&Xb[(long long)j0 * ldx];
    const ushort4 x1 = *(const ushort4*)&Xb[(long long)j1 * ldx];
    p0[0] += a0 * b2f(x0.x); p0[1] += a0 * b2f(x0.y);
    p0[2] += a0 * b2f(x0.z); p0[3] += a0 * b2f(x0.w);
    p1[0] += a1 * b2f(x1.x); p1[1] += a1 * b2f(x1.y);
    p1[2] += a1 * b2f(x1.z); p1[3] += a1 * b2f(x1.w);
  }
  if (e < e1) {
    const int j = colidx[e];
    const float a = vals[e];
    const ushort4 xv = *(const ushort4*)&Xb[(long long)j * ldx];
    p0[0] += a * b2f(xv.x); p0[1] += a * b2f(xv.y);
    p0[2] += a * b2f(xv.z); p0[3] += a * b2f(xv.w);
  }
  ushort4 o;
  o.x = f2b((p0[0] + p1[0]) + (p2[0] + p3[0]));
  o.y = f2b((p0[1] + p1[1]) + (p2[1] + p3[1]));
  o.z = f2b((p0[2] + p1[2]) + (p2[2] + p3[2]));
  o.w = f2b((p0[3] + p1[3]) + (p2[3] + p3[3]));
  *(ushort4*)&Y[((long long)b * 2048 + row) * 1024 + c0] = o;
}

// ================= row softmax over cols [0,1024) of x [B][2048][ldx] ========
__global__ __launch_bounds__(256) void rowsm_k(US* __restrict__ x, int ldx,
                                               long long sB) {
  __shared__ float red[256];
  const int bid = blockIdx.x;
  const int b = bid & 7;
  const int row = bid >> 3;
  const int t = threadIdx.x;
  US* p = x + (long long)b * sB + (long long)row * ldx + t * 4;
  union { ushort4 v; US s[4]; } buf;
  buf.v = *(const ushort4*)p;
  float v[4];
#pragma unroll
  for (int i = 0; i < 4; ++i) v[i] = b2f(buf.s[i]);
  float mx = fmaxf(fmaxf(v[0], v[1]), fmaxf(v[2], v[3]));
  red[t] = mx;
  __syncthreads();
  for (int s = 128; s; s >>= 1) {
    if (t < s) red[t] = fmaxf(red[t], red[t + s]);
    __syncthreads();
  }
  mx = red[0];
  __syncthreads();
  float sum = 0.f;
#pragma unroll
  for (int i = 0; i < 4; ++i) {
    v[i] = __expf(v[i] - mx);
    sum += v[i];
  }
  red[t] = sum;
  __syncthreads();
  for (int s = 128; s; s >>= 1) {
    if (t < s) red[t] += red[t + s];
    __syncthreads();
  }
  const float inv = 1.0f / red[0];
#pragma unroll
  for (int i = 0; i < 4; ++i) buf.s[i] = f2b(v[i] * inv);
  *(ushort4*)p = buf.v;
}

// ---------------- split column softmax over R of x [B][R][C] (stage 2) -------
template <int RPT>
__global__ __launch_bounds__(256) void sm_partial_k(
    const US* __restrict__ x, float* __restrict__ pm, float* __restrict__ ps,
    int R, int C, long long sB, int NS) {
  const int b = blockIdx.y, blk = blockIdx.x;
  const int cpr = C >> 3;
  const int t = threadIdx.x;
  const int cslot = t & (cpr - 1);
  const int rsub = t / cpr;
  const int nsub = 256 / cpr;
  const int rowsPerBlock = R / NS;
  const int r0 = blk * rowsPerBlock + rsub * RPT;
  const US* p = x + (long long)b * sB + (long long)r0 * C + cslot * 8;
  union { uint4 v; US s[8]; } buf[RPT];
#pragma unroll
  for (int i = 0; i < RPT; ++i) buf[i].v = *(const uint4*)(p + (long long)i * C);
  float M[8], S[8];
#pragma unroll
  for (int j = 0; j < 8; ++j) M[j] = b2f(buf[0].s[j]);
#pragma unroll
  for (int i = 1; i < RPT; ++i)
#pragma unroll
    for (int j = 0; j < 8; ++j) M[j] = fmaxf(M[j], b2f(buf[i].s[j]));
#pragma unroll
  for (int j = 0; j < 8; ++j) S[j] = 0.f;
#pragma unroll
  for (int i = 0; i < RPT; ++i)
#pragma unroll
    for (int j = 0; j < 8; ++j) S[j] += __expf(b2f(buf[i].s[j]) - M[j]);
  const long long pi = (long long)(b * NS + blk) * nsub + rsub;
  float* pmo = pm + pi * C + cslot * 8;
  float* pso = ps + pi * C + cslot * 8;
  *(float4*)pmo = make_float4(M[0], M[1], M[2], M[3]);
  *(float4*)(pmo + 4) = make_float4(M[4], M[5], M[6], M[7]);
  *(float4*)pso = make_float4(S[0], S[1], S[2], S[3]);
  *(float4*)(pso + 4) = make_float4(S[4], S[5], S[6], S[7]);
}

__global__ __launch_bounds__(256) void sm_combine_k(
    const float* __restrict__ pm, const float* __restrict__ ps,
    float* __restrict__ Mf, float* __restrict__ Sinv, int C, int NP) {
  const int b = blockIdx.x, t = threadIdx.x;
  const int cpr = C >> 3;
  if (t >= cpr) return;
  const int c = t * 8;
  const float* pmB = pm + (long long)b * NP * C + c;
  const float* psB = ps + (long long)b * NP * C + c;
  float M[8], S[8];
#pragma unroll
  for (int j = 0; j < 8; ++j) { M[j] = pmB[j]; S[j] = psB[j]; }
  for (int e = 1; e < NP; ++e) {
    const float* pme = pmB + (long long)e * C;
    const float* pse = psB + (long long)e * C;
#pragma unroll
    for (int j = 0; j < 8; ++j) {
      const float m2 = pme[j], s2 = pse[j];
      const float nm = fmaxf(M[j], m2);
      S[j] = S[j] * __expf(M[j] - nm) + s2 * __expf(m2 - nm);
      M[j] = nm;
    }
  }
#pragma unroll
  for (int j = 0; j < 8; ++j) {
    Mf[(long long)b * C + c + j] = M[j];
    Sinv[(long long)b * C + c + j] = 1.0f / S[j];
  }
}

template <int RPT>
__global__ __launch_bounds__(256) void sm_norm_k(
    US* __restrict__ x, const float* __restrict__ Mf,
    const float* __restrict__ Sinv, int R, int C, long long sB, int NS) {
  const int b = blockIdx.y, blk = blockIdx.x;
  const int cpr = C >> 3;
  const int t = threadIdx.x;
  const int cslot = t & (cpr - 1);
  const int rsub = t / cpr;
  const int rowsPerBlock = R / NS;
  const int r0 = blk * rowsPerBlock + rsub * RPT;
  US* p = x + (long long)b * sB + (long long)r0 * C + cslot * 8;
  float M[8], Si[8];
#pragma unroll
  for (int j = 0; j < 8; ++j) {
    M[j] = Mf[(long long)b * C + cslot * 8 + j];
    Si[j] = Sinv[(long long)b * C + cslot * 8 + j];
  }
#pragma unroll
  for (int i = 0; i < RPT; ++i) {
    union { uint4 v; US s[8]; } buf;
    buf.v = *(const uint4*)(p + (long long)i * C);
#pragma unroll
    for (int j = 0; j < 8; ++j)
      buf.s[j] = f2b(__expf(b2f(buf.s[j]) - M[j]) * Si[j]);
    *(uint4*)(p + (long long)i * C) = buf.v;
  }
}

// ---------------- bf16 transpose: src [B][R][C] -> dst [B][C][R] -------------
__global__ __launch_bounds__(256) void transb_k(const US* __restrict__ src,
                                                US* __restrict__ dst, int R,
                                                int C, long long sIn,
                                                long long sOut) {
  __shared__ US L[64][65];
  const int b = blockIdx.z;
  const int r0 = blockIdx.y * 64, c0 = blockIdx.x * 64;
  const int t = threadIdx.x;
  const int lr = t >> 4, lc = (t & 15) * 4;
  const US* s = src + (long long)b * sIn;
#pragma unroll
  for (int i = 0; i < 4; ++i) {
    const int rr = r0 + lr + 16 * i;
    const ushort4 v = *(const ushort4*)&s[(long long)rr * C + c0 + lc];
    L[lr + 16 * i][lc + 0] = v.x;
    L[lr + 16 * i][lc + 1] = v.y;
    L[lr + 16 * i][lc + 2] = v.z;
    L[lr + 16 * i][lc + 3] = v.w;
  }
  __syncthreads();
#pragma unroll
  for (int i = 0; i < 4; ++i) {
    ushort4 o;
    o.x = L[lc + 0][lr + 16 * i];
    o.y = L[lc + 1][lr + 16 * i];
    o.z = L[lc + 2][lr + 16 * i];
    o.w = L[lc + 3][lr + 16 * i];
    *(ushort4*)&dst[(long long)b * sOut + (long long)(c0 + lr + 16 * i) * R + r0 + lc] = o;
  }
}

// ---------------- fused weight transposes ----------------
struct WT { const float* src; US* dst; int R, C, tileOff; };
struct WTab { WT e[11]; };

__global__ __launch_bounds__(256) void wtrans_k(WTab tab) {
  __shared__ US L[64][65];
  const int tile = blockIdx.x;
  int i = 0;
#pragma unroll
  for (int j = 1; j < 11; ++j)
    if (tab.e[j].tileOff <= tile) i = j;
  const WT w = tab.e[i];
  const int lt = tile - w.tileOff;
  const int tc = w.C / 64;
  const int r0 = (lt / tc) * 64, c0 = (lt % tc) * 64;
  const int t = threadIdx.x;
  const int lr = t >> 4, lc = (t & 15) * 4;
#pragma unroll
  for (int k = 0; k < 4; ++k) {
    const int rr = r0 + lr + 16 * k;
    const float4 v = *(const float4*)&w.src[(long long)rr * w.C + c0 + lc];
    L[lr + 16 * k][lc + 0] = f2b(v.x);
    L[lr + 16 * k][lc + 1] = f2b(v.y);
    L[lr + 16 * k][lc + 2] = f2b(v.z);
    L[lr + 16 * k][lc + 3] = f2b(v.w);
  }
  __syncthreads();
#pragma unroll
  for (int k = 0; k < 4; ++k) {
    ushort4 o;
    o.x = L[lc + 0][lr + 16 * k];
    o.y = L[lc + 1][lr + 16 * k];
    o.z = L[lc + 2][lr + 16 * k];
    o.w = L[lc + 3][lr + 16 * k];
    *(ushort4*)&w.dst[(long long)(c0 + lr + 16 * k) * w.R + r0 + lc] = o;
  }
}

// ---------------- reparameterize ----------------
__global__ __launch_bounds__(256) void reparam_k(
    const float* __restrict__ h3, const float* __restrict__ eps,
    float* __restrict__ om, float* __restrict__ olv, US* __restrict__ z,
    int total) {
  const int i = blockIdx.x * 256 + threadIdx.x;
  if (i >= total) return;
  const int j = i & 63;
  const long long r = i >> 6;
  const float m = h3[r * 128 + j];
  const float lv = h3[r * 128 + 64 + j];
  om[i] = m;
  olv[i] = lv;
  z[i] = f2b(m + expf(0.5f * lv) * eps[i]);
}

// ---------------- host dispatch ----------------
static void mm(hipStream_t st, const US* A, const US* B, const float* bias,
               void* C, void* C2, int M, int N, int K, int lda, long long sA,
               long long sB, long long sC, long long sC2, int act, int outm,
               int tn) {
  const int gx = N / tn, gy = M / 128;
  dim3 g(gx * gy * BATCH), blk(256);
#define L(TN, ACT, OUT, HB) \
  mm_k<TN, ACT, OUT, HB><<<g, blk, 0, st>>>(A, B, bias, C, C2, M, N, K, lda, sA, sB, sC, sC2, gx, gy)
  if (tn == 64) {
    if (outm == 0) L(64, 0, 0, false);
    else if (outm == 1) L(64, 0, 1, false);
    else L(64, 2, 2, true);
  } else {
    if (outm == 0) {
      if (act == 1) L(128, 1, 0, true);
      else L(128, 0, 0, false);
    } else if (outm == 1) {
      if (act == 1) L(128, 1, 1, true);
      else L(128, 0, 1, false);
    } else if (outm == 2) L(128, 0, 2, true);
    else L(128, 0, 3, false);
  }
#undef L
}

static void mm256(hipStream_t st, const US* A, const US* B, void* C, void* C2,
                  int M, int N, int K, int lda, long long sA, long long sB,
                  long long sC, long long sC2, int outm) {
  const int gx = N / 256, gy = M / 256;
  dim3 g(gx * gy * BATCH), blk(512);
  if (outm == 0)
    mm256_k<0><<<g, blk, 0, st>>>(A, B, C, C2, M, N, K, lda, sA, sB, sC, sC2, gx, gy);
  else if (outm == 1)
    mm256_k<1><<<g, blk, 0, st>>>(A, B, C, C2, M, N, K, lda, sA, sB, sC, sC2, gx, gy);
  else
    mm256_k<3><<<g, blk, 0, st>>>(A, B, C, C2, M, N, K, lda, sA, sB, sC, sC2, gx, gy);
}

static void mm64(hipStream_t st, const US* A, const US* B, const float* bias,
                 void* C, int M, int N, int K, int lda, long long sA,
                 long long sB, long long sC, int act, int outm) {
  const int gx = N / 64, gy = M / 64;
  dim3 g(gx * gy * BATCH), blk(256);
  if (outm == 0)
    mm64_k<0, 0, false><<<g, blk, 0, st>>>(A, B, nullptr, C, M, N, K, lda, sA, sB, sC, gx, gy);
  else if (outm == 1)
    mm64_k<0, 1, false><<<g, blk, 0, st>>>(A, B, nullptr, C, M, N, K, lda, sA, sB, sC, gx, gy);
  else
    mm64_k<2, 2, true><<<g, blk, 0, st>>>(A, B, bias, C, M, N, K, lda, sA, sB, sC, gx, gy);
}

extern "C" void kernel_launch(void* const* d_in, const int* in_sizes, int n_in,
                              void* d_out, int out_size, void* d_ws, size_t ws_size,
                              hipStream_t stream) {
  const float* x      = (const float*)d_in[0];
  const float* eps    = (const float*)d_in[1];
  const float* adj    = (const float*)d_in[2];
  const float* We1    = (const float*)d_in[3];
  const float* be1    = (const float*)d_in[4];
  const float* Kemb1  = (const float*)d_in[5];
  const float* Kpool1 = (const float*)d_in[6];
  const float* We2    = (const float*)d_in[7];
  const float* be2    = (const float*)d_in[8];
  const float* Kemb2  = (const float*)d_in[9];
  const float* Kpool2 = (const float*)d_in[10];
  const float* We3    = (const float*)d_in[11];
  const float* be3    = (const float*)d_in[12];
  const float* Wd0    = (const float*)d_in[13];
  const float* bd0    = (const float*)d_in[14];
  const float* Wd1    = (const float*)d_in[15];
  const float* bd1    = (const float*)d_in[16];
  const float* Wd2    = (const float*)d_in[17];
  const float* bd2    = (const float*)d_in[18];
  const float* Wdf    = (const float*)d_in[19];
  const float* bdf    = (const float*)d_in[20];
  (void)in_sizes; (void)n_in; (void)ws_size; (void)out_size;

  float* out = (float*)d_out;
  float* out_mean = out + (long long)8 * 2048 * 64;
  float* out_lv = out_mean + (long long)8 * 512 * 64;

  char* base = (char*)d_ws;
  size_t off = 0;
  auto alloc = [&](size_t bytes) {
    char* p = base + off;
    off += (bytes + 255) & ~(size_t)255;
    return p;
  };
  US* Y0   = (US*)alloc(8LL * 2048 * 64 * 2);
  US* h1b  = (US*)alloc(8LL * 2048 * 256 * 2);   // h1 natural [2048][256]
  US* g1   = (US*)alloc(8LL * 2048 * 256 * 2);
  // R1n [8][2048][1280] natural [s1|z1] — dead after transb+spmm1024; its
  // 41,943,040 B are overlaid with pm/ps (stage-2 softmax) + decode temps.
  US* R1n  = (US*)alloc(8LL * 2048 * 1280 * 2);
  float* pm = (float*)R1n;                         //  8 MB
  float* ps = pm + 8LL * 128 * 2048;               //  8 MB
  US* d4    = (US*)(ps + 8LL * 128 * 2048);        //  8 MB [8][2048][256]
  US* t5T   = d4 + 8LL * 2048 * 256;               //  4 MB
  US* d2    = t5T + 8LL * 256 * 1024;              //  4 MB
  US* t3T   = d2 + 8LL * 1024 * 256;               //  2 MB
  US* t4T   = t3T + 8LL * 256 * 512;               //  2 MB
  US* d0    = t4T + 8LL * 256 * 512;               //  2 MB
  US* t6    = d0 + 8LL * 512 * 256;                //  2 MB  (sum = 41,943,040)
  US* R1   = (US*)alloc(8LL * 2304 * 2048 * 2);  // rows [s1T|z1T|AS1T]
  US* AS1  = (US*)alloc(8LL * 2048 * 1024 * 2);
  US* P1o  = (US*)alloc(8LL * 1024 * 1280 * 2);
  US* t1T  = (US*)alloc(8LL * 256 * 1024 * 2);
  US* h2T  = (US*)alloc(8LL * 256 * 1024 * 2);
  US* g2   = (US*)alloc(8LL * 1024 * 256 * 2);
  US* R2   = (US*)alloc(8LL * 1280 * 1024 * 2);
  US* AS2  = (US*)alloc(8LL * 1024 * 512 * 2);
  US* P2o  = (US*)alloc(8LL * 512 * 768 * 2);
  US* t2T  = (US*)alloc(8LL * 128 * 512 * 2);
  float* h3f = (float*)alloc(8LL * 512 * 128 * 4);
  US* zlb  = (US*)alloc(8LL * 512 * 64 * 2);
  float* Mf   = (float*)alloc(8LL * 2048 * 4);
  float* Sinv = (float*)alloc(8LL * 2048 * 4);
  int* rowcnt = (int*)alloc(2048 * 4);
  int* rowptr = (int*)alloc(2049 * 4);
  int* colidx = (int*)alloc(2048LL * 256 * 4);
  float* vals = (float*)alloc(2048LL * 256 * 4);
  US* We1T  = (US*)alloc(256 * 64 * 2);
  US* KpKe1 = (US*)alloc(1280 * 256 * 2);
  US* We2T  = (US*)alloc(256 * 256 * 2);
  US* KpKe2 = (US*)alloc(768 * 256 * 2);
  US* We3T  = (US*)alloc(128 * 256 * 2);
  US* Wd0T  = (US*)alloc(256 * 64 * 2);
  US* Wd1T  = (US*)alloc(256 * 256 * 2);
  US* Wd2T  = (US*)alloc(256 * 256 * 2);
  US* WdfT  = (US*)alloc(64 * 256 * 2);

  // ---- weight conversions + CSR build ----
  {
    WTab tab;
    int toff = 0, i = 0;
    auto add = [&](const float* s, US* d, int R, int C) {
      tab.e[i++] = WT{s, d, R, C, toff};
      toff += (R / 64) * (C / 64);
    };
    add(We1, We1T, 64, 256);
    add(Kpool1, KpKe1, 256, 1024);
    add(Kemb1, KpKe1 + 1024 * 256, 256, 256);
    add(We2, We2T, 256, 256);
    add(Kpool2, KpKe2, 256, 512);
    add(Kemb2, KpKe2 + 512 * 256, 256, 256);
    add(We3, We3T, 256, 128);
    add(Wd0, Wd0T, 64, 256);
    add(Wd1, Wd1T, 256, 256);
    add(Wd2, Wd2T, 256, 256);
    add(Wdf, WdfT, 256, 64);
    wtrans_k<<<dim3(toff), dim3(256), 0, stream>>>(tab);
  }
  csr_count_k<<<dim3(2048), dim3(256), 0, stream>>>(adj, rowcnt);
  csr_scan_k<<<dim3(1), dim3(256), 0, stream>>>(rowcnt, rowptr);
  csr_fill_k<<<dim3(2048), dim3(256), 0, stream>>>(adj, rowptr, colidx, vals);

  const long long SR1 = 2304LL * 2048, SR2 = 1280LL * 1024;
  const long long SR1n = 2048LL * 1280;
  US* s1T  = R1;
  US* B1   = R1 + 1024 * 2048;           // rows [z1T(256) | AS1T(1024)]
  US* AS1T = R1 + 1280 * 2048;
  US* s2T  = R2;
  US* B2   = R2 + 512 * 1024;
  US* AS2T = R2 + 768 * 1024;
  US* A1c  = P1o + 256;
  US* A2c  = P2o + 256;

  // ---------------- encode ----------------
  // Y0 = adj @ x  (SpMM from f32 x)
  spmm_k<64, true, 0, false, false><<<dim3(2048), dim3(256), 0, stream>>>(
      rowptr, colidx, vals, x, nullptr, Y0);
  // h1 = relu(Y0@We1+b)
  mm(stream, Y0, We1T, be1, h1b, nullptr, 2048, 256, 64, 64, 2048LL * 64, 0,
     2048LL * 256, 0, 1, 0, 128);
  // g1 = adj @ h1  (SpMM)
  spmm_k<256, false, 0, false, false><<<dim3(2048), dim3(256), 0, stream>>>(
      rowptr, colidx, vals, h1b, nullptr, g1);
  // R1n = g1 @ [Kp1|Ke1]  (natural [2048][1280]: cols [s1 logits | z1])
  mm256(stream, g1, KpKe1, R1n, nullptr, 2048, 1280, 256, 256, 2048LL * 256, 0,
        SR1n, 0, 0);
  // row softmax over s1 logits (cols 0..1024)
  rowsm_k<<<dim3(16384), dim3(256), 0, stream>>>(R1n, 1280, SR1n);
  // R1 = R1n^T  ([1280][2048]: rows [s1T | z1T])
  transb_k<<<dim3(20, 32, 8), dim3(256), 0, stream>>>(R1n, R1, 2048, 1280,
                                                      SR1n, SR1);
  // AS1 = adj @ s1  (SpMM wide, 8-way ILP)
  spmm1024_k<<<dim3(16384), dim3(256), 0, stream>>>(rowptr, colidx, vals, R1n,
                                                    1280, SR1n, AS1);
  // AS1T into B1 region  (R1n now dead — overlay region reusable)
  transb_k<<<dim3(16, 32, 8), dim3(256), 0, stream>>>(AS1, AS1T, 2048, 1024,
                                                      2048LL * 1024, SR1);
  // P1 = s1^T @ [z1 | AS1] -> [xp1 | A1]   (256^2)
  mm256(stream, s1T, B1, P1o, nullptr, 1024, 1280, 2048, 2048, SR1, SR1,
        1024LL * 1280, 0, 0);
  mm(stream, P1o, We2T, nullptr, t1T, nullptr, 1024, 256, 256, 1280, 1024LL * 1280,
     0, 0, 256LL * 1024, 0, 1, 128);
  mm(stream, A1c, t1T, be2, h2T, nullptr, 1024, 256, 1024, 1280, 1024LL * 1280,
     256LL * 1024, 0, 256LL * 1024, 1, 1, 128);
  mm(stream, A1c, h2T, nullptr, g2, nullptr, 1024, 256, 1024, 1280, 1024LL * 1280,
     256LL * 1024, 1024LL * 256, 0, 0, 0, 128);
  mm(stream, g2, KpKe2, nullptr, R2, nullptr, 1024, 768, 256, 256, 1024LL * 256,
     0, 0, SR2, 0, 1, 128);
  sm_partial_k<4><<<dim3(64, 8), dim3(256), 0, stream>>>(s2T, pm, ps, 512, 1024, SR2, 64);
  sm_combine_k<<<dim3(8), dim3(256), 0, stream>>>(pm, ps, Mf, Sinv, 1024, 128);
  sm_norm_k<4><<<dim3(64, 8), dim3(256), 0, stream>>>(s2T, Mf, Sinv, 512, 1024, SR2, 64);
  mm(stream, A1c, s2T, nullptr, AS2, AS2T, 1024, 512, 1024, 1280, 1024LL * 1280,
     SR2, 1024LL * 512, SR2, 0, 3, 128);
  mm(stream, s2T, B2, nullptr, P2o, nullptr, 512, 768, 1024, 1024, SR2, SR2,
     512LL * 768, 0, 0, 0, 128);
  mm(stream, P2o, We3T, nullptr, t2T, nullptr, 512, 128, 256, 768, 512LL * 768,
     0, 0, 128LL * 512, 0, 1, 128);
  mm(stream, A2c, t2T, be3, h3f, nullptr, 512, 128, 512, 768, 512LL * 768,
     128LL * 512, 512LL * 128, 0, 0, 2, 128);
  reparam_k<<<dim3(8 * 512 * 64 / 256), dim3(256), 0, stream>>>(h3f, eps, out_mean,
                                                                out_lv, zlb, 8 * 512 * 64);

  // ---------------- decode ----------------
  mm(stream, zlb, Wd0T, nullptr, t3T, nullptr, 512, 256, 64, 64, 512LL * 64, 0, 0,
     256LL * 512, 0, 1, 128);
  mm(stream, A2c, t3T, bd0, d0, nullptr, 512, 256, 512, 768, 512LL * 768,
     256LL * 512, 512LL * 256, 0, 1, 0, 128);
  mm(stream, d0, Wd1T, nullptr, t4T, nullptr, 512, 256, 256, 256, 512LL * 256, 0,
     0, 256LL * 512, 0, 1, 128);
  mm(stream, AS2, t4T, bd1, d2, nullptr, 1024, 256, 512, 512, 1024LL * 512,
     256LL * 512, 1024LL * 256, 0, 1, 0, 128);
  mm(stream, d2, Wd2T, nullptr, t5T, nullptr, 1024, 256, 256, 256, 1024LL * 256, 0,
     0, 256LL * 1024, 0, 1, 128);
  mm(stream, AS1, t5T, bd2, d4, nullptr, 2048, 256, 1024, 1024, 2048LL * 1024,
     256LL * 1024, 2048LL * 256, 0, 1, 0, 128);
  mm64(stream, d4, WdfT, nullptr, t6, 2048, 64, 256, 256, 2048LL * 256, 0,
       2048LL * 64, 0, 0);
  spmm_k<64, false, 2, true, true><<<dim3(2048), dim3(256), 0, stream>>>(
      rowptr, colidx, vals, t6, bdf, out);
}

// Round 17
// 623.644 us; speedup vs baseline: 1.1553x; 1.0090x over previous
//
#include <hip/hip_runtime.h>
#include <math.h>

#define BATCH 8
typedef unsigned short US;

typedef __attribute__((ext_vector_type(8))) short short8;
typedef __attribute__((ext_vector_type(4))) float f32x4;

__device__ __forceinline__ US f2b(float f) {
  union { float f; unsigned u; } v; v.f = f;
  unsigned r = v.u + 0x7fffu + ((v.u >> 16) & 1u);
  return (US)(r >> 16);
}
__device__ __forceinline__ float b2f(US h) {
  union { unsigned u; float f; } v; v.u = ((unsigned)h) << 16;
  return v.f;
}

__device__ __forceinline__ void gload16(const US* g, US* l) {
  __builtin_amdgcn_global_load_lds(
      (const __attribute__((address_space(1))) unsigned int*)g,
      (__attribute__((address_space(3))) unsigned int*)l, 16, 0, 0);
}

// LDS tile [rows][64] linear, XOR swizzle: 16B-cell index ^= (row&7).
__device__ __forceinline__ int lidx2(int r, int ko) {
  return r * 64 + ((((ko >> 3) ^ (r & 7)) << 3));
}

// ================= 128^2 1-phase MFMA GEMM (verified r3-r7) ==================
// C = act(A@B + bias). A bf16 phys [M][lda], B bf16 phys [N][K].
// OUT: 0=bf16 [M][N], 1=bf16 [N][M], 2=f32 [M][N], 3=dual bf16 [M][N]+[N][M].
template <int TN, int ACT, int OUT, bool HASBIAS>
__global__ __launch_bounds__(256) void mm_k(
    const US* __restrict__ A, const US* __restrict__ B,
    const float* __restrict__ bias, void* __restrict__ Cv, void* __restrict__ Cv2,
    int M, int N, int K, int lda, long long sA, long long sB, long long sC,
    long long sC2, int gx, int gy) {
  constexpr int JF = TN / 32;
  __shared__ US As[128 * 64];
  __shared__ US Bs[TN * 64];

  const int nb = blockIdx.x;
  const int nb2 = (nb & 7) * (gx * gy) + (nb >> 3);
  const int bx = nb2 % gx;
  const int by = (nb2 / gx) % gy;
  const int b = nb2 / (gx * gy);

  A += (long long)b * sA;
  B += (long long)b * sB;
  const int m0 = by * 128, n0 = bx * TN;
  const int t = threadIdx.x, lane = t & 63, w = t >> 6;
  const int wm = (w >> 1) * 64, wn = (w & 1) * (TN / 2);
  const int l15 = lane & 15, lg = lane >> 4;
  const int lrow = lane >> 3;
  const int gcell = (((lane & 7) ^ lrow) << 3);

  f32x4 acc[4][JF];
#pragma unroll
  for (int i = 0; i < 4; ++i)
#pragma unroll
    for (int j = 0; j < JF; ++j) acc[i][j] = (f32x4){0.f, 0.f, 0.f, 0.f};

  for (int k0 = 0; k0 < K; k0 += 64) {
#pragma unroll
    for (int i = 0; i < 4; ++i) {
      const int g = w * 4 + i;
      gload16(A + (long long)(m0 + g * 8 + lrow) * lda + k0 + gcell, &As[g * 512]);
    }
#pragma unroll
    for (int i = 0; i < TN / 32; ++i) {
      const int g = w * (TN / 32) + i;
      gload16(B + (long long)(n0 + g * 8 + lrow) * K + k0 + gcell, &Bs[g * 512]);
    }
    __syncthreads();

#pragma unroll
    for (int kk = 0; kk < 2; ++kk) {
      const int ko = kk * 32 + lg * 8;
      short8 af[4], bf[JF];
#pragma unroll
      for (int i = 0; i < 4; ++i)
        af[i] = *(const short8*)&As[lidx2(wm + i * 16 + l15, ko)];
#pragma unroll
      for (int j = 0; j < JF; ++j)
        bf[j] = *(const short8*)&Bs[lidx2(wn + j * 16 + l15, ko)];
#pragma unroll
      for (int i = 0; i < 4; ++i)
#pragma unroll
        for (int j = 0; j < JF; ++j)
          acc[i][j] = __builtin_amdgcn_mfma_f32_16x16x32_bf16(af[i], bf[j],
                                                              acc[i][j], 0, 0, 0);
    }
    __syncthreads();
  }

  const long long cb = (long long)b * sC;
  const long long cb2 = (long long)b * sC2;
#pragma unroll
  for (int fj = 0; fj < JF; ++fj) {
    const int col = n0 + wn + fj * 16 + l15;
    const float bsv = HASBIAS ? bias[col] : 0.0f;
#pragma unroll
    for (int fi = 0; fi < 4; ++fi) {
      const int row0 = m0 + wm + fi * 16 + lg * 4;
      float v[4];
#pragma unroll
      for (int e = 0; e < 4; ++e) {
        float x = acc[fi][fj][e] + bsv;
        if (ACT == 1) x = fmaxf(x, 0.0f);
        if (ACT == 2) x = (x > 20.0f) ? x : log1pf(expf(x));
        v[e] = x;
      }
      if (OUT == 1 || OUT == 3) {
        ushort4 pk;
        pk.x = f2b(v[0]); pk.y = f2b(v[1]); pk.z = f2b(v[2]); pk.w = f2b(v[3]);
        US* c2 = (OUT == 3) ? (US*)Cv2 : (US*)Cv;
        *(ushort4*)&c2[cb2 + (long long)col * M + row0] = pk;
      }
      if (OUT == 0 || OUT == 3) {
#pragma unroll
        for (int e = 0; e < 4; ++e)
          ((US*)Cv)[cb + (long long)(row0 + e) * N + col] = f2b(v[e]);
      }
      if (OUT == 2) {
#pragma unroll
        for (int e = 0; e < 4; ++e)
          ((float*)Cv)[cb + (long long)(row0 + e) * N + col] = v[e];
      }
    }
  }
}

// ================= 256^2 deep-pipelined MFMA GEMM (r7-exact) =================
template <int OUT>
__global__ __launch_bounds__(512, 1) void mm256_k(
    const US* __restrict__ A, const US* __restrict__ B, void* __restrict__ Cv,
    void* __restrict__ Cv2, int M, int N, int K, int lda, long long sA,
    long long sB, long long sC, long long sC2, int gx, int gy) {
  __shared__ US lds[8][8192];

  const int nb = blockIdx.x;
  const int chunk = gx * gy;
  const int nb2 = (nb & 7) * chunk + (nb >> 3);
  const int bx = nb2 % gx;
  const int by = (nb2 / gx) % gy;
  const int b = nb2 / chunk;

  const int m0 = by * 256, n0 = bx * 256;
  const int tid = threadIdx.x;
  const int lane = tid & 63, w = tid >> 6;
  const int wr = w >> 2, wc = w & 3;
  const int l15 = lane & 15, lg = lane >> 4;

  const US* Ab = A + (long long)b * sA + (long long)m0 * lda;
  const US* Bb = B + (long long)b * sB + (long long)n0 * K;
  const int NT = K >> 6;

  auto stageH = [&](int H) {
    const int s = H >> 2, h = H & 3;
    const int ab = h & 1, kk = h >> 1;
    US* reg = &lds[ab * 4 + (s & 1) * 2 + kk][0];
    const US* src = ab ? Bb : Ab;
    const int ld = ab ? K : lda;
#pragma unroll
    for (int i = 0; i < 2; ++i) {
      const int rbase = (w * 2 + i) * 16;
      const int r = rbase + (lane >> 2);
      const int csrc = (lane & 3) ^ ((r >> 1) & 3);
      gload16(src + (long long)r * ld + s * 64 + kk * 32 + csrc * 8,
              reg + rbase * 32);
    }
  };

  f32x4 acc[8][4];
#pragma unroll
  for (int m = 0; m < 8; ++m)
#pragma unroll
    for (int j = 0; j < 4; ++j) acc[m][j] = (f32x4){0.f, 0.f, 0.f, 0.f};
  short8 a4[4], b4[4];

  for (int H = 0; H < 6; ++H) stageH(H);
  asm volatile("s_waitcnt vmcnt(4)" ::: "memory");
  __builtin_amdgcn_s_barrier();

#define PH(kk_, mh_, DOH, HV, VM, tt)                                          \
  {                                                                            \
    const US* Ar = &lds[((tt) & 1) * 2 + (kk_)][0];                            \
    const US* Br = &lds[4 + ((tt) & 1) * 2 + (kk_)][0];                        \
    _Pragma("unroll") for (int i = 0; i < 4; ++i) {                            \
      const int r = wr * 128 + (mh_) * 64 + i * 16 + l15;                      \
      a4[i] = *(const short8*)&Ar[r * 32 + ((lg ^ ((r >> 1) & 3)) << 3)];      \
    }                                                                          \
    if ((mh_) == 0) {                                                          \
      _Pragma("unroll") for (int j = 0; j < 4; ++j) {                          \
        const int rr = wc * 64 + j * 16 + l15;                                 \
        b4[j] = *(const short8*)&Br[rr * 32 + ((lg ^ ((rr >> 1) & 3)) << 3)];  \
      }                                                                        \
    }                                                                          \
    if (DOH) stageH(HV);                                                       \
    if ((VM) == 1) asm volatile("s_waitcnt vmcnt(4)" ::: "memory");            \
    if ((VM) == 2) asm volatile("s_waitcnt vmcnt(0)" ::: "memory");            \
    __builtin_amdgcn_s_barrier();                                              \
    __builtin_amdgcn_s_setprio(1);                                             \
    _Pragma("unroll") for (int i = 0; i < 4; ++i)                              \
      _Pragma("unroll") for (int j = 0; j < 4; ++j)                            \
        acc[(mh_) * 4 + i][j] = __builtin_amdgcn_mfma_f32_16x16x32_bf16(       \
            a4[i], b4[j], acc[(mh_) * 4 + i][j], 0, 0, 0);                     \
    __builtin_amdgcn_s_setprio(0);                                             \
    __builtin_amdgcn_s_barrier();                                              \
  }

  int t2 = 0;
  for (; t2 < NT - 2; ++t2) {
    PH(0, 0, true, 4 * t2 + 6, 0, t2)
    PH(0, 1, true, 4 * t2 + 7, 0, t2)
    PH(1, 0, true, 4 * t2 + 8, 0, t2)
    PH(1, 1, true, 4 * t2 + 9, 1, t2)
  }
  PH(0, 0, true, 4 * (NT - 2) + 6, 0, NT - 2)
  PH(0, 1, true, 4 * (NT - 2) + 7, 0, NT - 2)
  PH(1, 0, false, 0, 0, NT - 2)
  PH(1, 1, false, 0, 2, NT - 2)
  PH(0, 0, false, 0, 0, NT - 1)
  PH(0, 1, false, 0, 0, NT - 1)
  PH(1, 0, false, 0, 0, NT - 1)
  PH(1, 1, false, 0, 0, NT - 1)
#undef PH

  const long long cb = (long long)b * sC;
  const long long cb2 = (long long)b * sC2;
#pragma unroll
  for (int j = 0; j < 4; ++j) {
    const int col = n0 + wc * 64 + j * 16 + l15;
#pragma unroll
    for (int m = 0; m < 8; ++m) {
      const int row0 = m0 + wr * 128 + m * 16 + lg * 4;
      if (OUT == 1 || OUT == 3) {
        ushort4 pk;
        pk.x = f2b(acc[m][j][0]); pk.y = f2b(acc[m][j][1]);
        pk.z = f2b(acc[m][j][2]); pk.w = f2b(acc[m][j][3]);
        US* c2 = (OUT == 3) ? (US*)Cv2 : (US*)Cv;
        *(ushort4*)&c2[cb2 + (long long)col * M + row0] = pk;
      }
      if (OUT == 0 || OUT == 3) {
#pragma unroll
        for (int e = 0; e < 4; ++e)
          ((US*)Cv)[cb + (long long)(row0 + e) * N + col] = f2b(acc[m][j][e]);
      }
    }
  }
}

// ================= 64x64 4-deep pipelined MFMA GEMM (skinny N) ===============
template <int ACT, int OUT, bool HASBIAS>
__global__ __launch_bounds__(256) void mm64_k(
    const US* __restrict__ A, const US* __restrict__ B,
    const float* __restrict__ bias, void* __restrict__ Cv,
    int M, int N, int K, int lda, long long sA, long long sB, long long sC,
    int gx, int gy) {
  __shared__ US As[4][4096];
  __shared__ US Bs[4][4096];

  const int nb = blockIdx.x;
  const int chunk = gx * gy;
  const int nb2 = (nb & 7) * chunk + (nb >> 3);
  const int bx = nb2 % gx;
  const int by = (nb2 / gx) % gy;
  const int b = nb2 / chunk;

  const int m0 = by * 64, n0 = bx * 64;
  const int tid = threadIdx.x;
  const int lane = tid & 63, w = tid >> 6;
  const int wr = w >> 1, wc = w & 1;
  const int l15 = lane & 15, lg = lane >> 4;
  const int lrow = lane >> 3;
  const int gcell = (((lane & 7) ^ lrow) << 3);

  const US* Ag = A + (long long)b * sA + (long long)m0 * lda;
  const US* Bg = B + (long long)b * sB + (long long)n0 * K;
  const int NT = K >> 6;

  auto stage = [&](int tt) {
    US* Ad = &As[tt & 3][0];
    US* Bd = &Bs[tt & 3][0];
    const int k0 = tt * 64;
#pragma unroll
    for (int i = 0; i < 2; ++i) {
      const int g = w * 2 + i;
      const int r = g * 8 + lrow;
      gload16(Ag + (long long)r * lda + k0 + gcell, Ad + g * 512);
      gload16(Bg + (long long)r * K + k0 + gcell, Bd + g * 512);
    }
  };

  f32x4 acc[2][2];
#pragma unroll
  for (int i = 0; i < 2; ++i)
#pragma unroll
    for (int j = 0; j < 2; ++j) acc[i][j] = (f32x4){0.f, 0.f, 0.f, 0.f};

  for (int i = 0; i < 3 && i < NT; ++i) stage(i);

  for (int t = 0; t < NT; ++t) {
    if (t + 3 < NT) stage(t + 3);
    const int rem = NT - 1 - t;
    if (rem >= 3) asm volatile("s_waitcnt vmcnt(12)" ::: "memory");
    else if (rem == 2) asm volatile("s_waitcnt vmcnt(8)" ::: "memory");
    else if (rem == 1) asm volatile("s_waitcnt vmcnt(4)" ::: "memory");
    else asm volatile("s_waitcnt vmcnt(0)" ::: "memory");
    asm volatile("s_barrier" ::: "memory");
    const US* Ad = &As[t & 3][0];
    const US* Bd = &Bs[t & 3][0];
#pragma unroll
    for (int kk = 0; kk < 2; ++kk) {
      const int ko = kk * 32 + lg * 8;
      short8 af[2], bf[2];
      af[0] = *(const short8*)&Ad[lidx2(wr * 32 + l15, ko)];
      af[1] = *(const short8*)&Ad[lidx2(wr * 32 + 16 + l15, ko)];
      bf[0] = *(const short8*)&Bd[lidx2(wc * 32 + l15, ko)];
      bf[1] = *(const short8*)&Bd[lidx2(wc * 32 + 16 + l15, ko)];
#pragma unroll
      for (int i = 0; i < 2; ++i)
#pragma unroll
        for (int j = 0; j < 2; ++j)
          acc[i][j] = __builtin_amdgcn_mfma_f32_16x16x32_bf16(af[i], bf[j],
                                                              acc[i][j], 0, 0, 0);
    }
    asm volatile("s_barrier" ::: "memory");
  }

  const long long cb = (long long)b * sC;
#pragma unroll
  for (int fj = 0; fj < 2; ++fj) {
    const int col = n0 + wc * 32 + fj * 16 + l15;
    const float bsv = HASBIAS ? bias[col] : 0.0f;
#pragma unroll
    for (int fi = 0; fi < 2; ++fi) {
      const int row0 = m0 + wr * 32 + fi * 16 + lg * 4;
      float v[4];
#pragma unroll
      for (int e = 0; e < 4; ++e) {
        float x = acc[fi][fj][e] + bsv;
        if (ACT == 1) x = fmaxf(x, 0.0f);
        if (ACT == 2) x = (x > 20.0f) ? x : log1pf(expf(x));
        v[e] = x;
      }
      if (OUT == 1) {
        ushort4 pk;
        pk.x = f2b(v[0]); pk.y = f2b(v[1]); pk.z = f2b(v[2]); pk.w = f2b(v[3]);
        *(ushort4*)&((US*)Cv)[cb + (long long)col * M + row0] = pk;
      } else if (OUT == 0) {
#pragma unroll
        for (int e = 0; e < 4; ++e)
          ((US*)Cv)[cb + (long long)(row0 + e) * N + col] = f2b(v[e]);
      } else {
#pragma unroll
        for (int e = 0; e < 4; ++e)
          ((float*)Cv)[cb + (long long)(row0 + e) * N + col] = v[e];
      }
    }
  }
}

// ================= CSR build (deterministic, no global atomics) ==============
__global__ __launch_bounds__(256) void csr_count_k(const float* __restrict__ adj,
                                                   int* __restrict__ rowcnt) {
  const int row = blockIdx.x, t = threadIdx.x;
  const float* p = adj + (long long)row * 2048;
  int c = 0;
  for (int j = t; j < 2048; j += 256) c += (p[j] != 0.0f);
  __shared__ int red[256];
  red[t] = c;
  __syncthreads();
  for (int s = 128; s; s >>= 1) {
    if (t < s) red[t] += red[t + s];
    __syncthreads();
  }
  if (t == 0) rowcnt[row] = red[0];
}

__global__ __launch_bounds__(256) void csr_scan_k(const int* __restrict__ rowcnt,
                                                  int* __restrict__ rowptr) {
  __shared__ int red[256];
  const int t = threadIdx.x;
  int base = 0;
  for (int ch = 0; ch < 8; ++ch) {
    const int v = rowcnt[ch * 256 + t];
    red[t] = v;
    __syncthreads();
    for (int s = 1; s < 256; s <<= 1) {
      const int add = (t >= s) ? red[t - s] : 0;
      __syncthreads();
      red[t] += add;
      __syncthreads();
    }
    rowptr[ch * 256 + t] = base + red[t] - v;
    const int tot = red[255];
    __syncthreads();
    base += tot;
  }
  if (t == 0) rowptr[2048] = base;
}

__global__ __launch_bounds__(256) void csr_fill_k(const float* __restrict__ adj,
                                                  const int* __restrict__ rowptr,
                                                  int* __restrict__ colidx,
                                                  float* __restrict__ vals) {
  const int row = blockIdx.x, t = threadIdx.x;
  const float* p = adj + (long long)row * 2048;
  int cnt = 0;
  for (int j = t; j < 2048; j += 256) cnt += (p[j] != 0.0f);
  __shared__ int red[256];
  red[t] = cnt;
  __syncthreads();
  for (int s = 1; s < 256; s <<= 1) {
    const int add = (t >= s) ? red[t - s] : 0;
    __syncthreads();
    red[t] += add;
    __syncthreads();
  }
  int off = rowptr[row] + red[t] - cnt;
  for (int j = t; j < 2048; j += 256) {
    const float a = p[j];
    if (a != 0.0f) {
      colidx[off] = j;
      vals[off] = a;
      ++off;
    }
  }
}

// ================= SpMM narrow: Y[b][row][c] = act(sum_j a_rj X[b][j][c]+bias)
template <int COLS, bool INF32, int ACT, bool OUTF32, bool HASBIAS>
__global__ __launch_bounds__(256) void spmm_k(
    const int* __restrict__ rowptr, const int* __restrict__ colidx,
    const float* __restrict__ vals, const void* __restrict__ Xv,
    const float* __restrict__ bias, void* __restrict__ Yv) {
  constexpr int BP = 256 / COLS;
  constexpr int NP = BATCH / BP;
  const int row = blockIdx.x;
  const int t = threadIdx.x;
  const int c = t & (COLS - 1);
  const int bsub = t / COLS;
  const int e0 = rowptr[row], e1 = rowptr[row + 1];
  float acc[NP];
#pragma unroll
  for (int p = 0; p < NP; ++p) acc[p] = 0.0f;
  for (int e = e0; e < e1; ++e) {
    const int j = colidx[e];
    const float a = vals[e];
#pragma unroll
    for (int p = 0; p < NP; ++p) {
      const int b = p * BP + bsub;
      const long long idx = ((long long)b * 2048 + j) * COLS + c;
      const float xv = INF32 ? ((const float*)Xv)[idx] : b2f(((const US*)Xv)[idx]);
      acc[p] += a * xv;
    }
  }
#pragma unroll
  for (int p = 0; p < NP; ++p) {
    const int b = p * BP + bsub;
    float v = acc[p] + (HASBIAS ? bias[c] : 0.0f);
    if (ACT == 2) v = (v > 20.0f) ? v : log1pf(expf(v));
    const long long idx = ((long long)b * 2048 + row) * COLS + c;
    if (OUTF32) ((float*)Yv)[idx] = v;
    else ((US*)Yv)[idx] = f2b(v);
  }
}

// ================= SpMM wide (1024 cols), 16B gathers, 4-way ILP =============
// Y[b][row][0..1024) = sum_j a_rj X[b][j][0..1024); X row stride ldx.
// Grid 8192: b = bid&7 (XCD-local batch), rowpair = bid>>3; 2 rows/block,
// 128 threads/row, 8 cols (16B) per thread. 4-way unroll, 2 accumulator sets.
__global__ __launch_bounds__(256) void spmm1024_k(
    const int* __restrict__ rowptr, const int* __restrict__ colidx,
    const float* __restrict__ vals, const US* __restrict__ X, int ldx,
    long long sX, US* __restrict__ Y) {
  const int bid = blockIdx.x;
  const int b = bid & 7;
  const int rp = bid >> 3;
  const int t = threadIdx.x;
  const int row = rp * 2 + (t >> 7);
  const int c0 = (t & 127) * 8;
  const US* Xb = X + (long long)b * sX + c0;
  const int e0 = rowptr[row], e1 = rowptr[row + 1];
  union U8 { uint4 v; US s[8]; };
  float p0[8] = {0.f, 0.f, 0.f, 0.f, 0.f, 0.f, 0.f, 0.f};
  float p1[8] = {0.f, 0.f, 0.f, 0.f, 0.f, 0.f, 0.f, 0.f};
  int e = e0;
  for (; e + 4 <= e1; e += 4) {
    const int j0 = colidx[e + 0], j1 = colidx[e + 1];
    const int j2 = colidx[e + 2], j3 = colidx[e + 3];
    const float a0 = vals[e + 0], a1 = vals[e + 1];
    const float a2 = vals[e + 2], a3 = vals[e + 3];
    U8 x0, x1, x2, x3;
    x0.v = *(const uint4*)&Xb[(long long)j0 * ldx];
    x1.v = *(const uint4*)&Xb[(long long)j1 * ldx];
    x2.v = *(const uint4*)&Xb[(long long)j2 * ldx];
    x3.v = *(const uint4*)&Xb[(long long)j3 * ldx];
#pragma unroll
    for (int q = 0; q < 8; ++q) {
      p0[q] += a0 * b2f(x0.s[q]) + a2 * b2f(x2.s[q]);
      p1[q] += a1 * b2f(x1.s[q]) + a3 * b2f(x3.s[q]);
    }
  }
  for (; e < e1; ++e) {
    const int j = colidx[e];
    const float a = vals[e];
    U8 xv;
    xv.v = *(const uint4*)&Xb[(long long)j * ldx];
#pragma unroll
    for (int q = 0; q < 8; ++q) p0[q] += a * b2f(xv.s[q]);
  }
  US o[8];
#pragma unroll
  for (int q = 0; q < 8; ++q) o[q] = f2b(p0[q] + p1[q]);
  *(uint4*)&Y[((long long)b * 2048 + row) * 1024 + c0] = *(uint4*)o;
}

// ================= row softmax over cols [0,1024) of x [B][2048][ldx] ========
__global__ __launch_bounds__(256) void rowsm_k(US* __restrict__ x, int ldx,
                                               long long sB) {
  __shared__ float red[256];
  const int bid = blockIdx.x;
  const int b = bid & 7;
  const int row = bid >> 3;
  const int t = threadIdx.x;
  US* p = x + (long long)b * sB + (long long)row * ldx + t * 4;
  union { ushort4 v; US s[4]; } buf;
  buf.v = *(const ushort4*)p;
  float v[4];
#pragma unroll
  for (int i = 0; i < 4; ++i) v[i] = b2f(buf.s[i]);
  float mx = fmaxf(fmaxf(v[0], v[1]), fmaxf(v[2], v[3]));
  red[t] = mx;
  __syncthreads();
  for (int s = 128; s; s >>= 1) {
    if (t < s) red[t] = fmaxf(red[t], red[t + s]);
    __syncthreads();
  }
  mx = red[0];
  __syncthreads();
  float sum = 0.f;
#pragma unroll
  for (int i = 0; i < 4; ++i) {
    v[i] = __expf(v[i] - mx);
    sum += v[i];
  }
  red[t] = sum;
  __syncthreads();
  for (int s = 128; s; s >>= 1) {
    if (t < s) red[t] += red[t + s];
    __syncthreads();
  }
  const float inv = 1.0f / red[0];
#pragma unroll
  for (int i = 0; i < 4; ++i) buf.s[i] = f2b(v[i] * inv);
  *(ushort4*)p = buf.v;
}

// ---------------- split column softmax over R of x [B][R][C] (stage 2) -------
template <int RPT>
__global__ __launch_bounds__(256) void sm_partial_k(
    const US* __restrict__ x, float* __restrict__ pm, float* __restrict__ ps,
    int R, int C, long long sB, int NS) {
  const int b = blockIdx.y, blk = blockIdx.x;
  const int cpr = C >> 3;
  const int t = threadIdx.x;
  const int cslot = t & (cpr - 1);
  const int rsub = t / cpr;
  const int nsub = 256 / cpr;
  const int rowsPerBlock = R / NS;
  const int r0 = blk * rowsPerBlock + rsub * RPT;
  const US* p = x + (long long)b * sB + (long long)r0 * C + cslot * 8;
  union { uint4 v; US s[8]; } buf[RPT];
#pragma unroll
  for (int i = 0; i < RPT; ++i) buf[i].v = *(const uint4*)(p + (long long)i * C);
  float M[8], S[8];
#pragma unroll
  for (int j = 0; j < 8; ++j) M[j] = b2f(buf[0].s[j]);
#pragma unroll
  for (int i = 1; i < RPT; ++i)
#pragma unroll
    for (int j = 0; j < 8; ++j) M[j] = fmaxf(M[j], b2f(buf[i].s[j]));
#pragma unroll
  for (int j = 0; j < 8; ++j) S[j] = 0.f;
#pragma unroll
  for (int i = 0; i < RPT; ++i)
#pragma unroll
    for (int j = 0; j < 8; ++j) S[j] += __expf(b2f(buf[i].s[j]) - M[j]);
  const long long pi = (long long)(b * NS + blk) * nsub + rsub;
  float* pmo = pm + pi * C + cslot * 8;
  float* pso = ps + pi * C + cslot * 8;
  *(float4*)pmo = make_float4(M[0], M[1], M[2], M[3]);
  *(float4*)(pmo + 4) = make_float4(M[4], M[5], M[6], M[7]);
  *(float4*)pso = make_float4(S[0], S[1], S[2], S[3]);
  *(float4*)(pso + 4) = make_float4(S[4], S[5], S[6], S[7]);
}

__global__ __launch_bounds__(256) void sm_combine_k(
    const float* __restrict__ pm, const float* __restrict__ ps,
    float* __restrict__ Mf, float* __restrict__ Sinv, int C, int NP) {
  const int b = blockIdx.x, t = threadIdx.x;
  const int cpr = C >> 3;
  if (t >= cpr) return;
  const int c = t * 8;
  const float* pmB = pm + (long long)b * NP * C + c;
  const float* psB = ps + (long long)b * NP * C + c;
  float M[8], S[8];
#pragma unroll
  for (int j = 0; j < 8; ++j) { M[j] = pmB[j]; S[j] = psB[j]; }
  for (int e = 1; e < NP; ++e) {
    const float* pme = pmB + (long long)e * C;
    const float* pse = psB + (long long)e * C;
#pragma unroll
    for (int j = 0; j < 8; ++j) {
      const float m2 = pme[j], s2 = pse[j];
      const float nm = fmaxf(M[j], m2);
      S[j] = S[j] * __expf(M[j] - nm) + s2 * __expf(m2 - nm);
      M[j] = nm;
    }
  }
#pragma unroll
  for (int j = 0; j < 8; ++j) {
    Mf[(long long)b * C + c + j] = M[j];
    Sinv[(long long)b * C + c + j] = 1.0f / S[j];
  }
}

template <int RPT>
__global__ __launch_bounds__(256) void sm_norm_k(
    US* __restrict__ x, const float* __restrict__ Mf,
    const float* __restrict__ Sinv, int R, int C, long long sB, int NS) {
  const int b = blockIdx.y, blk = blockIdx.x;
  const int cpr = C >> 3;
  const int t = threadIdx.x;
  const int cslot = t & (cpr - 1);
  const int rsub = t / cpr;
  const int rowsPerBlock = R / NS;
  const int r0 = blk * rowsPerBlock + rsub * RPT;
  US* p = x + (long long)b * sB + (long long)r0 * C + cslot * 8;
  float M[8], Si[8];
#pragma unroll
  for (int j = 0; j < 8; ++j) {
    M[j] = Mf[(long long)b * C + cslot * 8 + j];
    Si[j] = Sinv[(long long)b * C + cslot * 8 + j];
  }
#pragma unroll
  for (int i = 0; i < RPT; ++i) {
    union { uint4 v; US s[8]; } buf;
    buf.v = *(const uint4*)(p + (long long)i * C);
#pragma unroll
    for (int j = 0; j < 8; ++j)
      buf.s[j] = f2b(__expf(b2f(buf.s[j]) - M[j]) * Si[j]);
    *(uint4*)(p + (long long)i * C) = buf.v;
  }
}

// ---------------- bf16 transpose: src [B][R][C] -> dst [B][C][R] -------------
__global__ __launch_bounds__(256) void transb_k(const US* __restrict__ src,
                                                US* __restrict__ dst, int R,
                                                int C, long long sIn,
                                                long long sOut) {
  __shared__ US L[64][65];
  const int b = blockIdx.z;
  const int r0 = blockIdx.y * 64, c0 = blockIdx.x * 64;
  const int t = threadIdx.x;
  const int lr = t >> 4, lc = (t & 15) * 4;
  const US* s = src + (long long)b * sIn;
#pragma unroll
  for (int i = 0; i < 4; ++i) {
    const int rr = r0 + lr + 16 * i;
    const ushort4 v = *(const ushort4*)&s[(long long)rr * C + c0 + lc];
    L[lr + 16 * i][lc + 0] = v.x;
    L[lr + 16 * i][lc + 1] = v.y;
    L[lr + 16 * i][lc + 2] = v.z;
    L[lr + 16 * i][lc + 3] = v.w;
  }
  __syncthreads();
#pragma unroll
  for (int i = 0; i < 4; ++i) {
    ushort4 o;
    o.x = L[lc + 0][lr + 16 * i];
    o.y = L[lc + 1][lr + 16 * i];
    o.z = L[lc + 2][lr + 16 * i];
    o.w = L[lc + 3][lr + 16 * i];
    *(ushort4*)&dst[(long long)b * sOut + (long long)(c0 + lr + 16 * i) * R + r0 + lc] = o;
  }
}

// ---------------- fused weight transposes ----------------
struct WT { const float* src; US* dst; int R, C, tileOff; };
struct WTab { WT e[11]; };

__global__ __launch_bounds__(256) void wtrans_k(WTab tab) {
  __shared__ US L[64][65];
  const int tile = blockIdx.x;
  int i = 0;
#pragma unroll
  for (int j = 1; j < 11; ++j)
    if (tab.e[j].tileOff <= tile) i = j;
  const WT w = tab.e[i];
  const int lt = tile - w.tileOff;
  const int tc = w.C / 64;
  const int r0 = (lt / tc) * 64, c0 = (lt % tc) * 64;
  const int t = threadIdx.x;
  const int lr = t >> 4, lc = (t & 15) * 4;
#pragma unroll
  for (int k = 0; k < 4; ++k) {
    const int rr = r0 + lr + 16 * k;
    const float4 v = *(const float4*)&w.src[(long long)rr * w.C + c0 + lc];
    L[lr + 16 * k][lc + 0] = f2b(v.x);
    L[lr + 16 * k][lc + 1] = f2b(v.y);
    L[lr + 16 * k][lc + 2] = f2b(v.z);
    L[lr + 16 * k][lc + 3] = f2b(v.w);
  }
  __syncthreads();
#pragma unroll
  for (int k = 0; k < 4; ++k) {
    ushort4 o;
    o.x = L[lc + 0][lr + 16 * k];
    o.y = L[lc + 1][lr + 16 * k];
    o.z = L[lc + 2][lr + 16 * k];
    o.w = L[lc + 3][lr + 16 * k];
    *(ushort4*)&w.dst[(long long)(c0 + lr + 16 * k) * w.R + r0 + lc] = o;
  }
}

// ---------------- reparameterize ----------------
__global__ __launch_bounds__(256) void reparam_k(
    const float* __restrict__ h3, const float* __restrict__ eps,
    float* __restrict__ om, float* __restrict__ olv, US* __restrict__ z,
    int total) {
  const int i = blockIdx.x * 256 + threadIdx.x;
  if (i >= total) return;
  const int j = i & 63;
  const long long r = i >> 6;
  const float m = h3[r * 128 + j];
  const float lv = h3[r * 128 + 64 + j];
  om[i] = m;
  olv[i] = lv;
  z[i] = f2b(m + expf(0.5f * lv) * eps[i]);
}

// ---------------- host dispatch ----------------
static void mm(hipStream_t st, const US* A, const US* B, const float* bias,
               void* C, void* C2, int M, int N, int K, int lda, long long sA,
               long long sB, long long sC, long long sC2, int act, int outm,
               int tn) {
  const int gx = N / tn, gy = M / 128;
  dim3 g(gx * gy * BATCH), blk(256);
#define L(TN, ACT, OUT, HB) \
  mm_k<TN, ACT, OUT, HB><<<g, blk, 0, st>>>(A, B, bias, C, C2, M, N, K, lda, sA, sB, sC, sC2, gx, gy)
  if (tn == 64) {
    if (outm == 0) L(64, 0, 0, false);
    else if (outm == 1) L(64, 0, 1, false);
    else L(64, 2, 2, true);
  } else {
    if (outm == 0) {
      if (act == 1) L(128, 1, 0, true);
      else L(128, 0, 0, false);
    } else if (outm == 1) {
      if (act == 1) L(128, 1, 1, true);
      else L(128, 0, 1, false);
    } else if (outm == 2) L(128, 0, 2, true);
    else L(128, 0, 3, false);
  }
#undef L
}

static void mm256(hipStream_t st, const US* A, const US* B, void* C, void* C2,
                  int M, int N, int K, int lda, long long sA, long long sB,
                  long long sC, long long sC2, int outm) {
  const int gx = N / 256, gy = M / 256;
  dim3 g(gx * gy * BATCH), blk(512);
  if (outm == 0)
    mm256_k<0><<<g, blk, 0, st>>>(A, B, C, C2, M, N, K, lda, sA, sB, sC, sC2, gx, gy);
  else if (outm == 1)
    mm256_k<1><<<g, blk, 0, st>>>(A, B, C, C2, M, N, K, lda, sA, sB, sC, sC2, gx, gy);
  else
    mm256_k<3><<<g, blk, 0, st>>>(A, B, C, C2, M, N, K, lda, sA, sB, sC, sC2, gx, gy);
}

static void mm64(hipStream_t st, const US* A, const US* B, const float* bias,
                 void* C, int M, int N, int K, int lda, long long sA,
                 long long sB, long long sC, int act, int outm) {
  const int gx = N / 64, gy = M / 64;
  dim3 g(gx * gy * BATCH), blk(256);
  if (outm == 0)
    mm64_k<0, 0, false><<<g, blk, 0, st>>>(A, B, nullptr, C, M, N, K, lda, sA, sB, sC, gx, gy);
  else if (outm == 1)
    mm64_k<0, 1, false><<<g, blk, 0, st>>>(A, B, nullptr, C, M, N, K, lda, sA, sB, sC, gx, gy);
  else
    mm64_k<2, 2, true><<<g, blk, 0, st>>>(A, B, bias, C, M, N, K, lda, sA, sB, sC, gx, gy);
}

extern "C" void kernel_launch(void* const* d_in, const int* in_sizes, int n_in,
                              void* d_out, int out_size, void* d_ws, size_t ws_size,
                              hipStream_t stream) {
  const float* x      = (const float*)d_in[0];
  const float* eps    = (const float*)d_in[1];
  const float* adj    = (const float*)d_in[2];
  const float* We1    = (const float*)d_in[3];
  const float* be1    = (const float*)d_in[4];
  const float* Kemb1  = (const float*)d_in[5];
  const float* Kpool1 = (const float*)d_in[6];
  const float* We2    = (const float*)d_in[7];
  const float* be2    = (const float*)d_in[8];
  const float* Kemb2  = (const float*)d_in[9];
  const float* Kpool2 = (const float*)d_in[10];
  const float* We3    = (const float*)d_in[11];
  const float* be3    = (const float*)d_in[12];
  const float* Wd0    = (const float*)d_in[13];
  const float* bd0    = (const float*)d_in[14];
  const float* Wd1    = (const float*)d_in[15];
  const float* bd1    = (const float*)d_in[16];
  const float* Wd2    = (const float*)d_in[17];
  const float* bd2    = (const float*)d_in[18];
  const float* Wdf    = (const float*)d_in[19];
  const float* bdf    = (const float*)d_in[20];
  (void)in_sizes; (void)n_in; (void)ws_size; (void)out_size;

  float* out = (float*)d_out;
  float* out_mean = out + (long long)8 * 2048 * 64;
  float* out_lv = out_mean + (long long)8 * 512 * 64;

  char* base = (char*)d_ws;
  size_t off = 0;
  auto alloc = [&](size_t bytes) {
    char* p = base + off;
    off += (bytes + 255) & ~(size_t)255;
    return p;
  };
  US* Y0   = (US*)alloc(8LL * 2048 * 64 * 2);
  US* h1b  = (US*)alloc(8LL * 2048 * 256 * 2);   // h1 natural [2048][256]
  US* g1   = (US*)alloc(8LL * 2048 * 256 * 2);
  // R1n [8][2048][1280] natural [s1|z1] — dead after transb+spmm1024; its
  // 41,943,040 B are overlaid with pm/ps (stage-2 softmax) + decode temps.
  US* R1n  = (US*)alloc(8LL * 2048 * 1280 * 2);
  float* pm = (float*)R1n;                         //  8 MB
  float* ps = pm + 8LL * 128 * 2048;               //  8 MB
  US* d4    = (US*)(ps + 8LL * 128 * 2048);        //  8 MB [8][2048][256]
  US* t5T   = d4 + 8LL * 2048 * 256;               //  4 MB
  US* d2    = t5T + 8LL * 256 * 1024;              //  4 MB
  US* t3T   = d2 + 8LL * 1024 * 256;               //  2 MB
  US* t4T   = t3T + 8LL * 256 * 512;               //  2 MB
  US* d0    = t4T + 8LL * 256 * 512;               //  2 MB
  US* t6    = d0 + 8LL * 512 * 256;                //  2 MB  (sum = 41,943,040)
  US* R1   = (US*)alloc(8LL * 2304 * 2048 * 2);  // rows [s1T|z1T|AS1T]
  US* AS1  = (US*)alloc(8LL * 2048 * 1024 * 2);
  US* P1o  = (US*)alloc(8LL * 1024 * 1280 * 2);
  US* t1T  = (US*)alloc(8LL * 256 * 1024 * 2);
  US* h2T  = (US*)alloc(8LL * 256 * 1024 * 2);
  US* g2   = (US*)alloc(8LL * 1024 * 256 * 2);
  US* R2   = (US*)alloc(8LL * 1280 * 1024 * 2);
  US* AS2  = (US*)alloc(8LL * 1024 * 512 * 2);
  US* P2o  = (US*)alloc(8LL * 512 * 768 * 2);
  US* t2T  = (US*)alloc(8LL * 128 * 512 * 2);
  float* h3f = (float*)alloc(8LL * 512 * 128 * 4);
  US* zlb  = (US*)alloc(8LL * 512 * 64 * 2);
  float* Mf   = (float*)alloc(8LL * 2048 * 4);
  float* Sinv = (float*)alloc(8LL * 2048 * 4);
  int* rowcnt = (int*)alloc(2048 * 4);
  int* rowptr = (int*)alloc(2049 * 4);
  int* colidx = (int*)alloc(2048LL * 256 * 4);
  float* vals = (float*)alloc(2048LL * 256 * 4);
  US* We1T  = (US*)alloc(256 * 64 * 2);
  US* KpKe1 = (US*)alloc(1280 * 256 * 2);
  US* We2T  = (US*)alloc(256 * 256 * 2);
  US* KpKe2 = (US*)alloc(768 * 256 * 2);
  US* We3T  = (US*)alloc(128 * 256 * 2);
  US* Wd0T  = (US*)alloc(256 * 64 * 2);
  US* Wd1T  = (US*)alloc(256 * 256 * 2);
  US* Wd2T  = (US*)alloc(256 * 256 * 2);
  US* WdfT  = (US*)alloc(64 * 256 * 2);

  // ---- weight conversions + CSR build ----
  {
    WTab tab;
    int toff = 0, i = 0;
    auto add = [&](const float* s, US* d, int R, int C) {
      tab.e[i++] = WT{s, d, R, C, toff};
      toff += (R / 64) * (C / 64);
    };
    add(We1, We1T, 64, 256);
    add(Kpool1, KpKe1, 256, 1024);
    add(Kemb1, KpKe1 + 1024 * 256, 256, 256);
    add(We2, We2T, 256, 256);
    add(Kpool2, KpKe2, 256, 512);
    add(Kemb2, KpKe2 + 512 * 256, 256, 256);
    add(We3, We3T, 256, 128);
    add(Wd0, Wd0T, 64, 256);
    add(Wd1, Wd1T, 256, 256);
    add(Wd2, Wd2T, 256, 256);
    add(Wdf, WdfT, 256, 64);
    wtrans_k<<<dim3(toff), dim3(256), 0, stream>>>(tab);
  }
  csr_count_k<<<dim3(2048), dim3(256), 0, stream>>>(adj, rowcnt);
  csr_scan_k<<<dim3(1), dim3(256), 0, stream>>>(rowcnt, rowptr);
  csr_fill_k<<<dim3(2048), dim3(256), 0, stream>>>(adj, rowptr, colidx, vals);

  const long long SR1 = 2304LL * 2048, SR2 = 1280LL * 1024;
  const long long SR1n = 2048LL * 1280;
  US* s1T  = R1;
  US* B1   = R1 + 1024 * 2048;           // rows [z1T(256) | AS1T(1024)]
  US* AS1T = R1 + 1280 * 2048;
  US* s2T  = R2;
  US* B2   = R2 + 512 * 1024;
  US* AS2T = R2 + 768 * 1024;
  US* A1c  = P1o + 256;
  US* A2c  = P2o + 256;

  // ---------------- encode ----------------
  // Y0 = adj @ x  (SpMM from f32 x)
  spmm_k<64, true, 0, false, false><<<dim3(2048), dim3(256), 0, stream>>>(
      rowptr, colidx, vals, x, nullptr, Y0);
  // h1 = relu(Y0@We1+b)
  mm(stream, Y0, We1T, be1, h1b, nullptr, 2048, 256, 64, 64, 2048LL * 64, 0,
     2048LL * 256, 0, 1, 0, 128);
  // g1 = adj @ h1  (SpMM)
  spmm_k<256, false, 0, false, false><<<dim3(2048), dim3(256), 0, stream>>>(
      rowptr, colidx, vals, h1b, nullptr, g1);
  // R1n = g1 @ [Kp1|Ke1]  (natural [2048][1280]: cols [s1 logits | z1])
  mm256(stream, g1, KpKe1, R1n, nullptr, 2048, 1280, 256, 256, 2048LL * 256, 0,
        SR1n, 0, 0);
  // row softmax over s1 logits (cols 0..1024)
  rowsm_k<<<dim3(16384), dim3(256), 0, stream>>>(R1n, 1280, SR1n);
  // R1 = R1n^T  ([1280][2048]: rows [s1T | z1T])
  transb_k<<<dim3(20, 32, 8), dim3(256), 0, stream>>>(R1n, R1, 2048, 1280,
                                                      SR1n, SR1);
  // AS1 = adj @ s1  (SpMM wide, 16B gathers, 4-way ILP)
  spmm1024_k<<<dim3(8192), dim3(256), 0, stream>>>(rowptr, colidx, vals, R1n,
                                                   1280, SR1n, AS1);
  // AS1T into B1 region  (R1n now dead — overlay region reusable)
  transb_k<<<dim3(16, 32, 8), dim3(256), 0, stream>>>(AS1, AS1T, 2048, 1024,
                                                      2048LL * 1024, SR1);
  // P1 = s1^T @ [z1 | AS1] -> [xp1 | A1]   (256^2)
  mm256(stream, s1T, B1, P1o, nullptr, 1024, 1280, 2048, 2048, SR1, SR1,
        1024LL * 1280, 0, 0);
  mm(stream, P1o, We2T, nullptr, t1T, nullptr, 1024, 256, 256, 1280, 1024LL * 1280,
     0, 0, 256LL * 1024, 0, 1, 128);
  mm(stream, A1c, t1T, be2, h2T, nullptr, 1024, 256, 1024, 1280, 1024LL * 1280,
     256LL * 1024, 0, 256LL * 1024, 1, 1, 128);
  mm(stream, A1c, h2T, nullptr, g2, nullptr, 1024, 256, 1024, 1280, 1024LL * 1280,
     256LL * 1024, 1024LL * 256, 0, 0, 0, 128);
  mm(stream, g2, KpKe2, nullptr, R2, nullptr, 1024, 768, 256, 256, 1024LL * 256,
     0, 0, SR2, 0, 1, 128);
  sm_partial_k<4><<<dim3(64, 8), dim3(256), 0, stream>>>(s2T, pm, ps, 512, 1024, SR2, 64);
  sm_combine_k<<<dim3(8), dim3(256), 0, stream>>>(pm, ps, Mf, Sinv, 1024, 128);
  sm_norm_k<4><<<dim3(64, 8), dim3(256), 0, stream>>>(s2T, Mf, Sinv, 512, 1024, SR2, 64);
  mm(stream, A1c, s2T, nullptr, AS2, AS2T, 1024, 512, 1024, 1280, 1024LL * 1280,
     SR2, 1024LL * 512, SR2, 0, 3, 128);
  mm(stream, s2T, B2, nullptr, P2o, nullptr, 512, 768, 1024, 1024, SR2, SR2,
     512LL * 768, 0, 0, 0, 128);
  mm(stream, P2o, We3T, nullptr, t2T, nullptr, 512, 128, 256, 768, 512LL * 768,
     0, 0, 128LL * 512, 0, 1, 128);
  mm(stream, A2c, t2T, be3, h3f, nullptr, 512, 128, 512, 768, 512LL * 768,
     128LL * 512, 512LL * 128, 0, 0, 2, 128);
  reparam_k<<<dim3(8 * 512 * 64 / 256), dim3(256), 0, stream>>>(h3f, eps, out_mean,
                                                                out_lv, zlb, 8 * 512 * 64);

  // ---------------- decode ----------------
  mm(stream, zlb, Wd0T, nullptr, t3T, nullptr, 512, 256, 64, 64, 512LL * 64, 0, 0,
     256LL * 512, 0, 1, 128);
  mm(stream, A2c, t3T, bd0, d0, nullptr, 512, 256, 512, 768, 512LL * 768,
     256LL * 512, 512LL * 256, 0, 1, 0, 128);
  mm(stream, d0, Wd1T, nullptr, t4T, nullptr, 512, 256, 256, 256, 512LL * 256, 0,
     0, 256LL * 512, 0, 1, 128);
  mm(stream, AS2, t4T, bd1, d2, nullptr, 1024, 256, 512, 512, 1024LL * 512,
     256LL * 512, 1024LL * 256, 0, 1, 0, 128);
  mm(stream, d2, Wd2T, nullptr, t5T, nullptr, 1024, 256, 256, 256, 1024LL * 256, 0,
     0, 256LL * 1024, 0, 1, 128);
  mm(stream, AS1, t5T, bd2, d4, nullptr, 2048, 256, 1024, 1024, 2048LL * 1024,
     256LL * 1024, 2048LL * 256, 0, 1, 0, 128);
  mm64(stream, d4, WdfT, nullptr, t6, 2048, 64, 256, 256, 2048LL * 256, 0,
       2048LL * 64, 0, 0);
  spmm_k<64, false, 2, true, true><<<dim3(2048), dim3(256), 0, stream>>>(
      rowptr, colidx, vals, t6, bdf, out);
}

// Round 18
// 623.488 us; speedup vs baseline: 1.1556x; 1.0003x over previous
//
#include <hip/hip_runtime.h>
#include <math.h>

#define BATCH 8
typedef unsigned short US;

typedef __attribute__((ext_vector_type(8))) short short8;
typedef __attribute__((ext_vector_type(4))) float f32x4;

__device__ __forceinline__ US f2b(float f) {
  union { float f; unsigned u; } v; v.f = f;
  unsigned r = v.u + 0x7fffu + ((v.u >> 16) & 1u);
  return (US)(r >> 16);
}
__device__ __forceinline__ float b2f(US h) {
  union { unsigned u; float f; } v; v.u = ((unsigned)h) << 16;
  return v.f;
}

__device__ __forceinline__ void gload16(const US* g, US* l) {
  __builtin_amdgcn_global_load_lds(
      (const __attribute__((address_space(1))) unsigned int*)g,
      (__attribute__((address_space(3))) unsigned int*)l, 16, 0, 0);
}

// LDS tile [rows][64] linear, XOR swizzle: 16B-cell index ^= (row&7).
__device__ __forceinline__ int lidx2(int r, int ko) {
  return r * 64 + ((((ko >> 3) ^ (r & 7)) << 3));
}

// ================= 128^2 1-phase MFMA GEMM (verified r3-r7) ==================
// C = act(A@B + bias). A bf16 phys [M][lda], B bf16 phys [N][K].
// OUT: 0=bf16 [M][N], 1=bf16 [N][M], 2=f32 [M][N], 3=dual bf16 [M][N]+[N][M].
template <int TN, int ACT, int OUT, bool HASBIAS>
__global__ __launch_bounds__(256) void mm_k(
    const US* __restrict__ A, const US* __restrict__ B,
    const float* __restrict__ bias, void* __restrict__ Cv, void* __restrict__ Cv2,
    int M, int N, int K, int lda, long long sA, long long sB, long long sC,
    long long sC2, int gx, int gy) {
  constexpr int JF = TN / 32;
  __shared__ US As[128 * 64];
  __shared__ US Bs[TN * 64];

  const int nb = blockIdx.x;
  const int nb2 = (nb & 7) * (gx * gy) + (nb >> 3);
  const int bx = nb2 % gx;
  const int by = (nb2 / gx) % gy;
  const int b = nb2 / (gx * gy);

  A += (long long)b * sA;
  B += (long long)b * sB;
  const int m0 = by * 128, n0 = bx * TN;
  const int t = threadIdx.x, lane = t & 63, w = t >> 6;
  const int wm = (w >> 1) * 64, wn = (w & 1) * (TN / 2);
  const int l15 = lane & 15, lg = lane >> 4;
  const int lrow = lane >> 3;
  const int gcell = (((lane & 7) ^ lrow) << 3);

  f32x4 acc[4][JF];
#pragma unroll
  for (int i = 0; i < 4; ++i)
#pragma unroll
    for (int j = 0; j < JF; ++j) acc[i][j] = (f32x4){0.f, 0.f, 0.f, 0.f};

  for (int k0 = 0; k0 < K; k0 += 64) {
#pragma unroll
    for (int i = 0; i < 4; ++i) {
      const int g = w * 4 + i;
      gload16(A + (long long)(m0 + g * 8 + lrow) * lda + k0 + gcell, &As[g * 512]);
    }
#pragma unroll
    for (int i = 0; i < TN / 32; ++i) {
      const int g = w * (TN / 32) + i;
      gload16(B + (long long)(n0 + g * 8 + lrow) * K + k0 + gcell, &Bs[g * 512]);
    }
    __syncthreads();

#pragma unroll
    for (int kk = 0; kk < 2; ++kk) {
      const int ko = kk * 32 + lg * 8;
      short8 af[4], bf[JF];
#pragma unroll
      for (int i = 0; i < 4; ++i)
        af[i] = *(const short8*)&As[lidx2(wm + i * 16 + l15, ko)];
#pragma unroll
      for (int j = 0; j < JF; ++j)
        bf[j] = *(const short8*)&Bs[lidx2(wn + j * 16 + l15, ko)];
#pragma unroll
      for (int i = 0; i < 4; ++i)
#pragma unroll
        for (int j = 0; j < JF; ++j)
          acc[i][j] = __builtin_amdgcn_mfma_f32_16x16x32_bf16(af[i], bf[j],
                                                              acc[i][j], 0, 0, 0);
    }
    __syncthreads();
  }

  const long long cb = (long long)b * sC;
  const long long cb2 = (long long)b * sC2;
#pragma unroll
  for (int fj = 0; fj < JF; ++fj) {
    const int col = n0 + wn + fj * 16 + l15;
    const float bsv = HASBIAS ? bias[col] : 0.0f;
#pragma unroll
    for (int fi = 0; fi < 4; ++fi) {
      const int row0 = m0 + wm + fi * 16 + lg * 4;
      float v[4];
#pragma unroll
      for (int e = 0; e < 4; ++e) {
        float x = acc[fi][fj][e] + bsv;
        if (ACT == 1) x = fmaxf(x, 0.0f);
        if (ACT == 2) x = (x > 20.0f) ? x : log1pf(expf(x));
        v[e] = x;
      }
      if (OUT == 1 || OUT == 3) {
        ushort4 pk;
        pk.x = f2b(v[0]); pk.y = f2b(v[1]); pk.z = f2b(v[2]); pk.w = f2b(v[3]);
        US* c2 = (OUT == 3) ? (US*)Cv2 : (US*)Cv;
        *(ushort4*)&c2[cb2 + (long long)col * M + row0] = pk;
      }
      if (OUT == 0 || OUT == 3) {
#pragma unroll
        for (int e = 0; e < 4; ++e)
          ((US*)Cv)[cb + (long long)(row0 + e) * N + col] = f2b(v[e]);
      }
      if (OUT == 2) {
#pragma unroll
        for (int e = 0; e < 4; ++e)
          ((float*)Cv)[cb + (long long)(row0 + e) * N + col] = v[e];
      }
    }
  }
}

// ================= 256^2 deep-pipelined MFMA GEMM (r7-exact) =================
template <int OUT>
__global__ __launch_bounds__(512, 1) void mm256_k(
    const US* __restrict__ A, const US* __restrict__ B, void* __restrict__ Cv,
    void* __restrict__ Cv2, int M, int N, int K, int lda, long long sA,
    long long sB, long long sC, long long sC2, int gx, int gy) {
  __shared__ US lds[8][8192];

  const int nb = blockIdx.x;
  const int chunk = gx * gy;
  const int nb2 = (nb & 7) * chunk + (nb >> 3);
  const int bx = nb2 % gx;
  const int by = (nb2 / gx) % gy;
  const int b = nb2 / chunk;

  const int m0 = by * 256, n0 = bx * 256;
  const int tid = threadIdx.x;
  const int lane = tid & 63, w = tid >> 6;
  const int wr = w >> 2, wc = w & 3;
  const int l15 = lane & 15, lg = lane >> 4;

  const US* Ab = A + (long long)b * sA + (long long)m0 * lda;
  const US* Bb = B + (long long)b * sB + (long long)n0 * K;
  const int NT = K >> 6;

  auto stageH = [&](int H) {
    const int s = H >> 2, h = H & 3;
    const int ab = h & 1, kk = h >> 1;
    US* reg = &lds[ab * 4 + (s & 1) * 2 + kk][0];
    const US* src = ab ? Bb : Ab;
    const int ld = ab ? K : lda;
#pragma unroll
    for (int i = 0; i < 2; ++i) {
      const int rbase = (w * 2 + i) * 16;
      const int r = rbase + (lane >> 2);
      const int csrc = (lane & 3) ^ ((r >> 1) & 3);
      gload16(src + (long long)r * ld + s * 64 + kk * 32 + csrc * 8,
              reg + rbase * 32);
    }
  };

  f32x4 acc[8][4];
#pragma unroll
  for (int m = 0; m < 8; ++m)
#pragma unroll
    for (int j = 0; j < 4; ++j) acc[m][j] = (f32x4){0.f, 0.f, 0.f, 0.f};
  short8 a4[4], b4[4];

  for (int H = 0; H < 6; ++H) stageH(H);
  asm volatile("s_waitcnt vmcnt(4)" ::: "memory");
  __builtin_amdgcn_s_barrier();

#define PH(kk_, mh_, DOH, HV, VM, tt)                                          \
  {                                                                            \
    const US* Ar = &lds[((tt) & 1) * 2 + (kk_)][0];                            \
    const US* Br = &lds[4 + ((tt) & 1) * 2 + (kk_)][0];                        \
    _Pragma("unroll") for (int i = 0; i < 4; ++i) {                            \
      const int r = wr * 128 + (mh_) * 64 + i * 16 + l15;                      \
      a4[i] = *(const short8*)&Ar[r * 32 + ((lg ^ ((r >> 1) & 3)) << 3)];      \
    }                                                                          \
    if ((mh_) == 0) {                                                          \
      _Pragma("unroll") for (int j = 0; j < 4; ++j) {                          \
        const int rr = wc * 64 + j * 16 + l15;                                 \
        b4[j] = *(const short8*)&Br[rr * 32 + ((lg ^ ((rr >> 1) & 3)) << 3)];  \
      }                                                                        \
    }                                                                          \
    if (DOH) stageH(HV);                                                       \
    if ((VM) == 1) asm volatile("s_waitcnt vmcnt(4)" ::: "memory");            \
    if ((VM) == 2) asm volatile("s_waitcnt vmcnt(0)" ::: "memory");            \
    __builtin_amdgcn_s_barrier();                                              \
    __builtin_amdgcn_s_setprio(1);                                             \
    _Pragma("unroll") for (int i = 0; i < 4; ++i)                              \
      _Pragma("unroll") for (int j = 0; j < 4; ++j)                            \
        acc[(mh_) * 4 + i][j] = __builtin_amdgcn_mfma_f32_16x16x32_bf16(       \
            a4[i], b4[j], acc[(mh_) * 4 + i][j], 0, 0, 0);                     \
    __builtin_amdgcn_s_setprio(0);                                             \
    __builtin_amdgcn_s_barrier();                                              \
  }

  int t2 = 0;
  for (; t2 < NT - 2; ++t2) {
    PH(0, 0, true, 4 * t2 + 6, 0, t2)
    PH(0, 1, true, 4 * t2 + 7, 0, t2)
    PH(1, 0, true, 4 * t2 + 8, 0, t2)
    PH(1, 1, true, 4 * t2 + 9, 1, t2)
  }
  PH(0, 0, true, 4 * (NT - 2) + 6, 0, NT - 2)
  PH(0, 1, true, 4 * (NT - 2) + 7, 0, NT - 2)
  PH(1, 0, false, 0, 0, NT - 2)
  PH(1, 1, false, 0, 2, NT - 2)
  PH(0, 0, false, 0, 0, NT - 1)
  PH(0, 1, false, 0, 0, NT - 1)
  PH(1, 0, false, 0, 0, NT - 1)
  PH(1, 1, false, 0, 0, NT - 1)
#undef PH

  const long long cb = (long long)b * sC;
  const long long cb2 = (long long)b * sC2;
#pragma unroll
  for (int j = 0; j < 4; ++j) {
    const int col = n0 + wc * 64 + j * 16 + l15;
#pragma unroll
    for (int m = 0; m < 8; ++m) {
      const int row0 = m0 + wr * 128 + m * 16 + lg * 4;
      if (OUT == 1 || OUT == 3) {
        ushort4 pk;
        pk.x = f2b(acc[m][j][0]); pk.y = f2b(acc[m][j][1]);
        pk.z = f2b(acc[m][j][2]); pk.w = f2b(acc[m][j][3]);
        US* c2 = (OUT == 3) ? (US*)Cv2 : (US*)Cv;
        *(ushort4*)&c2[cb2 + (long long)col * M + row0] = pk;
      }
      if (OUT == 0 || OUT == 3) {
#pragma unroll
        for (int e = 0; e < 4; ++e)
          ((US*)Cv)[cb + (long long)(row0 + e) * N + col] = f2b(acc[m][j][e]);
      }
    }
  }
}

// ================= 64x64 4-deep pipelined MFMA GEMM (skinny N) ===============
template <int ACT, int OUT, bool HASBIAS>
__global__ __launch_bounds__(256) void mm64_k(
    const US* __restrict__ A, const US* __restrict__ B,
    const float* __restrict__ bias, void* __restrict__ Cv,
    int M, int N, int K, int lda, long long sA, long long sB, long long sC,
    int gx, int gy) {
  __shared__ US As[4][4096];
  __shared__ US Bs[4][4096];

  const int nb = blockIdx.x;
  const int chunk = gx * gy;
  const int nb2 = (nb & 7) * chunk + (nb >> 3);
  const int bx = nb2 % gx;
  const int by = (nb2 / gx) % gy;
  const int b = nb2 / chunk;

  const int m0 = by * 64, n0 = bx * 64;
  const int tid = threadIdx.x;
  const int lane = tid & 63, w = tid >> 6;
  const int wr = w >> 1, wc = w & 1;
  const int l15 = lane & 15, lg = lane >> 4;
  const int lrow = lane >> 3;
  const int gcell = (((lane & 7) ^ lrow) << 3);

  const US* Ag = A + (long long)b * sA + (long long)m0 * lda;
  const US* Bg = B + (long long)b * sB + (long long)n0 * K;
  const int NT = K >> 6;

  auto stage = [&](int tt) {
    US* Ad = &As[tt & 3][0];
    US* Bd = &Bs[tt & 3][0];
    const int k0 = tt * 64;
#pragma unroll
    for (int i = 0; i < 2; ++i) {
      const int g = w * 2 + i;
      const int r = g * 8 + lrow;
      gload16(Ag + (long long)r * lda + k0 + gcell, Ad + g * 512);
      gload16(Bg + (long long)r * K + k0 + gcell, Bd + g * 512);
    }
  };

  f32x4 acc[2][2];
#pragma unroll
  for (int i = 0; i < 2; ++i)
#pragma unroll
    for (int j = 0; j < 2; ++j) acc[i][j] = (f32x4){0.f, 0.f, 0.f, 0.f};

  for (int i = 0; i < 3 && i < NT; ++i) stage(i);

  for (int t = 0; t < NT; ++t) {
    if (t + 3 < NT) stage(t + 3);
    const int rem = NT - 1 - t;
    if (rem >= 3) asm volatile("s_waitcnt vmcnt(12)" ::: "memory");
    else if (rem == 2) asm volatile("s_waitcnt vmcnt(8)" ::: "memory");
    else if (rem == 1) asm volatile("s_waitcnt vmcnt(4)" ::: "memory");
    else asm volatile("s_waitcnt vmcnt(0)" ::: "memory");
    asm volatile("s_barrier" ::: "memory");
    const US* Ad = &As[t & 3][0];
    const US* Bd = &Bs[t & 3][0];
#pragma unroll
    for (int kk = 0; kk < 2; ++kk) {
      const int ko = kk * 32 + lg * 8;
      short8 af[2], bf[2];
      af[0] = *(const short8*)&Ad[lidx2(wr * 32 + l15, ko)];
      af[1] = *(const short8*)&Ad[lidx2(wr * 32 + 16 + l15, ko)];
      bf[0] = *(const short8*)&Bd[lidx2(wc * 32 + l15, ko)];
      bf[1] = *(const short8*)&Bd[lidx2(wc * 32 + 16 + l15, ko)];
#pragma unroll
      for (int i = 0; i < 2; ++i)
#pragma unroll
        for (int j = 0; j < 2; ++j)
          acc[i][j] = __builtin_amdgcn_mfma_f32_16x16x32_bf16(af[i], bf[j],
                                                              acc[i][j], 0, 0, 0);
    }
    asm volatile("s_barrier" ::: "memory");
  }

  const long long cb = (long long)b * sC;
#pragma unroll
  for (int fj = 0; fj < 2; ++fj) {
    const int col = n0 + wc * 32 + fj * 16 + l15;
    const float bsv = HASBIAS ? bias[col] : 0.0f;
#pragma unroll
    for (int fi = 0; fi < 2; ++fi) {
      const int row0 = m0 + wr * 32 + fi * 16 + lg * 4;
      float v[4];
#pragma unroll
      for (int e = 0; e < 4; ++e) {
        float x = acc[fi][fj][e] + bsv;
        if (ACT == 1) x = fmaxf(x, 0.0f);
        if (ACT == 2) x = (x > 20.0f) ? x : log1pf(expf(x));
        v[e] = x;
      }
      if (OUT == 1) {
        ushort4 pk;
        pk.x = f2b(v[0]); pk.y = f2b(v[1]); pk.z = f2b(v[2]); pk.w = f2b(v[3]);
        *(ushort4*)&((US*)Cv)[cb + (long long)col * M + row0] = pk;
      } else if (OUT == 0) {
#pragma unroll
        for (int e = 0; e < 4; ++e)
          ((US*)Cv)[cb + (long long)(row0 + e) * N + col] = f2b(v[e]);
      } else {
#pragma unroll
        for (int e = 0; e < 4; ++e)
          ((float*)Cv)[cb + (long long)(row0 + e) * N + col] = v[e];
      }
    }
  }
}

// ================= CSR build (deterministic, no global atomics) ==============
__global__ __launch_bounds__(256) void csr_count_k(const float* __restrict__ adj,
                                                   int* __restrict__ rowcnt) {
  const int row = blockIdx.x, t = threadIdx.x;
  const float* p = adj + (long long)row * 2048;
  int c = 0;
  for (int j = t; j < 2048; j += 256) c += (p[j] != 0.0f);
  __shared__ int red[256];
  red[t] = c;
  __syncthreads();
  for (int s = 128; s; s >>= 1) {
    if (t < s) red[t] += red[t + s];
    __syncthreads();
  }
  if (t == 0) rowcnt[row] = red[0];
}

__global__ __launch_bounds__(256) void csr_scan_k(const int* __restrict__ rowcnt,
                                                  int* __restrict__ rowptr) {
  __shared__ int red[256];
  const int t = threadIdx.x;
  int base = 0;
  for (int ch = 0; ch < 8; ++ch) {
    const int v = rowcnt[ch * 256 + t];
    red[t] = v;
    __syncthreads();
    for (int s = 1; s < 256; s <<= 1) {
      const int add = (t >= s) ? red[t - s] : 0;
      __syncthreads();
      red[t] += add;
      __syncthreads();
    }
    rowptr[ch * 256 + t] = base + red[t] - v;
    const int tot = red[255];
    __syncthreads();
    base += tot;
  }
  if (t == 0) rowptr[2048] = base;
}

__global__ __launch_bounds__(256) void csr_fill_k(const float* __restrict__ adj,
                                                  const int* __restrict__ rowptr,
                                                  int* __restrict__ colidx,
                                                  float* __restrict__ vals,
                                                  int* __restrict__ coloff) {
  const int row = blockIdx.x, t = threadIdx.x;
  const float* p = adj + (long long)row * 2048;
  int cnt = 0;
  for (int j = t; j < 2048; j += 256) cnt += (p[j] != 0.0f);
  __shared__ int red[256];
  red[t] = cnt;
  __syncthreads();
  for (int s = 1; s < 256; s <<= 1) {
    const int add = (t >= s) ? red[t - s] : 0;
    __syncthreads();
    red[t] += add;
    __syncthreads();
  }
  int off = rowptr[row] + red[t] - cnt;
  for (int j = t; j < 2048; j += 256) {
    const float a = p[j];
    if (a != 0.0f) {
      colidx[off] = j;
      vals[off] = a;
      coloff[off] = j * 1280;  // pre-scaled element offset for spmm1024 (ldx)
      ++off;
    }
  }
}

// ================= SpMM narrow: Y[b][row][c] = act(sum_j a_rj X[b][j][c]+bias)
template <int COLS, bool INF32, int ACT, bool OUTF32, bool HASBIAS>
__global__ __launch_bounds__(256) void spmm_k(
    const int* __restrict__ rowptr, const int* __restrict__ colidx,
    const float* __restrict__ vals, const void* __restrict__ Xv,
    const float* __restrict__ bias, void* __restrict__ Yv) {
  constexpr int BP = 256 / COLS;
  constexpr int NP = BATCH / BP;
  const int row = blockIdx.x;
  const int t = threadIdx.x;
  const int c = t & (COLS - 1);
  const int bsub = t / COLS;
  const int e0 = rowptr[row], e1 = rowptr[row + 1];
  float acc[NP];
#pragma unroll
  for (int p = 0; p < NP; ++p) acc[p] = 0.0f;
  for (int e = e0; e < e1; ++e) {
    const int j = colidx[e];
    const float a = vals[e];
#pragma unroll
    for (int p = 0; p < NP; ++p) {
      const int b = p * BP + bsub;
      const long long idx = ((long long)b * 2048 + j) * COLS + c;
      const float xv = INF32 ? ((const float*)Xv)[idx] : b2f(((const US*)Xv)[idx]);
      acc[p] += a * xv;
    }
  }
#pragma unroll
  for (int p = 0; p < NP; ++p) {
    const int b = p * BP + bsub;
    float v = acc[p] + (HASBIAS ? bias[c] : 0.0f);
    if (ACT == 2) v = (v > 20.0f) ? v : log1pf(expf(v));
    const long long idx = ((long long)b * 2048 + row) * COLS + c;
    if (OUTF32) ((float*)Yv)[idx] = v;
    else ((US*)Yv)[idx] = f2b(v);
  }
}

// ================= SpMM wide (1024 cols), 16B gathers, 4-way ILP =============
// Y[b][row][0..1024) = sum over nnz of a * X[b][coloff + c]; coloff pre-scaled.
// Grid 8192: b = bid&7 (XCD-local batch), rowpair = bid>>3; 2 rows/block,
// 128 threads/row, 8 cols (16B) per thread. 4-way unroll, 2 accumulator sets.
__global__ __launch_bounds__(256) void spmm1024_k(
    const int* __restrict__ rowptr, const int* __restrict__ coloff,
    const float* __restrict__ vals, const US* __restrict__ X,
    long long sX, US* __restrict__ Y) {
  const int bid = blockIdx.x;
  const int b = bid & 7;
  const int rp = bid >> 3;
  const int t = threadIdx.x;
  const int row = rp * 2 + (t >> 7);
  const int c0 = (t & 127) * 8;
  const US* Xb = X + (long long)b * sX + c0;
  const int e0 = rowptr[row], e1 = rowptr[row + 1];
  union U8 { uint4 v; US s[8]; };
  float p0[8] = {0.f, 0.f, 0.f, 0.f, 0.f, 0.f, 0.f, 0.f};
  float p1[8] = {0.f, 0.f, 0.f, 0.f, 0.f, 0.f, 0.f, 0.f};
  int e = e0;
  for (; e + 4 <= e1; e += 4) {
    const int o0 = coloff[e + 0], o1 = coloff[e + 1];
    const int o2 = coloff[e + 2], o3 = coloff[e + 3];
    const float a0 = vals[e + 0], a1 = vals[e + 1];
    const float a2 = vals[e + 2], a3 = vals[e + 3];
    U8 x0, x1, x2, x3;
    x0.v = *(const uint4*)&Xb[o0];
    x1.v = *(const uint4*)&Xb[o1];
    x2.v = *(const uint4*)&Xb[o2];
    x3.v = *(const uint4*)&Xb[o3];
#pragma unroll
    for (int q = 0; q < 8; ++q) {
      p0[q] += a0 * b2f(x0.s[q]) + a2 * b2f(x2.s[q]);
      p1[q] += a1 * b2f(x1.s[q]) + a3 * b2f(x3.s[q]);
    }
  }
  for (; e < e1; ++e) {
    const int o = coloff[e];
    const float a = vals[e];
    U8 xv;
    xv.v = *(const uint4*)&Xb[o];
#pragma unroll
    for (int q = 0; q < 8; ++q) p0[q] += a * b2f(xv.s[q]);
  }
  US o[8];
#pragma unroll
  for (int q = 0; q < 8; ++q) o[q] = f2b(p0[q] + p1[q]);
  *(uint4*)&Y[((long long)b * 2048 + row) * 1024 + c0] = *(uint4*)o;
}

// ================= row softmax over cols [0,1024) of x [B][2048][ldx] ========
__global__ __launch_bounds__(256) void rowsm_k(US* __restrict__ x, int ldx,
                                               long long sB) {
  __shared__ float red[256];
  const int bid = blockIdx.x;
  const int b = bid & 7;
  const int row = bid >> 3;
  const int t = threadIdx.x;
  US* p = x + (long long)b * sB + (long long)row * ldx + t * 4;
  union { ushort4 v; US s[4]; } buf;
  buf.v = *(const ushort4*)p;
  float v[4];
#pragma unroll
  for (int i = 0; i < 4; ++i) v[i] = b2f(buf.s[i]);
  float mx = fmaxf(fmaxf(v[0], v[1]), fmaxf(v[2], v[3]));
  red[t] = mx;
  __syncthreads();
  for (int s = 128; s; s >>= 1) {
    if (t < s) red[t] = fmaxf(red[t], red[t + s]);
    __syncthreads();
  }
  mx = red[0];
  __syncthreads();
  float sum = 0.f;
#pragma unroll
  for (int i = 0; i < 4; ++i) {
    v[i] = __expf(v[i] - mx);
    sum += v[i];
  }
  red[t] = sum;
  __syncthreads();
  for (int s = 128; s; s >>= 1) {
    if (t < s) red[t] += red[t + s];
    __syncthreads();
  }
  const float inv = 1.0f / red[0];
#pragma unroll
  for (int i = 0; i < 4; ++i) buf.s[i] = f2b(v[i] * inv);
  *(ushort4*)p = buf.v;
}

// ---------------- split column softmax over R of x [B][R][C] (stage 2) -------
template <int RPT>
__global__ __launch_bounds__(256) void sm_partial_k(
    const US* __restrict__ x, float* __restrict__ pm, float* __restrict__ ps,
    int R, int C, long long sB, int NS) {
  const int b = blockIdx.y, blk = blockIdx.x;
  const int cpr = C >> 3;
  const int t = threadIdx.x;
  const int cslot = t & (cpr - 1);
  const int rsub = t / cpr;
  const int nsub = 256 / cpr;
  const int rowsPerBlock = R / NS;
  const int r0 = blk * rowsPerBlock + rsub * RPT;
  const US* p = x + (long long)b * sB + (long long)r0 * C + cslot * 8;
  union { uint4 v; US s[8]; } buf[RPT];
#pragma unroll
  for (int i = 0; i < RPT; ++i) buf[i].v = *(const uint4*)(p + (long long)i * C);
  float M[8], S[8];
#pragma unroll
  for (int j = 0; j < 8; ++j) M[j] = b2f(buf[0].s[j]);
#pragma unroll
  for (int i = 1; i < RPT; ++i)
#pragma unroll
    for (int j = 0; j < 8; ++j) M[j] = fmaxf(M[j], b2f(buf[i].s[j]));
#pragma unroll
  for (int j = 0; j < 8; ++j) S[j] = 0.f;
#pragma unroll
  for (int i = 0; i < RPT; ++i)
#pragma unroll
    for (int j = 0; j < 8; ++j) S[j] += __expf(b2f(buf[i].s[j]) - M[j]);
  const long long pi = (long long)(b * NS + blk) * nsub + rsub;
  float* pmo = pm + pi * C + cslot * 8;
  float* pso = ps + pi * C + cslot * 8;
  *(float4*)pmo = make_float4(M[0], M[1], M[2], M[3]);
  *(float4*)(pmo + 4) = make_float4(M[4], M[5], M[6], M[7]);
  *(float4*)pso = make_float4(S[0], S[1], S[2], S[3]);
  *(float4*)(pso + 4) = make_float4(S[4], S[5], S[6], S[7]);
}

__global__ __launch_bounds__(256) void sm_combine_k(
    const float* __restrict__ pm, const float* __restrict__ ps,
    float* __restrict__ Mf, float* __restrict__ Sinv, int C, int NP) {
  const int b = blockIdx.x, t = threadIdx.x;
  const int cpr = C >> 3;
  if (t >= cpr) return;
  const int c = t * 8;
  const float* pmB = pm + (long long)b * NP * C + c;
  const float* psB = ps + (long long)b * NP * C + c;
  float M[8], S[8];
#pragma unroll
  for (int j = 0; j < 8; ++j) { M[j] = pmB[j]; S[j] = psB[j]; }
  for (int e = 1; e < NP; ++e) {
    const float* pme = pmB + (long long)e * C;
    const float* pse = psB + (long long)e * C;
#pragma unroll
    for (int j = 0; j < 8; ++j) {
      const float m2 = pme[j], s2 = pse[j];
      const float nm = fmaxf(M[j], m2);
      S[j] = S[j] * __expf(M[j] - nm) + s2 * __expf(m2 - nm);
      M[j] = nm;
    }
  }
#pragma unroll
  for (int j = 0; j < 8; ++j) {
    Mf[(long long)b * C + c + j] = M[j];
    Sinv[(long long)b * C + c + j] = 1.0f / S[j];
  }
}

template <int RPT>
__global__ __launch_bounds__(256) void sm_norm_k(
    US* __restrict__ x, const float* __restrict__ Mf,
    const float* __restrict__ Sinv, int R, int C, long long sB, int NS) {
  const int b = blockIdx.y, blk = blockIdx.x;
  const int cpr = C >> 3;
  const int t = threadIdx.x;
  const int cslot = t & (cpr - 1);
  const int rsub = t / cpr;
  const int rowsPerBlock = R / NS;
  const int r0 = blk * rowsPerBlock + rsub * RPT;
  US* p = x + (long long)b * sB + (long long)r0 * C + cslot * 8;
  float M[8], Si[8];
#pragma unroll
  for (int j = 0; j < 8; ++j) {
    M[j] = Mf[(long long)b * C + cslot * 8 + j];
    Si[j] = Sinv[(long long)b * C + cslot * 8 + j];
  }
#pragma unroll
  for (int i = 0; i < RPT; ++i) {
    union { uint4 v; US s[8]; } buf;
    buf.v = *(const uint4*)(p + (long long)i * C);
#pragma unroll
    for (int j = 0; j < 8; ++j)
      buf.s[j] = f2b(__expf(b2f(buf.s[j]) - M[j]) * Si[j]);
    *(uint4*)(p + (long long)i * C) = buf.v;
  }
}

// ---------------- bf16 transpose: src [B][R][C] -> dst [B][C][R] -------------
__global__ __launch_bounds__(256) void transb_k(const US* __restrict__ src,
                                                US* __restrict__ dst, int R,
                                                int C, long long sIn,
                                                long long sOut) {
  __shared__ US L[64][65];
  const int b = blockIdx.z;
  const int r0 = blockIdx.y * 64, c0 = blockIdx.x * 64;
  const int t = threadIdx.x;
  const int lr = t >> 4, lc = (t & 15) * 4;
  const US* s = src + (long long)b * sIn;
#pragma unroll
  for (int i = 0; i < 4; ++i) {
    const int rr = r0 + lr + 16 * i;
    const ushort4 v = *(const ushort4*)&s[(long long)rr * C + c0 + lc];
    L[lr + 16 * i][lc + 0] = v.x;
    L[lr + 16 * i][lc + 1] = v.y;
    L[lr + 16 * i][lc + 2] = v.z;
    L[lr + 16 * i][lc + 3] = v.w;
  }
  __syncthreads();
#pragma unroll
  for (int i = 0; i < 4; ++i) {
    ushort4 o;
    o.x = L[lc + 0][lr + 16 * i];
    o.y = L[lc + 1][lr + 16 * i];
    o.z = L[lc + 2][lr + 16 * i];
    o.w = L[lc + 3][lr + 16 * i];
    *(ushort4*)&dst[(long long)b * sOut + (long long)(c0 + lr + 16 * i) * R + r0 + lc] = o;
  }
}

// ---------------- fused weight transposes ----------------
struct WT { const float* src; US* dst; int R, C, tileOff; };
struct WTab { WT e[11]; };

__global__ __launch_bounds__(256) void wtrans_k(WTab tab) {
  __shared__ US L[64][65];
  const int tile = blockIdx.x;
  int i = 0;
#pragma unroll
  for (int j = 1; j < 11; ++j)
    if (tab.e[j].tileOff <= tile) i = j;
  const WT w = tab.e[i];
  const int lt = tile - w.tileOff;
  const int tc = w.C / 64;
  const int r0 = (lt / tc) * 64, c0 = (lt % tc) * 64;
  const int t = threadIdx.x;
  const int lr = t >> 4, lc = (t & 15) * 4;
#pragma unroll
  for (int k = 0; k < 4; ++k) {
    const int rr = r0 + lr + 16 * k;
    const float4 v = *(const float4*)&w.src[(long long)rr * w.C + c0 + lc];
    L[lr + 16 * k][lc + 0] = f2b(v.x);
    L[lr + 16 * k][lc + 1] = f2b(v.y);
    L[lr + 16 * k][lc + 2] = f2b(v.z);
    L[lr + 16 * k][lc + 3] = f2b(v.w);
  }
  __syncthreads();
#pragma unroll
  for (int k = 0; k < 4; ++k) {
    ushort4 o;
    o.x = L[lc + 0][lr + 16 * k];
    o.y = L[lc + 1][lr + 16 * k];
    o.z = L[lc + 2][lr + 16 * k];
    o.w = L[lc + 3][lr + 16 * k];
    *(ushort4*)&w.dst[(long long)(c0 + lr + 16 * k) * w.R + r0 + lc] = o;
  }
}

// ---------------- reparameterize ----------------
__global__ __launch_bounds__(256) void reparam_k(
    const float* __restrict__ h3, const float* __restrict__ eps,
    float* __restrict__ om, float* __restrict__ olv, US* __restrict__ z,
    int total) {
  const int i = blockIdx.x * 256 + threadIdx.x;
  if (i >= total) return;
  const int j = i & 63;
  const long long r = i >> 6;
  const float m = h3[r * 128 + j];
  const float lv = h3[r * 128 + 64 + j];
  om[i] = m;
  olv[i] = lv;
  z[i] = f2b(m + expf(0.5f * lv) * eps[i]);
}

// ---------------- host dispatch ----------------
static void mm(hipStream_t st, const US* A, const US* B, const float* bias,
               void* C, void* C2, int M, int N, int K, int lda, long long sA,
               long long sB, long long sC, long long sC2, int act, int outm,
               int tn) {
  const int gx = N / tn, gy = M / 128;
  dim3 g(gx * gy * BATCH), blk(256);
#define L(TN, ACT, OUT, HB) \
  mm_k<TN, ACT, OUT, HB><<<g, blk, 0, st>>>(A, B, bias, C, C2, M, N, K, lda, sA, sB, sC, sC2, gx, gy)
  if (tn == 64) {
    if (outm == 0) L(64, 0, 0, false);
    else if (outm == 1) L(64, 0, 1, false);
    else L(64, 2, 2, true);
  } else {
    if (outm == 0) {
      if (act == 1) L(128, 1, 0, true);
      else L(128, 0, 0, false);
    } else if (outm == 1) {
      if (act == 1) L(128, 1, 1, true);
      else L(128, 0, 1, false);
    } else if (outm == 2) L(128, 0, 2, true);
    else L(128, 0, 3, false);
  }
#undef L
}

static void mm256(hipStream_t st, const US* A, const US* B, void* C, void* C2,
                  int M, int N, int K, int lda, long long sA, long long sB,
                  long long sC, long long sC2, int outm) {
  const int gx = N / 256, gy = M / 256;
  dim3 g(gx * gy * BATCH), blk(512);
  if (outm == 0)
    mm256_k<0><<<g, blk, 0, st>>>(A, B, C, C2, M, N, K, lda, sA, sB, sC, sC2, gx, gy);
  else if (outm == 1)
    mm256_k<1><<<g, blk, 0, st>>>(A, B, C, C2, M, N, K, lda, sA, sB, sC, sC2, gx, gy);
  else
    mm256_k<3><<<g, blk, 0, st>>>(A, B, C, C2, M, N, K, lda, sA, sB, sC, sC2, gx, gy);
}

static void mm64(hipStream_t st, const US* A, const US* B, const float* bias,
                 void* C, int M, int N, int K, int lda, long long sA,
                 long long sB, long long sC, int act, int outm) {
  const int gx = N / 64, gy = M / 64;
  dim3 g(gx * gy * BATCH), blk(256);
  if (outm == 0)
    mm64_k<0, 0, false><<<g, blk, 0, st>>>(A, B, nullptr, C, M, N, K, lda, sA, sB, sC, gx, gy);
  else if (outm == 1)
    mm64_k<0, 1, false><<<g, blk, 0, st>>>(A, B, nullptr, C, M, N, K, lda, sA, sB, sC, gx, gy);
  else
    mm64_k<2, 2, true><<<g, blk, 0, st>>>(A, B, bias, C, M, N, K, lda, sA, sB, sC, gx, gy);
}

extern "C" void kernel_launch(void* const* d_in, const int* in_sizes, int n_in,
                              void* d_out, int out_size, void* d_ws, size_t ws_size,
                              hipStream_t stream) {
  const float* x      = (const float*)d_in[0];
  const float* eps    = (const float*)d_in[1];
  const float* adj    = (const float*)d_in[2];
  const float* We1    = (const float*)d_in[3];
  const float* be1    = (const float*)d_in[4];
  const float* Kemb1  = (const float*)d_in[5];
  const float* Kpool1 = (const float*)d_in[6];
  const float* We2    = (const float*)d_in[7];
  const float* be2    = (const float*)d_in[8];
  const float* Kemb2  = (const float*)d_in[9];
  const float* Kpool2 = (const float*)d_in[10];
  const float* We3    = (const float*)d_in[11];
  const float* be3    = (const float*)d_in[12];
  const float* Wd0    = (const float*)d_in[13];
  const float* bd0    = (const float*)d_in[14];
  const float* Wd1    = (const float*)d_in[15];
  const float* bd1    = (const float*)d_in[16];
  const float* Wd2    = (const float*)d_in[17];
  const float* bd2    = (const float*)d_in[18];
  const float* Wdf    = (const float*)d_in[19];
  const float* bdf    = (const float*)d_in[20];
  (void)in_sizes; (void)n_in; (void)ws_size; (void)out_size;

  float* out = (float*)d_out;
  float* out_mean = out + (long long)8 * 2048 * 64;
  float* out_lv = out_mean + (long long)8 * 512 * 64;

  char* base = (char*)d_ws;
  size_t off = 0;
  auto alloc = [&](size_t bytes) {
    char* p = base + off;
    off += (bytes + 255) & ~(size_t)255;
    return p;
  };
  US* Y0   = (US*)alloc(8LL * 2048 * 64 * 2);
  US* h1b  = (US*)alloc(8LL * 2048 * 256 * 2);   // h1 natural [2048][256]
  US* g1   = (US*)alloc(8LL * 2048 * 256 * 2);
  // R1n [8][2048][1280] natural [s1|z1] — dead after transb+spmm1024; its
  // 41,943,040 B are overlaid with pm/ps (stage-2 softmax) + decode temps.
  US* R1n  = (US*)alloc(8LL * 2048 * 1280 * 2);
  float* pm = (float*)R1n;                         //  8 MB
  float* ps = pm + 8LL * 128 * 2048;               //  8 MB
  US* d4    = (US*)(ps + 8LL * 128 * 2048);        //  8 MB [8][2048][256]
  US* t5T   = d4 + 8LL * 2048 * 256;               //  4 MB
  US* d2    = t5T + 8LL * 256 * 1024;              //  4 MB
  US* t3T   = d2 + 8LL * 1024 * 256;               //  2 MB
  US* t4T   = t3T + 8LL * 256 * 512;               //  2 MB
  US* d0    = t4T + 8LL * 256 * 512;               //  2 MB
  US* t6    = d0 + 8LL * 512 * 256;                //  2 MB  (sum = 41,943,040)
  US* R1   = (US*)alloc(8LL * 2304 * 2048 * 2);  // rows [s1T|z1T|AS1T]
  US* AS1  = (US*)alloc(8LL * 2048 * 1024 * 2);
  US* P1o  = (US*)alloc(8LL * 1024 * 1280 * 2);
  US* t1T  = (US*)alloc(8LL * 256 * 1024 * 2);
  US* h2T  = (US*)alloc(8LL * 256 * 1024 * 2);
  US* g2   = (US*)alloc(8LL * 1024 * 256 * 2);
  US* R2   = (US*)alloc(8LL * 1280 * 1024 * 2);
  US* AS2  = (US*)alloc(8LL * 1024 * 512 * 2);
  US* P2o  = (US*)alloc(8LL * 512 * 768 * 2);
  US* t2T  = (US*)alloc(8LL * 128 * 512 * 2);
  float* h3f = (float*)alloc(8LL * 512 * 128 * 4);
  US* zlb  = (US*)alloc(8LL * 512 * 64 * 2);
  float* Mf   = (float*)alloc(8LL * 2048 * 4);
  float* Sinv = (float*)alloc(8LL * 2048 * 4);
  int* rowcnt = (int*)alloc(2048 * 4);
  int* rowptr = (int*)alloc(2049 * 4);
  int* colidx = (int*)alloc(2048LL * 256 * 4);
  float* vals = (float*)alloc(2048LL * 256 * 4);
  int* coloff = (int*)alloc(2048LL * 256 * 4);
  US* We1T  = (US*)alloc(256 * 64 * 2);
  US* KpKe1 = (US*)alloc(1280 * 256 * 2);
  US* We2T  = (US*)alloc(256 * 256 * 2);
  US* KpKe2 = (US*)alloc(768 * 256 * 2);
  US* We3T  = (US*)alloc(128 * 256 * 2);
  US* Wd0T  = (US*)alloc(256 * 64 * 2);
  US* Wd1T  = (US*)alloc(256 * 256 * 2);
  US* Wd2T  = (US*)alloc(256 * 256 * 2);
  US* WdfT  = (US*)alloc(64 * 256 * 2);

  // ---- weight conversions + CSR build ----
  {
    WTab tab;
    int toff = 0, i = 0;
    auto add = [&](const float* s, US* d, int R, int C) {
      tab.e[i++] = WT{s, d, R, C, toff};
      toff += (R / 64) * (C / 64);
    };
    add(We1, We1T, 64, 256);
    add(Kpool1, KpKe1, 256, 1024);
    add(Kemb1, KpKe1 + 1024 * 256, 256, 256);
    add(We2, We2T, 256, 256);
    add(Kpool2, KpKe2, 256, 512);
    add(Kemb2, KpKe2 + 512 * 256, 256, 256);
    add(We3, We3T, 256, 128);
    add(Wd0, Wd0T, 64, 256);
    add(Wd1, Wd1T, 256, 256);
    add(Wd2, Wd2T, 256, 256);
    add(Wdf, WdfT, 256, 64);
    wtrans_k<<<dim3(toff), dim3(256), 0, stream>>>(tab);
  }
  csr_count_k<<<dim3(2048), dim3(256), 0, stream>>>(adj, rowcnt);
  csr_scan_k<<<dim3(1), dim3(256), 0, stream>>>(rowcnt, rowptr);
  csr_fill_k<<<dim3(2048), dim3(256), 0, stream>>>(adj, rowptr, colidx, vals,
                                                   coloff);

  const long long SR1 = 2304LL * 2048, SR2 = 1280LL * 1024;
  const long long SR1n = 2048LL * 1280;
  US* s1T  = R1;
  US* B1   = R1 + 1024 * 2048;           // rows [z1T(256) | AS1T(1024)]
  US* AS1T = R1 + 1280 * 2048;
  US* s2T  = R2;
  US* B2   = R2 + 512 * 1024;
  US* AS2T = R2 + 768 * 1024;
  US* A1c  = P1o + 256;
  US* A2c  = P2o + 256;

  // ---------------- encode ----------------
  // Y0 = adj @ x  (SpMM from f32 x)
  spmm_k<64, true, 0, false, false><<<dim3(2048), dim3(256), 0, stream>>>(
      rowptr, colidx, vals, x, nullptr, Y0);
  // h1 = relu(Y0@We1+b)
  mm(stream, Y0, We1T, be1, h1b, nullptr, 2048, 256, 64, 64, 2048LL * 64, 0,
     2048LL * 256, 0, 1, 0, 128);
  // g1 = adj @ h1  (SpMM)
  spmm_k<256, false, 0, false, false><<<dim3(2048), dim3(256), 0, stream>>>(
      rowptr, colidx, vals, h1b, nullptr, g1);
  // R1n = g1 @ [Kp1|Ke1]  (natural [2048][1280]: cols [s1 logits | z1])
  mm256(stream, g1, KpKe1, R1n, nullptr, 2048, 1280, 256, 256, 2048LL * 256, 0,
        SR1n, 0, 0);
  // row softmax over s1 logits (cols 0..1024)
  rowsm_k<<<dim3(16384), dim3(256), 0, stream>>>(R1n, 1280, SR1n);
  // R1 = R1n^T  ([1280][2048]: rows [s1T | z1T])
  transb_k<<<dim3(20, 32, 8), dim3(256), 0, stream>>>(R1n, R1, 2048, 1280,
                                                      SR1n, SR1);
  // AS1 = adj @ s1  (SpMM wide, 16B gathers, pre-scaled offsets)
  spmm1024_k<<<dim3(8192), dim3(256), 0, stream>>>(rowptr, coloff, vals, R1n,
                                                   SR1n, AS1);
  // AS1T into B1 region  (R1n now dead — overlay region reusable)
  transb_k<<<dim3(16, 32, 8), dim3(256), 0, stream>>>(AS1, AS1T, 2048, 1024,
                                                      2048LL * 1024, SR1);
  // P1 = s1^T @ [z1 | AS1] -> [xp1 | A1]   (256^2)
  mm256(stream, s1T, B1, P1o, nullptr, 1024, 1280, 2048, 2048, SR1, SR1,
        1024LL * 1280, 0, 0);
  mm(stream, P1o, We2T, nullptr, t1T, nullptr, 1024, 256, 256, 1280, 1024LL * 1280,
     0, 0, 256LL * 1024, 0, 1, 128);
  mm(stream, A1c, t1T, be2, h2T, nullptr, 1024, 256, 1024, 1280, 1024LL * 1280,
     256LL * 1024, 0, 256LL * 1024, 1, 1, 128);
  mm(stream, A1c, h2T, nullptr, g2, nullptr, 1024, 256, 1024, 1280, 1024LL * 1280,
     256LL * 1024, 1024LL * 256, 0, 0, 0, 128);
  mm(stream, g2, KpKe2, nullptr, R2, nullptr, 1024, 768, 256, 256, 1024LL * 256,
     0, 0, SR2, 0, 1, 128);
  sm_partial_k<4><<<dim3(64, 8), dim3(256), 0, stream>>>(s2T, pm, ps, 512, 1024, SR2, 64);
  sm_combine_k<<<dim3(8), dim3(256), 0, stream>>>(pm, ps, Mf, Sinv, 1024, 128);
  sm_norm_k<4><<<dim3(64, 8), dim3(256), 0, stream>>>(s2T, Mf, Sinv, 512, 1024, SR2, 64);
  mm(stream, A1c, s2T, nullptr, AS2, AS2T, 1024, 512, 1024, 1280, 1024LL * 1280,
     SR2, 1024LL * 512, SR2, 0, 3, 128);
  mm(stream, s2T, B2, nullptr, P2o, nullptr, 512, 768, 1024, 1024, SR2, SR2,
     512LL * 768, 0, 0, 0, 128);
  mm(stream, P2o, We3T, nullptr, t2T, nullptr, 512, 128, 256, 768, 512LL * 768,
     0, 0, 128LL * 512, 0, 1, 128);
  mm(stream, A2c, t2T, be3, h3f, nullptr, 512, 128, 512, 768, 512LL * 768,
     128LL * 512, 512LL * 128, 0, 0, 2, 128);
  reparam_k<<<dim3(8 * 512 * 64 / 256), dim3(256), 0, stream>>>(h3f, eps, out_mean,
                                                                out_lv, zlb, 8 * 512 * 64);

  // ---------------- decode ----------------
  mm(stream, zlb, Wd0T, nullptr, t3T, nullptr, 512, 256, 64, 64, 512LL * 64, 0, 0,
     256LL * 512, 0, 1, 128);
  mm(stream, A2c, t3T, bd0, d0, nullptr, 512, 256, 512, 768, 512LL * 768,
     256LL * 512, 512LL * 256, 0, 1, 0, 128);
  mm(stream, d0, Wd1T, nullptr, t4T, nullptr, 512, 256, 256, 256, 512LL * 256, 0,
     0, 256LL * 512, 0, 1, 128);
  mm(stream, AS2, t4T, bd1, d2, nullptr, 1024, 256, 512, 512, 1024LL * 512,
     256LL * 512, 1024LL * 256, 0, 1, 0, 128);
  mm(stream, d2, Wd2T, nullptr, t5T, nullptr, 1024, 256, 256, 256, 1024LL * 256, 0,
     0, 256LL * 1024, 0, 1, 128);
  mm(stream, AS1, t5T, bd2, d4, nullptr, 2048, 256, 1024, 1024, 2048LL * 1024,
     256LL * 1024, 2048LL * 256, 0, 1, 0, 128);
  mm64(stream, d4, WdfT, nullptr, t6, 2048, 64, 256, 256, 2048LL * 256, 0,
       2048LL * 64, 0, 0);
  spmm_k<64, false, 2, true, true><<<dim3(2048), dim3(256), 0, stream>>>(
      rowptr, colidx, vals, t6, bdf, out);
}

// Round 19
// 594.176 us; speedup vs baseline: 1.2126x; 1.0493x over previous
//
#include <hip/hip_runtime.h>
#include <math.h>

#define BATCH 8
typedef unsigned short US;

typedef __attribute__((ext_vector_type(8))) short short8;
typedef __attribute__((ext_vector_type(4))) float f32x4;

__device__ __forceinline__ US f2b(float f) {
  union { float f; unsigned u; } v; v.f = f;
  unsigned r = v.u + 0x7fffu + ((v.u >> 16) & 1u);
  return (US)(r >> 16);
}
__device__ __forceinline__ float b2f(US h) {
  union { unsigned u; float f; } v; v.u = ((unsigned)h) << 16;
  return v.f;
}

__device__ __forceinline__ void gload16(const US* g, US* l) {
  __builtin_amdgcn_global_load_lds(
      (const __attribute__((address_space(1))) unsigned int*)g,
      (__attribute__((address_space(3))) unsigned int*)l, 16, 0, 0);
}

// LDS tile [rows][64] linear, XOR swizzle: 16B-cell index ^= (row&7).
__device__ __forceinline__ int lidx2(int r, int ko) {
  return r * 64 + ((((ko >> 3) ^ (r & 7)) << 3));
}

// ================= 128^2 1-phase MFMA GEMM (verified r3-r7) ==================
// C = act(A@B + bias). A bf16 phys [M][lda], B bf16 phys [N][K].
// OUT: 0=bf16 [M][N], 1=bf16 [N][M], 2=f32 [M][N], 3=dual bf16 [M][N]+[N][M].
template <int TN, int ACT, int OUT, bool HASBIAS>
__global__ __launch_bounds__(256) void mm_k(
    const US* __restrict__ A, const US* __restrict__ B,
    const float* __restrict__ bias, void* __restrict__ Cv, void* __restrict__ Cv2,
    int M, int N, int K, int lda, long long sA, long long sB, long long sC,
    long long sC2, int gx, int gy) {
  constexpr int JF = TN / 32;
  __shared__ US As[128 * 64];
  __shared__ US Bs[TN * 64];

  const int nb = blockIdx.x;
  const int nb2 = (nb & 7) * (gx * gy) + (nb >> 3);
  const int bx = nb2 % gx;
  const int by = (nb2 / gx) % gy;
  const int b = nb2 / (gx * gy);

  A += (long long)b * sA;
  B += (long long)b * sB;
  const int m0 = by * 128, n0 = bx * TN;
  const int t = threadIdx.x, lane = t & 63, w = t >> 6;
  const int wm = (w >> 1) * 64, wn = (w & 1) * (TN / 2);
  const int l15 = lane & 15, lg = lane >> 4;
  const int lrow = lane >> 3;
  const int gcell = (((lane & 7) ^ lrow) << 3);

  f32x4 acc[4][JF];
#pragma unroll
  for (int i = 0; i < 4; ++i)
#pragma unroll
    for (int j = 0; j < JF; ++j) acc[i][j] = (f32x4){0.f, 0.f, 0.f, 0.f};

  for (int k0 = 0; k0 < K; k0 += 64) {
#pragma unroll
    for (int i = 0; i < 4; ++i) {
      const int g = w * 4 + i;
      gload16(A + (long long)(m0 + g * 8 + lrow) * lda + k0 + gcell, &As[g * 512]);
    }
#pragma unroll
    for (int i = 0; i < TN / 32; ++i) {
      const int g = w * (TN / 32) + i;
      gload16(B + (long long)(n0 + g * 8 + lrow) * K + k0 + gcell, &Bs[g * 512]);
    }
    __syncthreads();

#pragma unroll
    for (int kk = 0; kk < 2; ++kk) {
      const int ko = kk * 32 + lg * 8;
      short8 af[4], bf[JF];
#pragma unroll
      for (int i = 0; i < 4; ++i)
        af[i] = *(const short8*)&As[lidx2(wm + i * 16 + l15, ko)];
#pragma unroll
      for (int j = 0; j < JF; ++j)
        bf[j] = *(const short8*)&Bs[lidx2(wn + j * 16 + l15, ko)];
#pragma unroll
      for (int i = 0; i < 4; ++i)
#pragma unroll
        for (int j = 0; j < JF; ++j)
          acc[i][j] = __builtin_amdgcn_mfma_f32_16x16x32_bf16(af[i], bf[j],
                                                              acc[i][j], 0, 0, 0);
    }
    __syncthreads();
  }

  const long long cb = (long long)b * sC;
  const long long cb2 = (long long)b * sC2;
#pragma unroll
  for (int fj = 0; fj < JF; ++fj) {
    const int col = n0 + wn + fj * 16 + l15;
    const float bsv = HASBIAS ? bias[col] : 0.0f;
#pragma unroll
    for (int fi = 0; fi < 4; ++fi) {
      const int row0 = m0 + wm + fi * 16 + lg * 4;
      float v[4];
#pragma unroll
      for (int e = 0; e < 4; ++e) {
        float x = acc[fi][fj][e] + bsv;
        if (ACT == 1) x = fmaxf(x, 0.0f);
        if (ACT == 2) x = (x > 20.0f) ? x : log1pf(expf(x));
        v[e] = x;
      }
      if (OUT == 1 || OUT == 3) {
        ushort4 pk;
        pk.x = f2b(v[0]); pk.y = f2b(v[1]); pk.z = f2b(v[2]); pk.w = f2b(v[3]);
        US* c2 = (OUT == 3) ? (US*)Cv2 : (US*)Cv;
        *(ushort4*)&c2[cb2 + (long long)col * M + row0] = pk;
      }
      if (OUT == 0 || OUT == 3) {
#pragma unroll
        for (int e = 0; e < 4; ++e)
          ((US*)Cv)[cb + (long long)(row0 + e) * N + col] = f2b(v[e]);
      }
      if (OUT == 2) {
#pragma unroll
        for (int e = 0; e < 4; ++e)
          ((float*)Cv)[cb + (long long)(row0 + e) * N + col] = v[e];
      }
    }
  }
}

// ================= 256^2 deep-pipelined MFMA GEMM (r7-exact) =================
template <int OUT>
__global__ __launch_bounds__(512, 1) void mm256_k(
    const US* __restrict__ A, const US* __restrict__ B, void* __restrict__ Cv,
    void* __restrict__ Cv2, int M, int N, int K, int lda, long long sA,
    long long sB, long long sC, long long sC2, int gx, int gy) {
  __shared__ US lds[8][8192];

  const int nb = blockIdx.x;
  const int chunk = gx * gy;
  const int nb2 = (nb & 7) * chunk + (nb >> 3);
  const int bx = nb2 % gx;
  const int by = (nb2 / gx) % gy;
  const int b = nb2 / chunk;

  const int m0 = by * 256, n0 = bx * 256;
  const int tid = threadIdx.x;
  const int lane = tid & 63, w = tid >> 6;
  const int wr = w >> 2, wc = w & 3;
  const int l15 = lane & 15, lg = lane >> 4;

  const US* Ab = A + (long long)b * sA + (long long)m0 * lda;
  const US* Bb = B + (long long)b * sB + (long long)n0 * K;
  const int NT = K >> 6;

  auto stageH = [&](int H) {
    const int s = H >> 2, h = H & 3;
    const int ab = h & 1, kk = h >> 1;
    US* reg = &lds[ab * 4 + (s & 1) * 2 + kk][0];
    const US* src = ab ? Bb : Ab;
    const int ld = ab ? K : lda;
#pragma unroll
    for (int i = 0; i < 2; ++i) {
      const int rbase = (w * 2 + i) * 16;
      const int r = rbase + (lane >> 2);
      const int csrc = (lane & 3) ^ ((r >> 1) & 3);
      gload16(src + (long long)r * ld + s * 64 + kk * 32 + csrc * 8,
              reg + rbase * 32);
    }
  };

  f32x4 acc[8][4];
#pragma unroll
  for (int m = 0; m < 8; ++m)
#pragma unroll
    for (int j = 0; j < 4; ++j) acc[m][j] = (f32x4){0.f, 0.f, 0.f, 0.f};
  short8 a4[4], b4[4];

  for (int H = 0; H < 6; ++H) stageH(H);
  asm volatile("s_waitcnt vmcnt(4)" ::: "memory");
  __builtin_amdgcn_s_barrier();

#define PH(kk_, mh_, DOH, HV, VM, tt)                                          \
  {                                                                            \
    const US* Ar = &lds[((tt) & 1) * 2 + (kk_)][0];                            \
    const US* Br = &lds[4 + ((tt) & 1) * 2 + (kk_)][0];                        \
    _Pragma("unroll") for (int i = 0; i < 4; ++i) {                            \
      const int r = wr * 128 + (mh_) * 64 + i * 16 + l15;                      \
      a4[i] = *(const short8*)&Ar[r * 32 + ((lg ^ ((r >> 1) & 3)) << 3)];      \
    }                                                                          \
    if ((mh_) == 0) {                                                          \
      _Pragma("unroll") for (int j = 0; j < 4; ++j) {                          \
        const int rr = wc * 64 + j * 16 + l15;                                 \
        b4[j] = *(const short8*)&Br[rr * 32 + ((lg ^ ((rr >> 1) & 3)) << 3)];  \
      }                                                                        \
    }                                                                          \
    if (DOH) stageH(HV);                                                       \
    if ((VM) == 1) asm volatile("s_waitcnt vmcnt(4)" ::: "memory");            \
    if ((VM) == 2) asm volatile("s_waitcnt vmcnt(0)" ::: "memory");            \
    __builtin_amdgcn_s_barrier();                                              \
    __builtin_amdgcn_s_setprio(1);                                             \
    _Pragma("unroll") for (int i = 0; i < 4; ++i)                              \
      _Pragma("unroll") for (int j = 0; j < 4; ++j)                            \
        acc[(mh_) * 4 + i][j] = __builtin_amdgcn_mfma_f32_16x16x32_bf16(       \
            a4[i], b4[j], acc[(mh_) * 4 + i][j], 0, 0, 0);                     \
    __builtin_amdgcn_s_setprio(0);                                             \
    __builtin_amdgcn_s_barrier();                                              \
  }

  int t2 = 0;
  for (; t2 < NT - 2; ++t2) {
    PH(0, 0, true, 4 * t2 + 6, 0, t2)
    PH(0, 1, true, 4 * t2 + 7, 0, t2)
    PH(1, 0, true, 4 * t2 + 8, 0, t2)
    PH(1, 1, true, 4 * t2 + 9, 1, t2)
  }
  PH(0, 0, true, 4 * (NT - 2) + 6, 0, NT - 2)
  PH(0, 1, true, 4 * (NT - 2) + 7, 0, NT - 2)
  PH(1, 0, false, 0, 0, NT - 2)
  PH(1, 1, false, 0, 2, NT - 2)
  PH(0, 0, false, 0, 0, NT - 1)
  PH(0, 1, false, 0, 0, NT - 1)
  PH(1, 0, false, 0, 0, NT - 1)
  PH(1, 1, false, 0, 0, NT - 1)
#undef PH

  const long long cb = (long long)b * sC;
  const long long cb2 = (long long)b * sC2;
#pragma unroll
  for (int j = 0; j < 4; ++j) {
    const int col = n0 + wc * 64 + j * 16 + l15;
#pragma unroll
    for (int m = 0; m < 8; ++m) {
      const int row0 = m0 + wr * 128 + m * 16 + lg * 4;
      if (OUT == 1 || OUT == 3) {
        ushort4 pk;
        pk.x = f2b(acc[m][j][0]); pk.y = f2b(acc[m][j][1]);
        pk.z = f2b(acc[m][j][2]); pk.w = f2b(acc[m][j][3]);
        US* c2 = (OUT == 3) ? (US*)Cv2 : (US*)Cv;
        *(ushort4*)&c2[cb2 + (long long)col * M + row0] = pk;
      }
      if (OUT == 0 || OUT == 3) {
#pragma unroll
        for (int e = 0; e < 4; ++e)
          ((US*)Cv)[cb + (long long)(row0 + e) * N + col] = f2b(acc[m][j][e]);
      }
    }
  }
}

// ================= 64x64 4-deep pipelined MFMA GEMM (skinny N) ===============
template <int ACT, int OUT, bool HASBIAS>
__global__ __launch_bounds__(256) void mm64_k(
    const US* __restrict__ A, const US* __restrict__ B,
    const float* __restrict__ bias, void* __restrict__ Cv,
    int M, int N, int K, int lda, long long sA, long long sB, long long sC,
    int gx, int gy) {
  __shared__ US As[4][4096];
  __shared__ US Bs[4][4096];

  const int nb = blockIdx.x;
  const int chunk = gx * gy;
  const int nb2 = (nb & 7) * chunk + (nb >> 3);
  const int bx = nb2 % gx;
  const int by = (nb2 / gx) % gy;
  const int b = nb2 / chunk;

  const int m0 = by * 64, n0 = bx * 64;
  const int tid = threadIdx.x;
  const int lane = tid & 63, w = tid >> 6;
  const int wr = w >> 1, wc = w & 1;
  const int l15 = lane & 15, lg = lane >> 4;
  const int lrow = lane >> 3;
  const int gcell = (((lane & 7) ^ lrow) << 3);

  const US* Ag = A + (long long)b * sA + (long long)m0 * lda;
  const US* Bg = B + (long long)b * sB + (long long)n0 * K;
  const int NT = K >> 6;

  auto stage = [&](int tt) {
    US* Ad = &As[tt & 3][0];
    US* Bd = &Bs[tt & 3][0];
    const int k0 = tt * 64;
#pragma unroll
    for (int i = 0; i < 2; ++i) {
      const int g = w * 2 + i;
      const int r = g * 8 + lrow;
      gload16(Ag + (long long)r * lda + k0 + gcell, Ad + g * 512);
      gload16(Bg + (long long)r * K + k0 + gcell, Bd + g * 512);
    }
  };

  f32x4 acc[2][2];
#pragma unroll
  for (int i = 0; i < 2; ++i)
#pragma unroll
    for (int j = 0; j < 2; ++j) acc[i][j] = (f32x4){0.f, 0.f, 0.f, 0.f};

  for (int i = 0; i < 3 && i < NT; ++i) stage(i);

  for (int t = 0; t < NT; ++t) {
    if (t + 3 < NT) stage(t + 3);
    const int rem = NT - 1 - t;
    if (rem >= 3) asm volatile("s_waitcnt vmcnt(12)" ::: "memory");
    else if (rem == 2) asm volatile("s_waitcnt vmcnt(8)" ::: "memory");
    else if (rem == 1) asm volatile("s_waitcnt vmcnt(4)" ::: "memory");
    else asm volatile("s_waitcnt vmcnt(0)" ::: "memory");
    asm volatile("s_barrier" ::: "memory");
    const US* Ad = &As[t & 3][0];
    const US* Bd = &Bs[t & 3][0];
#pragma unroll
    for (int kk = 0; kk < 2; ++kk) {
      const int ko = kk * 32 + lg * 8;
      short8 af[2], bf[2];
      af[0] = *(const short8*)&Ad[lidx2(wr * 32 + l15, ko)];
      af[1] = *(const short8*)&Ad[lidx2(wr * 32 + 16 + l15, ko)];
      bf[0] = *(const short8*)&Bd[lidx2(wc * 32 + l15, ko)];
      bf[1] = *(const short8*)&Bd[lidx2(wc * 32 + 16 + l15, ko)];
#pragma unroll
      for (int i = 0; i < 2; ++i)
#pragma unroll
        for (int j = 0; j < 2; ++j)
          acc[i][j] = __builtin_amdgcn_mfma_f32_16x16x32_bf16(af[i], bf[j],
                                                              acc[i][j], 0, 0, 0);
    }
    asm volatile("s_barrier" ::: "memory");
  }

  const long long cb = (long long)b * sC;
#pragma unroll
  for (int fj = 0; fj < 2; ++fj) {
    const int col = n0 + wc * 32 + fj * 16 + l15;
    const float bsv = HASBIAS ? bias[col] : 0.0f;
#pragma unroll
    for (int fi = 0; fi < 2; ++fi) {
      const int row0 = m0 + wr * 32 + fi * 16 + lg * 4;
      float v[4];
#pragma unroll
      for (int e = 0; e < 4; ++e) {
        float x = acc[fi][fj][e] + bsv;
        if (ACT == 1) x = fmaxf(x, 0.0f);
        if (ACT == 2) x = (x > 20.0f) ? x : log1pf(expf(x));
        v[e] = x;
      }
      if (OUT == 1) {
        ushort4 pk;
        pk.x = f2b(v[0]); pk.y = f2b(v[1]); pk.z = f2b(v[2]); pk.w = f2b(v[3]);
        *(ushort4*)&((US*)Cv)[cb + (long long)col * M + row0] = pk;
      } else if (OUT == 0) {
#pragma unroll
        for (int e = 0; e < 4; ++e)
          ((US*)Cv)[cb + (long long)(row0 + e) * N + col] = f2b(v[e]);
      } else {
#pragma unroll
        for (int e = 0; e < 4; ++e)
          ((float*)Cv)[cb + (long long)(row0 + e) * N + col] = v[e];
      }
    }
  }
}

// ================= CSR build (deterministic, no global atomics) ==============
__global__ __launch_bounds__(256) void csr_count_k(const float* __restrict__ adj,
                                                   int* __restrict__ rowcnt) {
  const int row = blockIdx.x, t = threadIdx.x;
  const float* p = adj + (long long)row * 2048;
  int c = 0;
  for (int j = t; j < 2048; j += 256) c += (p[j] != 0.0f);
  __shared__ int red[256];
  red[t] = c;
  __syncthreads();
  for (int s = 128; s; s >>= 1) {
    if (t < s) red[t] += red[t + s];
    __syncthreads();
  }
  if (t == 0) rowcnt[row] = red[0];
}

__global__ __launch_bounds__(256) void csr_scan_k(const int* __restrict__ rowcnt,
                                                  int* __restrict__ rowptr) {
  __shared__ int red[256];
  const int t = threadIdx.x;
  int base = 0;
  for (int ch = 0; ch < 8; ++ch) {
    const int v = rowcnt[ch * 256 + t];
    red[t] = v;
    __syncthreads();
    for (int s = 1; s < 256; s <<= 1) {
      const int add = (t >= s) ? red[t - s] : 0;
      __syncthreads();
      red[t] += add;
      __syncthreads();
    }
    rowptr[ch * 256 + t] = base + red[t] - v;
    const int tot = red[255];
    __syncthreads();
    base += tot;
  }
  if (t == 0) rowptr[2048] = base;
}

__global__ __launch_bounds__(256) void csr_fill_k(const float* __restrict__ adj,
                                                  const int* __restrict__ rowptr,
                                                  int* __restrict__ colidx,
                                                  float* __restrict__ vals,
                                                  int* __restrict__ coloff) {
  const int row = blockIdx.x, t = threadIdx.x;
  const float* p = adj + (long long)row * 2048;
  int cnt = 0;
  for (int j = t; j < 2048; j += 256) cnt += (p[j] != 0.0f);
  __shared__ int red[256];
  red[t] = cnt;
  __syncthreads();
  for (int s = 1; s < 256; s <<= 1) {
    const int add = (t >= s) ? red[t - s] : 0;
    __syncthreads();
    red[t] += add;
    __syncthreads();
  }
  int off = rowptr[row] + red[t] - cnt;
  for (int j = t; j < 2048; j += 256) {
    const float a = p[j];
    if (a != 0.0f) {
      colidx[off] = j;
      vals[off] = a;
      coloff[off] = j * 1280;  // pre-scaled element offset for spmm1024 (ldx)
      ++off;
    }
  }
}

// ================= SpMM narrow: Y[b][row][c] = act(sum_j a_rj X[b][j][c]+bias)
template <int COLS, bool INF32, int ACT, bool OUTF32, bool HASBIAS>
__global__ __launch_bounds__(256) void spmm_k(
    const int* __restrict__ rowptr, const int* __restrict__ colidx,
    const float* __restrict__ vals, const void* __restrict__ Xv,
    const float* __restrict__ bias, void* __restrict__ Yv) {
  constexpr int BP = 256 / COLS;
  constexpr int NP = BATCH / BP;
  const int row = blockIdx.x;
  const int t = threadIdx.x;
  const int c = t & (COLS - 1);
  const int bsub = t / COLS;
  const int e0 = rowptr[row], e1 = rowptr[row + 1];
  float acc[NP];
#pragma unroll
  for (int p = 0; p < NP; ++p) acc[p] = 0.0f;
  for (int e = e0; e < e1; ++e) {
    const int j = colidx[e];
    const float a = vals[e];
#pragma unroll
    for (int p = 0; p < NP; ++p) {
      const int b = p * BP + bsub;
      const long long idx = ((long long)b * 2048 + j) * COLS + c;
      const float xv = INF32 ? ((const float*)Xv)[idx] : b2f(((const US*)Xv)[idx]);
      acc[p] += a * xv;
    }
  }
#pragma unroll
  for (int p = 0; p < NP; ++p) {
    const int b = p * BP + bsub;
    float v = acc[p] + (HASBIAS ? bias[c] : 0.0f);
    if (ACT == 2) v = (v > 20.0f) ? v : log1pf(expf(v));
    const long long idx = ((long long)b * 2048 + row) * COLS + c;
    if (OUTF32) ((float*)Yv)[idx] = v;
    else ((US*)Yv)[idx] = f2b(v);
  }
}

// ================= SpMM wide (1024 cols), 16B gathers, scalar metadata =======
// Y[b][row][0..1024) = sum over nnz of a * X[b][coloff + c]; coloff pre-scaled.
// Grid 8192: b = bid&7 (XCD-local batch), rowpair = bid>>3; 2 rows/block,
// 128 threads/row, 8 cols (16B) per thread. row is wave-uniform -> metadata
// (rowptr/coloff/vals) lowered to scalar loads via readfirstlane.
__global__ __launch_bounds__(256) void spmm1024_k(
    const int* __restrict__ rowptr, const int* __restrict__ coloff,
    const float* __restrict__ vals, const US* __restrict__ X,
    long long sX, US* __restrict__ Y) {
  const int bid = blockIdx.x;
  const int b = bid & 7;
  const int rp = bid >> 3;
  const int t = threadIdx.x;
  // row is uniform within each wave (threads 0-127 -> row0, 128-255 -> row1)
  const int row = __builtin_amdgcn_readfirstlane(rp * 2 + (t >> 7));
  const int c0 = (t & 127) * 8;
  const US* Xb = X + (long long)b * sX + c0;
  const int e0 = __builtin_amdgcn_readfirstlane(rowptr[row]);
  const int e1 = __builtin_amdgcn_readfirstlane(rowptr[row + 1]);
  union U8 { uint4 v; US s[8]; };
  float p0[8] = {0.f, 0.f, 0.f, 0.f, 0.f, 0.f, 0.f, 0.f};
  float p1[8] = {0.f, 0.f, 0.f, 0.f, 0.f, 0.f, 0.f, 0.f};
  int e = e0;
  for (; e + 4 <= e1; e += 4) {
    const int o0 = __builtin_amdgcn_readfirstlane(coloff[e + 0]);
    const int o1 = __builtin_amdgcn_readfirstlane(coloff[e + 1]);
    const int o2 = __builtin_amdgcn_readfirstlane(coloff[e + 2]);
    const int o3 = __builtin_amdgcn_readfirstlane(coloff[e + 3]);
    const float a0 = vals[e + 0], a1 = vals[e + 1];
    const float a2 = vals[e + 2], a3 = vals[e + 3];
    U8 x0, x1, x2, x3;
    x0.v = *(const uint4*)&Xb[o0];
    x1.v = *(const uint4*)&Xb[o1];
    x2.v = *(const uint4*)&Xb[o2];
    x3.v = *(const uint4*)&Xb[o3];
#pragma unroll
    for (int q = 0; q < 8; ++q) {
      p0[q] += a0 * b2f(x0.s[q]) + a2 * b2f(x2.s[q]);
      p1[q] += a1 * b2f(x1.s[q]) + a3 * b2f(x3.s[q]);
    }
  }
  for (; e < e1; ++e) {
    const int o = __builtin_amdgcn_readfirstlane(coloff[e]);
    const float a = vals[e];
    U8 xv;
    xv.v = *(const uint4*)&Xb[o];
#pragma unroll
    for (int q = 0; q < 8; ++q) p0[q] += a * b2f(xv.s[q]);
  }
  US o[8];
#pragma unroll
  for (int q = 0; q < 8; ++q) o[q] = f2b(p0[q] + p1[q]);
  *(uint4*)&Y[((long long)b * 2048 + row) * 1024 + c0] = *(uint4*)o;
}

// ================= row softmax over cols [0,1024) of x [B][2048][ldx] ========
__global__ __launch_bounds__(256) void rowsm_k(US* __restrict__ x, int ldx,
                                               long long sB) {
  __shared__ float red[256];
  const int bid = blockIdx.x;
  const int b = bid & 7;
  const int row = bid >> 3;
  const int t = threadIdx.x;
  US* p = x + (long long)b * sB + (long long)row * ldx + t * 4;
  union { ushort4 v; US s[4]; } buf;
  buf.v = *(const ushort4*)p;
  float v[4];
#pragma unroll
  for (int i = 0; i < 4; ++i) v[i] = b2f(buf.s[i]);
  float mx = fmaxf(fmaxf(v[0], v[1]), fmaxf(v[2], v[3]));
  red[t] = mx;
  __syncthreads();
  for (int s = 128; s; s >>= 1) {
    if (t < s) red[t] = fmaxf(red[t], red[t + s]);
    __syncthreads();
  }
  mx = red[0];
  __syncthreads();
  float sum = 0.f;
#pragma unroll
  for (int i = 0; i < 4; ++i) {
    v[i] = __expf(v[i] - mx);
    sum += v[i];
  }
  red[t] = sum;
  __syncthreads();
  for (int s = 128; s; s >>= 1) {
    if (t < s) red[t] += red[t + s];
    __syncthreads();
  }
  const float inv = 1.0f / red[0];
#pragma unroll
  for (int i = 0; i < 4; ++i) buf.s[i] = f2b(v[i] * inv);
  *(ushort4*)p = buf.v;
}

// ---------------- split column softmax over R of x [B][R][C] (stage 2) -------
template <int RPT>
__global__ __launch_bounds__(256) void sm_partial_k(
    const US* __restrict__ x, float* __restrict__ pm, float* __restrict__ ps,
    int R, int C, long long sB, int NS) {
  const int b = blockIdx.y, blk = blockIdx.x;
  const int cpr = C >> 3;
  const int t = threadIdx.x;
  const int cslot = t & (cpr - 1);
  const int rsub = t / cpr;
  const int nsub = 256 / cpr;
  const int rowsPerBlock = R / NS;
  const int r0 = blk * rowsPerBlock + rsub * RPT;
  const US* p = x + (long long)b * sB + (long long)r0 * C + cslot * 8;
  union { uint4 v; US s[8]; } buf[RPT];
#pragma unroll
  for (int i = 0; i < RPT; ++i) buf[i].v = *(const uint4*)(p + (long long)i * C);
  float M[8], S[8];
#pragma unroll
  for (int j = 0; j < 8; ++j) M[j] = b2f(buf[0].s[j]);
#pragma unroll
  for (int i = 1; i < RPT; ++i)
#pragma unroll
    for (int j = 0; j < 8; ++j) M[j] = fmaxf(M[j], b2f(buf[i].s[j]));
#pragma unroll
  for (int j = 0; j < 8; ++j) S[j] = 0.f;
#pragma unroll
  for (int i = 0; i < RPT; ++i)
#pragma unroll
    for (int j = 0; j < 8; ++j) S[j] += __expf(b2f(buf[i].s[j]) - M[j]);
  const long long pi = (long long)(b * NS + blk) * nsub + rsub;
  float* pmo = pm + pi * C + cslot * 8;
  float* pso = ps + pi * C + cslot * 8;
  *(float4*)pmo = make_float4(M[0], M[1], M[2], M[3]);
  *(float4*)(pmo + 4) = make_float4(M[4], M[5], M[6], M[7]);
  *(float4*)pso = make_float4(S[0], S[1], S[2], S[3]);
  *(float4*)(pso + 4) = make_float4(S[4], S[5], S[6], S[7]);
}

__global__ __launch_bounds__(256) void sm_combine_k(
    const float* __restrict__ pm, const float* __restrict__ ps,
    float* __restrict__ Mf, float* __restrict__ Sinv, int C, int NP) {
  const int b = blockIdx.x, t = threadIdx.x;
  const int cpr = C >> 3;
  if (t >= cpr) return;
  const int c = t * 8;
  const float* pmB = pm + (long long)b * NP * C + c;
  const float* psB = ps + (long long)b * NP * C + c;
  float M[8], S[8];
#pragma unroll
  for (int j = 0; j < 8; ++j) { M[j] = pmB[j]; S[j] = psB[j]; }
  for (int e = 1; e < NP; ++e) {
    const float* pme = pmB + (long long)e * C;
    const float* pse = psB + (long long)e * C;
#pragma unroll
    for (int j = 0; j < 8; ++j) {
      const float m2 = pme[j], s2 = pse[j];
      const float nm = fmaxf(M[j], m2);
      S[j] = S[j] * __expf(M[j] - nm) + s2 * __expf(m2 - nm);
      M[j] = nm;
    }
  }
#pragma unroll
  for (int j = 0; j < 8; ++j) {
    Mf[(long long)b * C + c + j] = M[j];
    Sinv[(long long)b * C + c + j] = 1.0f / S[j];
  }
}

template <int RPT>
__global__ __launch_bounds__(256) void sm_norm_k(
    US* __restrict__ x, const float* __restrict__ Mf,
    const float* __restrict__ Sinv, int R, int C, long long sB, int NS) {
  const int b = blockIdx.y, blk = blockIdx.x;
  const int cpr = C >> 3;
  const int t = threadIdx.x;
  const int cslot = t & (cpr - 1);
  const int rsub = t / cpr;
  const int rowsPerBlock = R / NS;
  const int r0 = blk * rowsPerBlock + rsub * RPT;
  US* p = x + (long long)b * sB + (long long)r0 * C + cslot * 8;
  float M[8], Si[8];
#pragma unroll
  for (int j = 0; j < 8; ++j) {
    M[j] = Mf[(long long)b * C + cslot * 8 + j];
    Si[j] = Sinv[(long long)b * C + cslot * 8 + j];
  }
#pragma unroll
  for (int i = 0; i < RPT; ++i) {
    union { uint4 v; US s[8]; } buf;
    buf.v = *(const uint4*)(p + (long long)i * C);
#pragma unroll
    for (int j = 0; j < 8; ++j)
      buf.s[j] = f2b(__expf(b2f(buf.s[j]) - M[j]) * Si[j]);
    *(uint4*)(p + (long long)i * C) = buf.v;
  }
}

// ---------------- bf16 transpose: src [B][R][C] -> dst [B][C][R] -------------
__global__ __launch_bounds__(256) void transb_k(const US* __restrict__ src,
                                                US* __restrict__ dst, int R,
                                                int C, long long sIn,
                                                long long sOut) {
  __shared__ US L[64][65];
  const int b = blockIdx.z;
  const int r0 = blockIdx.y * 64, c0 = blockIdx.x * 64;
  const int t = threadIdx.x;
  const int lr = t >> 4, lc = (t & 15) * 4;
  const US* s = src + (long long)b * sIn;
#pragma unroll
  for (int i = 0; i < 4; ++i) {
    const int rr = r0 + lr + 16 * i;
    const ushort4 v = *(const ushort4*)&s[(long long)rr * C + c0 + lc];
    L[lr + 16 * i][lc + 0] = v.x;
    L[lr + 16 * i][lc + 1] = v.y;
    L[lr + 16 * i][lc + 2] = v.z;
    L[lr + 16 * i][lc + 3] = v.w;
  }
  __syncthreads();
#pragma unroll
  for (int i = 0; i < 4; ++i) {
    ushort4 o;
    o.x = L[lc + 0][lr + 16 * i];
    o.y = L[lc + 1][lr + 16 * i];
    o.z = L[lc + 2][lr + 16 * i];
    o.w = L[lc + 3][lr + 16 * i];
    *(ushort4*)&dst[(long long)b * sOut + (long long)(c0 + lr + 16 * i) * R + r0 + lc] = o;
  }
}

// ---------------- fused weight transposes ----------------
struct WT { const float* src; US* dst; int R, C, tileOff; };
struct WTab { WT e[11]; };

__global__ __launch_bounds__(256) void wtrans_k(WTab tab) {
  __shared__ US L[64][65];
  const int tile = blockIdx.x;
  int i = 0;
#pragma unroll
  for (int j = 1; j < 11; ++j)
    if (tab.e[j].tileOff <= tile) i = j;
  const WT w = tab.e[i];
  const int lt = tile - w.tileOff;
  const int tc = w.C / 64;
  const int r0 = (lt / tc) * 64, c0 = (lt % tc) * 64;
  const int t = threadIdx.x;
  const int lr = t >> 4, lc = (t & 15) * 4;
#pragma unroll
  for (int k = 0; k < 4; ++k) {
    const int rr = r0 + lr + 16 * k;
    const float4 v = *(const float4*)&w.src[(long long)rr * w.C + c0 + lc];
    L[lr + 16 * k][lc + 0] = f2b(v.x);
    L[lr + 16 * k][lc + 1] = f2b(v.y);
    L[lr + 16 * k][lc + 2] = f2b(v.z);
    L[lr + 16 * k][lc + 3] = f2b(v.w);
  }
  __syncthreads();
#pragma unroll
  for (int k = 0; k < 4; ++k) {
    ushort4 o;
    o.x = L[lc + 0][lr + 16 * k];
    o.y = L[lc + 1][lr + 16 * k];
    o.z = L[lc + 2][lr + 16 * k];
    o.w = L[lc + 3][lr + 16 * k];
    *(ushort4*)&w.dst[(long long)(c0 + lr + 16 * k) * w.R + r0 + lc] = o;
  }
}

// ---------------- reparameterize ----------------
__global__ __launch_bounds__(256) void reparam_k(
    const float* __restrict__ h3, const float* __restrict__ eps,
    float* __restrict__ om, float* __restrict__ olv, US* __restrict__ z,
    int total) {
  const int i = blockIdx.x * 256 + threadIdx.x;
  if (i >= total) return;
  const int j = i & 63;
  const long long r = i >> 6;
  const float m = h3[r * 128 + j];
  const float lv = h3[r * 128 + 64 + j];
  om[i] = m;
  olv[i] = lv;
  z[i] = f2b(m + expf(0.5f * lv) * eps[i]);
}

// ---------------- host dispatch ----------------
static void mm(hipStream_t st, const US* A, const US* B, const float* bias,
               void* C, void* C2, int M, int N, int K, int lda, long long sA,
               long long sB, long long sC, long long sC2, int act, int outm,
               int tn) {
  const int gx = N / tn, gy = M / 128;
  dim3 g(gx * gy * BATCH), blk(256);
#define L(TN, ACT, OUT, HB) \
  mm_k<TN, ACT, OUT, HB><<<g, blk, 0, st>>>(A, B, bias, C, C2, M, N, K, lda, sA, sB, sC, sC2, gx, gy)
  if (tn == 64) {
    if (outm == 0) L(64, 0, 0, false);
    else if (outm == 1) L(64, 0, 1, false);
    else L(64, 2, 2, true);
  } else {
    if (outm == 0) {
      if (act == 1) L(128, 1, 0, true);
      else L(128, 0, 0, false);
    } else if (outm == 1) {
      if (act == 1) L(128, 1, 1, true);
      else L(128, 0, 1, false);
    } else if (outm == 2) L(128, 0, 2, true);
    else L(128, 0, 3, false);
  }
#undef L
}

static void mm256(hipStream_t st, const US* A, const US* B, void* C, void* C2,
                  int M, int N, int K, int lda, long long sA, long long sB,
                  long long sC, long long sC2, int outm) {
  const int gx = N / 256, gy = M / 256;
  dim3 g(gx * gy * BATCH), blk(512);
  if (outm == 0)
    mm256_k<0><<<g, blk, 0, st>>>(A, B, C, C2, M, N, K, lda, sA, sB, sC, sC2, gx, gy);
  else if (outm == 1)
    mm256_k<1><<<g, blk, 0, st>>>(A, B, C, C2, M, N, K, lda, sA, sB, sC, sC2, gx, gy);
  else
    mm256_k<3><<<g, blk, 0, st>>>(A, B, C, C2, M, N, K, lda, sA, sB, sC, sC2, gx, gy);
}

static void mm64(hipStream_t st, const US* A, const US* B, const float* bias,
                 void* C, int M, int N, int K, int lda, long long sA,
                 long long sB, long long sC, int act, int outm) {
  const int gx = N / 64, gy = M / 64;
  dim3 g(gx * gy * BATCH), blk(256);
  if (outm == 0)
    mm64_k<0, 0, false><<<g, blk, 0, st>>>(A, B, nullptr, C, M, N, K, lda, sA, sB, sC, gx, gy);
  else if (outm == 1)
    mm64_k<0, 1, false><<<g, blk, 0, st>>>(A, B, nullptr, C, M, N, K, lda, sA, sB, sC, gx, gy);
  else
    mm64_k<2, 2, true><<<g, blk, 0, st>>>(A, B, bias, C, M, N, K, lda, sA, sB, sC, gx, gy);
}

extern "C" void kernel_launch(void* const* d_in, const int* in_sizes, int n_in,
                              void* d_out, int out_size, void* d_ws, size_t ws_size,
                              hipStream_t stream) {
  const float* x      = (const float*)d_in[0];
  const float* eps    = (const float*)d_in[1];
  const float* adj    = (const float*)d_in[2];
  const float* We1    = (const float*)d_in[3];
  const float* be1    = (const float*)d_in[4];
  const float* Kemb1  = (const float*)d_in[5];
  const float* Kpool1 = (const float*)d_in[6];
  const float* We2    = (const float*)d_in[7];
  const float* be2    = (const float*)d_in[8];
  const float* Kemb2  = (const float*)d_in[9];
  const float* Kpool2 = (const float*)d_in[10];
  const float* We3    = (const float*)d_in[11];
  const float* be3    = (const float*)d_in[12];
  const float* Wd0    = (const float*)d_in[13];
  const float* bd0    = (const float*)d_in[14];
  const float* Wd1    = (const float*)d_in[15];
  const float* bd1    = (const float*)d_in[16];
  const float* Wd2    = (const float*)d_in[17];
  const float* bd2    = (const float*)d_in[18];
  const float* Wdf    = (const float*)d_in[19];
  const float* bdf    = (const float*)d_in[20];
  (void)in_sizes; (void)n_in; (void)ws_size; (void)out_size;

  float* out = (float*)d_out;
  float* out_mean = out + (long long)8 * 2048 * 64;
  float* out_lv = out_mean + (long long)8 * 512 * 64;

  char* base = (char*)d_ws;
  size_t off = 0;
  auto alloc = [&](size_t bytes) {
    char* p = base + off;
    off += (bytes + 255) & ~(size_t)255;
    return p;
  };
  US* Y0   = (US*)alloc(8LL * 2048 * 64 * 2);
  US* h1b  = (US*)alloc(8LL * 2048 * 256 * 2);   // h1 natural [2048][256]
  US* g1   = (US*)alloc(8LL * 2048 * 256 * 2);
  // R1n [8][2048][1280] natural [s1|z1] — dead after transb+spmm1024; its
  // 41,943,040 B are overlaid with pm/ps (stage-2 softmax) + decode temps.
  US* R1n  = (US*)alloc(8LL * 2048 * 1280 * 2);
  float* pm = (float*)R1n;                         //  8 MB
  float* ps = pm + 8LL * 128 * 2048;               //  8 MB
  US* d4    = (US*)(ps + 8LL * 128 * 2048);        //  8 MB [8][2048][256]
  US* t5T   = d4 + 8LL * 2048 * 256;               //  4 MB
  US* d2    = t5T + 8LL * 256 * 1024;              //  4 MB
  US* t3T   = d2 + 8LL * 1024 * 256;               //  2 MB
  US* t4T   = t3T + 8LL * 256 * 512;               //  2 MB
  US* d0    = t4T + 8LL * 256 * 512;               //  2 MB
  US* t6    = d0 + 8LL * 512 * 256;                //  2 MB  (sum = 41,943,040)
  US* R1   = (US*)alloc(8LL * 2304 * 2048 * 2);  // rows [s1T|z1T|AS1T]
  US* AS1  = (US*)alloc(8LL * 2048 * 1024 * 2);
  US* P1o  = (US*)alloc(8LL * 1024 * 1280 * 2);
  US* t1T  = (US*)alloc(8LL * 256 * 1024 * 2);
  US* h2T  = (US*)alloc(8LL * 256 * 1024 * 2);
  US* g2   = (US*)alloc(8LL * 1024 * 256 * 2);
  US* R2   = (US*)alloc(8LL * 1280 * 1024 * 2);
  US* AS2  = (US*)alloc(8LL * 1024 * 512 * 2);
  US* P2o  = (US*)alloc(8LL * 512 * 768 * 2);
  US* t2T  = (US*)alloc(8LL * 128 * 512 * 2);
  float* h3f = (float*)alloc(8LL * 512 * 128 * 4);
  US* zlb  = (US*)alloc(8LL * 512 * 64 * 2);
  float* Mf   = (float*)alloc(8LL * 2048 * 4);
  float* Sinv = (float*)alloc(8LL * 2048 * 4);
  int* rowcnt = (int*)alloc(2048 * 4);
  int* rowptr = (int*)alloc(2049 * 4);
  int* colidx = (int*)alloc(2048LL * 256 * 4);
  float* vals = (float*)alloc(2048LL * 256 * 4);
  int* coloff = (int*)alloc(2048LL * 256 * 4);
  US* We1T  = (US*)alloc(256 * 64 * 2);
  US* KpKe1 = (US*)alloc(1280 * 256 * 2);
  US* We2T  = (US*)alloc(256 * 256 * 2);
  US* KpKe2 = (US*)alloc(768 * 256 * 2);
  US* We3T  = (US*)alloc(128 * 256 * 2);
  US* Wd0T  = (US*)alloc(256 * 64 * 2);
  US* Wd1T  = (US*)alloc(256 * 256 * 2);
  US* Wd2T  = (US*)alloc(256 * 256 * 2);
  US* WdfT  = (US*)alloc(64 * 256 * 2);

  // ---- weight conversions + CSR build ----
  {
    WTab tab;
    int toff = 0, i = 0;
    auto add = [&](const float* s, US* d, int R, int C) {
      tab.e[i++] = WT{s, d, R, C, toff};
      toff += (R / 64) * (C / 64);
    };
    add(We1, We1T, 64, 256);
    add(Kpool1, KpKe1, 256, 1024);
    add(Kemb1, KpKe1 + 1024 * 256, 256, 256);
    add(We2, We2T, 256, 256);
    add(Kpool2, KpKe2, 256, 512);
    add(Kemb2, KpKe2 + 512 * 256, 256, 256);
    add(We3, We3T, 256, 128);
    add(Wd0, Wd0T, 64, 256);
    add(Wd1, Wd1T, 256, 256);
    add(Wd2, Wd2T, 256, 256);
    add(Wdf, WdfT, 256, 64);
    wtrans_k<<<dim3(toff), dim3(256), 0, stream>>>(tab);
  }
  csr_count_k<<<dim3(2048), dim3(256), 0, stream>>>(adj, rowcnt);
  csr_scan_k<<<dim3(1), dim3(256), 0, stream>>>(rowcnt, rowptr);
  csr_fill_k<<<dim3(2048), dim3(256), 0, stream>>>(adj, rowptr, colidx, vals,
                                                   coloff);

  const long long SR1 = 2304LL * 2048, SR2 = 1280LL * 1024;
  const long long SR1n = 2048LL * 1280;
  US* s1T  = R1;
  US* B1   = R1 + 1024 * 2048;           // rows [z1T(256) | AS1T(1024)]
  US* AS1T = R1 + 1280 * 2048;
  US* s2T  = R2;
  US* B2   = R2 + 512 * 1024;
  US* AS2T = R2 + 768 * 1024;
  US* A1c  = P1o + 256;
  US* A2c  = P2o + 256;

  // ---------------- encode ----------------
  // Y0 = adj @ x  (SpMM from f32 x)
  spmm_k<64, true, 0, false, false><<<dim3(2048), dim3(256), 0, stream>>>(
      rowptr, colidx, vals, x, nullptr, Y0);
  // h1 = relu(Y0@We1+b)
  mm(stream, Y0, We1T, be1, h1b, nullptr, 2048, 256, 64, 64, 2048LL * 64, 0,
     2048LL * 256, 0, 1, 0, 128);
  // g1 = adj @ h1  (SpMM)
  spmm_k<256, false, 0, false, false><<<dim3(2048), dim3(256), 0, stream>>>(
      rowptr, colidx, vals, h1b, nullptr, g1);
  // R1n = g1 @ [Kp1|Ke1]  (natural [2048][1280]: cols [s1 logits | z1])
  mm256(stream, g1, KpKe1, R1n, nullptr, 2048, 1280, 256, 256, 2048LL * 256, 0,
        SR1n, 0, 0);
  // row softmax over s1 logits (cols 0..1024)
  rowsm_k<<<dim3(16384), dim3(256), 0, stream>>>(R1n, 1280, SR1n);
  // R1 = R1n^T  ([1280][2048]: rows [s1T | z1T])
  transb_k<<<dim3(20, 32, 8), dim3(256), 0, stream>>>(R1n, R1, 2048, 1280,
                                                      SR1n, SR1);
  // AS1 = adj @ s1  (SpMM wide, 16B gathers, scalar metadata)
  spmm1024_k<<<dim3(8192), dim3(256), 0, stream>>>(rowptr, coloff, vals, R1n,
                                                   SR1n, AS1);
  // AS1T into B1 region  (R1n now dead — overlay region reusable)
  transb_k<<<dim3(16, 32, 8), dim3(256), 0, stream>>>(AS1, AS1T, 2048, 1024,
                                                      2048LL * 1024, SR1);
  // P1 = s1^T @ [z1 | AS1] -> [xp1 | A1]   (256^2)
  mm256(stream, s1T, B1, P1o, nullptr, 1024, 1280, 2048, 2048, SR1, SR1,
        1024LL * 1280, 0, 0);
  mm(stream, P1o, We2T, nullptr, t1T, nullptr, 1024, 256, 256, 1280, 1024LL * 1280,
     0, 0, 256LL * 1024, 0, 1, 128);
  mm(stream, A1c, t1T, be2, h2T, nullptr, 1024, 256, 1024, 1280, 1024LL * 1280,
     256LL * 1024, 0, 256LL * 1024, 1, 1, 128);
  mm(stream, A1c, h2T, nullptr, g2, nullptr, 1024, 256, 1024, 1280, 1024LL * 1280,
     256LL * 1024, 1024LL * 256, 0, 0, 0, 128);
  mm(stream, g2, KpKe2, nullptr, R2, nullptr, 1024, 768, 256, 256, 1024LL * 256,
     0, 0, SR2, 0, 1, 128);
  sm_partial_k<4><<<dim3(64, 8), dim3(256), 0, stream>>>(s2T, pm, ps, 512, 1024, SR2, 64);
  sm_combine_k<<<dim3(8), dim3(256), 0, stream>>>(pm, ps, Mf, Sinv, 1024, 128);
  sm_norm_k<4><<<dim3(64, 8), dim3(256), 0, stream>>>(s2T, Mf, Sinv, 512, 1024, SR2, 64);
  mm(stream, A1c, s2T, nullptr, AS2, AS2T, 1024, 512, 1024, 1280, 1024LL * 1280,
     SR2, 1024LL * 512, SR2, 0, 3, 128);
  mm(stream, s2T, B2, nullptr, P2o, nullptr, 512, 768, 1024, 1024, SR2, SR2,
     512LL * 768, 0, 0, 0, 128);
  mm(stream, P2o, We3T, nullptr, t2T, nullptr, 512, 128, 256, 768, 512LL * 768,
     0, 0, 128LL * 512, 0, 1, 128);
  mm(stream, A2c, t2T, be3, h3f, nullptr, 512, 128, 512, 768, 512LL * 768,
     128LL * 512, 512LL * 128, 0, 0, 2, 128);
  reparam_k<<<dim3(8 * 512 * 64 / 256), dim3(256), 0, stream>>>(h3f, eps, out_mean,
                                                                out_lv, zlb, 8 * 512 * 64);

  // ---------------- decode ----------------
  mm(stream, zlb, Wd0T, nullptr, t3T, nullptr, 512, 256, 64, 64, 512LL * 64, 0, 0,
     256LL * 512, 0, 1, 128);
  mm(stream, A2c, t3T, bd0, d0, nullptr, 512, 256, 512, 768, 512LL * 768,
     256LL * 512, 512LL * 256, 0, 1, 0, 128);
  mm(stream, d0, Wd1T, nullptr, t4T, nullptr, 512, 256, 256, 256, 512LL * 256, 0,
     0, 256LL * 512, 0, 1, 128);
  mm(stream, AS2, t4T, bd1, d2, nullptr, 1024, 256, 512, 512, 1024LL * 512,
     256LL * 512, 1024LL * 256, 0, 1, 0, 128);
  mm(stream, d2, Wd2T, nullptr, t5T, nullptr, 1024, 256, 256, 256, 1024LL * 256, 0,
     0, 256LL * 1024, 0, 1, 128);
  mm(stream, AS1, t5T, bd2, d4, nullptr, 2048, 256, 1024, 1024, 2048LL * 1024,
     256LL * 1024, 2048LL * 256, 0, 1, 0, 128);
  mm64(stream, d4, WdfT, nullptr, t6, 2048, 64, 256, 256, 2048LL * 256, 0,
       2048LL * 64, 0, 0);
  spmm_k<64, false, 2, true, true><<<dim3(2048), dim3(256), 0, stream>>>(
      rowptr, colidx, vals, t6, bdf, out);
}

// Round 20
// 575.277 us; speedup vs baseline: 1.2525x; 1.0329x over previous
//
#include <hip/hip_runtime.h>
#include <math.h>

#define BATCH 8
typedef unsigned short US;

typedef __attribute__((ext_vector_type(8))) short short8;
typedef __attribute__((ext_vector_type(4))) float f32x4;

__device__ __forceinline__ US f2b(float f) {
  union { float f; unsigned u; } v; v.f = f;
  unsigned r = v.u + 0x7fffu + ((v.u >> 16) & 1u);
  return (US)(r >> 16);
}
__device__ __forceinline__ float b2f(US h) {
  union { unsigned u; float f; } v; v.u = ((unsigned)h) << 16;
  return v.f;
}

__device__ __forceinline__ void gload16(const US* g, US* l) {
  __builtin_amdgcn_global_load_lds(
      (const __attribute__((address_space(1))) unsigned int*)g,
      (__attribute__((address_space(3))) unsigned int*)l, 16, 0, 0);
}

// LDS tile [rows][64] linear, XOR swizzle: 16B-cell index ^= (row&7).
__device__ __forceinline__ int lidx2(int r, int ko) {
  return r * 64 + ((((ko >> 3) ^ (r & 7)) << 3));
}

// ================= 128^2 1-phase MFMA GEMM (verified r3-r7) ==================
// C = act(A@B + bias). A bf16 phys [M][lda], B bf16 phys [N][K].
// OUT: 0=bf16 [M][N], 1=bf16 [N][M], 2=f32 [M][N], 3=dual bf16 [M][N]+[N][M].
template <int TN, int ACT, int OUT, bool HASBIAS>
__global__ __launch_bounds__(256) void mm_k(
    const US* __restrict__ A, const US* __restrict__ B,
    const float* __restrict__ bias, void* __restrict__ Cv, void* __restrict__ Cv2,
    int M, int N, int K, int lda, long long sA, long long sB, long long sC,
    long long sC2, int gx, int gy) {
  constexpr int JF = TN / 32;
  __shared__ US As[128 * 64];
  __shared__ US Bs[TN * 64];

  const int nb = blockIdx.x;
  const int nb2 = (nb & 7) * (gx * gy) + (nb >> 3);
  const int bx = nb2 % gx;
  const int by = (nb2 / gx) % gy;
  const int b = nb2 / (gx * gy);

  A += (long long)b * sA;
  B += (long long)b * sB;
  const int m0 = by * 128, n0 = bx * TN;
  const int t = threadIdx.x, lane = t & 63, w = t >> 6;
  const int wm = (w >> 1) * 64, wn = (w & 1) * (TN / 2);
  const int l15 = lane & 15, lg = lane >> 4;
  const int lrow = lane >> 3;
  const int gcell = (((lane & 7) ^ lrow) << 3);

  f32x4 acc[4][JF];
#pragma unroll
  for (int i = 0; i < 4; ++i)
#pragma unroll
    for (int j = 0; j < JF; ++j) acc[i][j] = (f32x4){0.f, 0.f, 0.f, 0.f};

  for (int k0 = 0; k0 < K; k0 += 64) {
#pragma unroll
    for (int i = 0; i < 4; ++i) {
      const int g = w * 4 + i;
      gload16(A + (long long)(m0 + g * 8 + lrow) * lda + k0 + gcell, &As[g * 512]);
    }
#pragma unroll
    for (int i = 0; i < TN / 32; ++i) {
      const int g = w * (TN / 32) + i;
      gload16(B + (long long)(n0 + g * 8 + lrow) * K + k0 + gcell, &Bs[g * 512]);
    }
    __syncthreads();

#pragma unroll
    for (int kk = 0; kk < 2; ++kk) {
      const int ko = kk * 32 + lg * 8;
      short8 af[4], bf[JF];
#pragma unroll
      for (int i = 0; i < 4; ++i)
        af[i] = *(const short8*)&As[lidx2(wm + i * 16 + l15, ko)];
#pragma unroll
      for (int j = 0; j < JF; ++j)
        bf[j] = *(const short8*)&Bs[lidx2(wn + j * 16 + l15, ko)];
#pragma unroll
      for (int i = 0; i < 4; ++i)
#pragma unroll
        for (int j = 0; j < JF; ++j)
          acc[i][j] = __builtin_amdgcn_mfma_f32_16x16x32_bf16(af[i], bf[j],
                                                              acc[i][j], 0, 0, 0);
    }
    __syncthreads();
  }

  const long long cb = (long long)b * sC;
  const long long cb2 = (long long)b * sC2;
#pragma unroll
  for (int fj = 0; fj < JF; ++fj) {
    const int col = n0 + wn + fj * 16 + l15;
    const float bsv = HASBIAS ? bias[col] : 0.0f;
#pragma unroll
    for (int fi = 0; fi < 4; ++fi) {
      const int row0 = m0 + wm + fi * 16 + lg * 4;
      float v[4];
#pragma unroll
      for (int e = 0; e < 4; ++e) {
        float x = acc[fi][fj][e] + bsv;
        if (ACT == 1) x = fmaxf(x, 0.0f);
        if (ACT == 2) x = (x > 20.0f) ? x : log1pf(expf(x));
        v[e] = x;
      }
      if (OUT == 1 || OUT == 3) {
        ushort4 pk;
        pk.x = f2b(v[0]); pk.y = f2b(v[1]); pk.z = f2b(v[2]); pk.w = f2b(v[3]);
        US* c2 = (OUT == 3) ? (US*)Cv2 : (US*)Cv;
        *(ushort4*)&c2[cb2 + (long long)col * M + row0] = pk;
      }
      if (OUT == 0 || OUT == 3) {
#pragma unroll
        for (int e = 0; e < 4; ++e)
          ((US*)Cv)[cb + (long long)(row0 + e) * N + col] = f2b(v[e]);
      }
      if (OUT == 2) {
#pragma unroll
        for (int e = 0; e < 4; ++e)
          ((float*)Cv)[cb + (long long)(row0 + e) * N + col] = v[e];
      }
    }
  }
}

// ================= 256^2 deep-pipelined MFMA GEMM (r7-exact) =================
template <int OUT>
__global__ __launch_bounds__(512, 1) void mm256_k(
    const US* __restrict__ A, const US* __restrict__ B, void* __restrict__ Cv,
    void* __restrict__ Cv2, int M, int N, int K, int lda, long long sA,
    long long sB, long long sC, long long sC2, int gx, int gy) {
  __shared__ US lds[8][8192];

  const int nb = blockIdx.x;
  const int chunk = gx * gy;
  const int nb2 = (nb & 7) * chunk + (nb >> 3);
  const int bx = nb2 % gx;
  const int by = (nb2 / gx) % gy;
  const int b = nb2 / chunk;

  const int m0 = by * 256, n0 = bx * 256;
  const int tid = threadIdx.x;
  const int lane = tid & 63, w = tid >> 6;
  const int wr = w >> 2, wc = w & 3;
  const int l15 = lane & 15, lg = lane >> 4;

  const US* Ab = A + (long long)b * sA + (long long)m0 * lda;
  const US* Bb = B + (long long)b * sB + (long long)n0 * K;
  const int NT = K >> 6;

  auto stageH = [&](int H) {
    const int s = H >> 2, h = H & 3;
    const int ab = h & 1, kk = h >> 1;
    US* reg = &lds[ab * 4 + (s & 1) * 2 + kk][0];
    const US* src = ab ? Bb : Ab;
    const int ld = ab ? K : lda;
#pragma unroll
    for (int i = 0; i < 2; ++i) {
      const int rbase = (w * 2 + i) * 16;
      const int r = rbase + (lane >> 2);
      const int csrc = (lane & 3) ^ ((r >> 1) & 3);
      gload16(src + (long long)r * ld + s * 64 + kk * 32 + csrc * 8,
              reg + rbase * 32);
    }
  };

  f32x4 acc[8][4];
#pragma unroll
  for (int m = 0; m < 8; ++m)
#pragma unroll
    for (int j = 0; j < 4; ++j) acc[m][j] = (f32x4){0.f, 0.f, 0.f, 0.f};
  short8 a4[4], b4[4];

  for (int H = 0; H < 6; ++H) stageH(H);
  asm volatile("s_waitcnt vmcnt(4)" ::: "memory");
  __builtin_amdgcn_s_barrier();

#define PH(kk_, mh_, DOH, HV, VM, tt)                                          \
  {                                                                            \
    const US* Ar = &lds[((tt) & 1) * 2 + (kk_)][0];                            \
    const US* Br = &lds[4 + ((tt) & 1) * 2 + (kk_)][0];                        \
    _Pragma("unroll") for (int i = 0; i < 4; ++i) {                            \
      const int r = wr * 128 + (mh_) * 64 + i * 16 + l15;                      \
      a4[i] = *(const short8*)&Ar[r * 32 + ((lg ^ ((r >> 1) & 3)) << 3)];      \
    }                                                                          \
    if ((mh_) == 0) {                                                          \
      _Pragma("unroll") for (int j = 0; j < 4; ++j) {                          \
        const int rr = wc * 64 + j * 16 + l15;                                 \
        b4[j] = *(const short8*)&Br[rr * 32 + ((lg ^ ((rr >> 1) & 3)) << 3)];  \
      }                                                                        \
    }                                                                          \
    if (DOH) stageH(HV);                                                       \
    if ((VM) == 1) asm volatile("s_waitcnt vmcnt(4)" ::: "memory");            \
    if ((VM) == 2) asm volatile("s_waitcnt vmcnt(0)" ::: "memory");            \
    __builtin_amdgcn_s_barrier();                                              \
    __builtin_amdgcn_s_setprio(1);                                             \
    _Pragma("unroll") for (int i = 0; i < 4; ++i)                              \
      _Pragma("unroll") for (int j = 0; j < 4; ++j)                            \
        acc[(mh_) * 4 + i][j] = __builtin_amdgcn_mfma_f32_16x16x32_bf16(       \
            a4[i], b4[j], acc[(mh_) * 4 + i][j], 0, 0, 0);                     \
    __builtin_amdgcn_s_setprio(0);                                             \
    __builtin_amdgcn_s_barrier();                                              \
  }

  int t2 = 0;
  for (; t2 < NT - 2; ++t2) {
    PH(0, 0, true, 4 * t2 + 6, 0, t2)
    PH(0, 1, true, 4 * t2 + 7, 0, t2)
    PH(1, 0, true, 4 * t2 + 8, 0, t2)
    PH(1, 1, true, 4 * t2 + 9, 1, t2)
  }
  PH(0, 0, true, 4 * (NT - 2) + 6, 0, NT - 2)
  PH(0, 1, true, 4 * (NT - 2) + 7, 0, NT - 2)
  PH(1, 0, false, 0, 0, NT - 2)
  PH(1, 1, false, 0, 2, NT - 2)
  PH(0, 0, false, 0, 0, NT - 1)
  PH(0, 1, false, 0, 0, NT - 1)
  PH(1, 0, false, 0, 0, NT - 1)
  PH(1, 1, false, 0, 0, NT - 1)
#undef PH

  const long long cb = (long long)b * sC;
  const long long cb2 = (long long)b * sC2;
#pragma unroll
  for (int j = 0; j < 4; ++j) {
    const int col = n0 + wc * 64 + j * 16 + l15;
#pragma unroll
    for (int m = 0; m < 8; ++m) {
      const int row0 = m0 + wr * 128 + m * 16 + lg * 4;
      if (OUT == 1 || OUT == 3) {
        ushort4 pk;
        pk.x = f2b(acc[m][j][0]); pk.y = f2b(acc[m][j][1]);
        pk.z = f2b(acc[m][j][2]); pk.w = f2b(acc[m][j][3]);
        US* c2 = (OUT == 3) ? (US*)Cv2 : (US*)Cv;
        *(ushort4*)&c2[cb2 + (long long)col * M + row0] = pk;
      }
      if (OUT == 0 || OUT == 3) {
#pragma unroll
        for (int e = 0; e < 4; ++e)
          ((US*)Cv)[cb + (long long)(row0 + e) * N + col] = f2b(acc[m][j][e]);
      }
    }
  }
}

// ================= 64x64 4-deep pipelined MFMA GEMM (skinny N) ===============
template <int ACT, int OUT, bool HASBIAS>
__global__ __launch_bounds__(256) void mm64_k(
    const US* __restrict__ A, const US* __restrict__ B,
    const float* __restrict__ bias, void* __restrict__ Cv,
    int M, int N, int K, int lda, long long sA, long long sB, long long sC,
    int gx, int gy) {
  __shared__ US As[4][4096];
  __shared__ US Bs[4][4096];

  const int nb = blockIdx.x;
  const int chunk = gx * gy;
  const int nb2 = (nb & 7) * chunk + (nb >> 3);
  const int bx = nb2 % gx;
  const int by = (nb2 / gx) % gy;
  const int b = nb2 / chunk;

  const int m0 = by * 64, n0 = bx * 64;
  const int tid = threadIdx.x;
  const int lane = tid & 63, w = tid >> 6;
  const int wr = w >> 1, wc = w & 1;
  const int l15 = lane & 15, lg = lane >> 4;
  const int lrow = lane >> 3;
  const int gcell = (((lane & 7) ^ lrow) << 3);

  const US* Ag = A + (long long)b * sA + (long long)m0 * lda;
  const US* Bg = B + (long long)b * sB + (long long)n0 * K;
  const int NT = K >> 6;

  auto stage = [&](int tt) {
    US* Ad = &As[tt & 3][0];
    US* Bd = &Bs[tt & 3][0];
    const int k0 = tt * 64;
#pragma unroll
    for (int i = 0; i < 2; ++i) {
      const int g = w * 2 + i;
      const int r = g * 8 + lrow;
      gload16(Ag + (long long)r * lda + k0 + gcell, Ad + g * 512);
      gload16(Bg + (long long)r * K + k0 + gcell, Bd + g * 512);
    }
  };

  f32x4 acc[2][2];
#pragma unroll
  for (int i = 0; i < 2; ++i)
#pragma unroll
    for (int j = 0; j < 2; ++j) acc[i][j] = (f32x4){0.f, 0.f, 0.f, 0.f};

  for (int i = 0; i < 3 && i < NT; ++i) stage(i);

  for (int t = 0; t < NT; ++t) {
    if (t + 3 < NT) stage(t + 3);
    const int rem = NT - 1 - t;
    if (rem >= 3) asm volatile("s_waitcnt vmcnt(12)" ::: "memory");
    else if (rem == 2) asm volatile("s_waitcnt vmcnt(8)" ::: "memory");
    else if (rem == 1) asm volatile("s_waitcnt vmcnt(4)" ::: "memory");
    else asm volatile("s_waitcnt vmcnt(0)" ::: "memory");
    asm volatile("s_barrier" ::: "memory");
    const US* Ad = &As[t & 3][0];
    const US* Bd = &Bs[t & 3][0];
#pragma unroll
    for (int kk = 0; kk < 2; ++kk) {
      const int ko = kk * 32 + lg * 8;
      short8 af[2], bf[2];
      af[0] = *(const short8*)&Ad[lidx2(wr * 32 + l15, ko)];
      af[1] = *(const short8*)&Ad[lidx2(wr * 32 + 16 + l15, ko)];
      bf[0] = *(const short8*)&Bd[lidx2(wc * 32 + l15, ko)];
      bf[1] = *(const short8*)&Bd[lidx2(wc * 32 + 16 + l15, ko)];
#pragma unroll
      for (int i = 0; i < 2; ++i)
#pragma unroll
        for (int j = 0; j < 2; ++j)
          acc[i][j] = __builtin_amdgcn_mfma_f32_16x16x32_bf16(af[i], bf[j],
                                                              acc[i][j], 0, 0, 0);
    }
    asm volatile("s_barrier" ::: "memory");
  }

  const long long cb = (long long)b * sC;
#pragma unroll
  for (int fj = 0; fj < 2; ++fj) {
    const int col = n0 + wc * 32 + fj * 16 + l15;
    const float bsv = HASBIAS ? bias[col] : 0.0f;
#pragma unroll
    for (int fi = 0; fi < 2; ++fi) {
      const int row0 = m0 + wr * 32 + fi * 16 + lg * 4;
      float v[4];
#pragma unroll
      for (int e = 0; e < 4; ++e) {
        float x = acc[fi][fj][e] + bsv;
        if (ACT == 1) x = fmaxf(x, 0.0f);
        if (ACT == 2) x = (x > 20.0f) ? x : log1pf(expf(x));
        v[e] = x;
      }
      if (OUT == 1) {
        ushort4 pk;
        pk.x = f2b(v[0]); pk.y = f2b(v[1]); pk.z = f2b(v[2]); pk.w = f2b(v[3]);
        *(ushort4*)&((US*)Cv)[cb + (long long)col * M + row0] = pk;
      } else if (OUT == 0) {
#pragma unroll
        for (int e = 0; e < 4; ++e)
          ((US*)Cv)[cb + (long long)(row0 + e) * N + col] = f2b(v[e]);
      } else {
#pragma unroll
        for (int e = 0; e < 4; ++e)
          ((float*)Cv)[cb + (long long)(row0 + e) * N + col] = v[e];
      }
    }
  }
}

// ================= CSR build (deterministic, no global atomics) ==============
__global__ __launch_bounds__(256) void csr_count_k(const float* __restrict__ adj,
                                                   int* __restrict__ rowcnt) {
  const int row = blockIdx.x, t = threadIdx.x;
  const float* p = adj + (long long)row * 2048;
  int c = 0;
  for (int j = t; j < 2048; j += 256) c += (p[j] != 0.0f);
  __shared__ int red[256];
  red[t] = c;
  __syncthreads();
  for (int s = 128; s; s >>= 1) {
    if (t < s) red[t] += red[t + s];
    __syncthreads();
  }
  if (t == 0) rowcnt[row] = red[0];
}

__global__ __launch_bounds__(256) void csr_scan_k(const int* __restrict__ rowcnt,
                                                  int* __restrict__ rowptr) {
  __shared__ int red[256];
  const int t = threadIdx.x;
  int base = 0;
  for (int ch = 0; ch < 8; ++ch) {
    const int v = rowcnt[ch * 256 + t];
    red[t] = v;
    __syncthreads();
    for (int s = 1; s < 256; s <<= 1) {
      const int add = (t >= s) ? red[t - s] : 0;
      __syncthreads();
      red[t] += add;
      __syncthreads();
    }
    rowptr[ch * 256 + t] = base + red[t] - v;
    const int tot = red[255];
    __syncthreads();
    base += tot;
  }
  if (t == 0) rowptr[2048] = base;
}

__global__ __launch_bounds__(256) void csr_fill_k(const float* __restrict__ adj,
                                                  const int* __restrict__ rowptr,
                                                  int* __restrict__ colidx,
                                                  float* __restrict__ vals,
                                                  int* __restrict__ coloff) {
  const int row = blockIdx.x, t = threadIdx.x;
  const float* p = adj + (long long)row * 2048;
  int cnt = 0;
  for (int j = t; j < 2048; j += 256) cnt += (p[j] != 0.0f);
  __shared__ int red[256];
  red[t] = cnt;
  __syncthreads();
  for (int s = 1; s < 256; s <<= 1) {
    const int add = (t >= s) ? red[t - s] : 0;
    __syncthreads();
    red[t] += add;
    __syncthreads();
  }
  int off = rowptr[row] + red[t] - cnt;
  for (int j = t; j < 2048; j += 256) {
    const float a = p[j];
    if (a != 0.0f) {
      colidx[off] = j;
      vals[off] = a;
      coloff[off] = j * 1280;  // pre-scaled element offset for spmm1024 (ldx)
      ++off;
    }
  }
}

// ================= SpMM narrow: Y[b][row][c] = act(sum_j a_rj X[b][j][c]+bias)
template <int COLS, bool INF32, int ACT, bool OUTF32, bool HASBIAS>
__global__ __launch_bounds__(256) void spmm_k(
    const int* __restrict__ rowptr, const int* __restrict__ colidx,
    const float* __restrict__ vals, const void* __restrict__ Xv,
    const float* __restrict__ bias, void* __restrict__ Yv) {
  constexpr int BP = 256 / COLS;
  constexpr int NP = BATCH / BP;
  const int row = blockIdx.x;
  const int t = threadIdx.x;
  const int c = t & (COLS - 1);
  const int bsub = t / COLS;
  const int e0 = rowptr[row], e1 = rowptr[row + 1];
  float acc[NP];
#pragma unroll
  for (int p = 0; p < NP; ++p) acc[p] = 0.0f;
  for (int e = e0; e < e1; ++e) {
    const int j = colidx[e];
    const float a = vals[e];
#pragma unroll
    for (int p = 0; p < NP; ++p) {
      const int b = p * BP + bsub;
      const long long idx = ((long long)b * 2048 + j) * COLS + c;
      const float xv = INF32 ? ((const float*)Xv)[idx] : b2f(((const US*)Xv)[idx]);
      acc[p] += a * xv;
    }
  }
#pragma unroll
  for (int p = 0; p < NP; ++p) {
    const int b = p * BP + bsub;
    float v = acc[p] + (HASBIAS ? bias[c] : 0.0f);
    if (ACT == 2) v = (v > 20.0f) ? v : log1pf(expf(v));
    const long long idx = ((long long)b * 2048 + row) * COLS + c;
    if (OUTF32) ((float*)Yv)[idx] = v;
    else ((US*)Yv)[idx] = f2b(v);
  }
}

// ================= SpMM wide (1024 cols), 16B gathers, scalar metadata =======
__global__ __launch_bounds__(256) void spmm1024_k(
    const int* __restrict__ rowptr, const int* __restrict__ coloff,
    const float* __restrict__ vals, const US* __restrict__ X,
    long long sX, US* __restrict__ Y) {
  const int bid = blockIdx.x;
  const int b = bid & 7;
  const int rp = bid >> 3;
  const int t = threadIdx.x;
  const int row = __builtin_amdgcn_readfirstlane(rp * 2 + (t >> 7));
  const int c0 = (t & 127) * 8;
  const US* Xb = X + (long long)b * sX + c0;
  const int e0 = __builtin_amdgcn_readfirstlane(rowptr[row]);
  const int e1 = __builtin_amdgcn_readfirstlane(rowptr[row + 1]);
  union U8 { uint4 v; US s[8]; };
  float p0[8] = {0.f, 0.f, 0.f, 0.f, 0.f, 0.f, 0.f, 0.f};
  float p1[8] = {0.f, 0.f, 0.f, 0.f, 0.f, 0.f, 0.f, 0.f};
  int e = e0;
  for (; e + 4 <= e1; e += 4) {
    const int o0 = __builtin_amdgcn_readfirstlane(coloff[e + 0]);
    const int o1 = __builtin_amdgcn_readfirstlane(coloff[e + 1]);
    const int o2 = __builtin_amdgcn_readfirstlane(coloff[e + 2]);
    const int o3 = __builtin_amdgcn_readfirstlane(coloff[e + 3]);
    const float a0 = vals[e + 0], a1 = vals[e + 1];
    const float a2 = vals[e + 2], a3 = vals[e + 3];
    U8 x0, x1, x2, x3;
    x0.v = *(const uint4*)&Xb[o0];
    x1.v = *(const uint4*)&Xb[o1];
    x2.v = *(const uint4*)&Xb[o2];
    x3.v = *(const uint4*)&Xb[o3];
#pragma unroll
    for (int q = 0; q < 8; ++q) {
      p0[q] += a0 * b2f(x0.s[q]) + a2 * b2f(x2.s[q]);
      p1[q] += a1 * b2f(x1.s[q]) + a3 * b2f(x3.s[q]);
    }
  }
  for (; e < e1; ++e) {
    const int o = __builtin_amdgcn_readfirstlane(coloff[e]);
    const float a = vals[e];
    U8 xv;
    xv.v = *(const uint4*)&Xb[o];
#pragma unroll
    for (int q = 0; q < 8; ++q) p0[q] += a * b2f(xv.s[q]);
  }
  US o[8];
#pragma unroll
  for (int q = 0; q < 8; ++q) o[q] = f2b(p0[q] + p1[q]);
  *(uint4*)&Y[((long long)b * 2048 + row) * 1024 + c0] = *(uint4*)o;
}

// ================= row softmax over cols [0,1024) of x [B][2048][ldx] ========
__global__ __launch_bounds__(256) void rowsm_k(US* __restrict__ x, int ldx,
                                               long long sB) {
  __shared__ float red[256];
  const int bid = blockIdx.x;
  const int b = bid & 7;
  const int row = bid >> 3;
  const int t = threadIdx.x;
  US* p = x + (long long)b * sB + (long long)row * ldx + t * 4;
  union { ushort4 v; US s[4]; } buf;
  buf.v = *(const ushort4*)p;
  float v[4];
#pragma unroll
  for (int i = 0; i < 4; ++i) v[i] = b2f(buf.s[i]);
  float mx = fmaxf(fmaxf(v[0], v[1]), fmaxf(v[2], v[3]));
  red[t] = mx;
  __syncthreads();
  for (int s = 128; s; s >>= 1) {
    if (t < s) red[t] = fmaxf(red[t], red[t + s]);
    __syncthreads();
  }
  mx = red[0];
  __syncthreads();
  float sum = 0.f;
#pragma unroll
  for (int i = 0; i < 4; ++i) {
    v[i] = __expf(v[i] - mx);
    sum += v[i];
  }
  red[t] = sum;
  __syncthreads();
  for (int s = 128; s; s >>= 1) {
    if (t < s) red[t] += red[t + s];
    __syncthreads();
  }
  const float inv = 1.0f / red[0];
#pragma unroll
  for (int i = 0; i < 4; ++i) buf.s[i] = f2b(v[i] * inv);
  *(ushort4*)p = buf.v;
}

// ---------------- split column softmax over R of x [B][R][C] (stage 2) -------
template <int RPT>
__global__ __launch_bounds__(256) void sm_partial_k(
    const US* __restrict__ x, float* __restrict__ pm, float* __restrict__ ps,
    int R, int C, long long sB, int NS) {
  const int b = blockIdx.y, blk = blockIdx.x;
  const int cpr = C >> 3;
  const int t = threadIdx.x;
  const int cslot = t & (cpr - 1);
  const int rsub = t / cpr;
  const int nsub = 256 / cpr;
  const int rowsPerBlock = R / NS;
  const int r0 = blk * rowsPerBlock + rsub * RPT;
  const US* p = x + (long long)b * sB + (long long)r0 * C + cslot * 8;
  union { uint4 v; US s[8]; } buf[RPT];
#pragma unroll
  for (int i = 0; i < RPT; ++i) buf[i].v = *(const uint4*)(p + (long long)i * C);
  float M[8], S[8];
#pragma unroll
  for (int j = 0; j < 8; ++j) M[j] = b2f(buf[0].s[j]);
#pragma unroll
  for (int i = 1; i < RPT; ++i)
#pragma unroll
    for (int j = 0; j < 8; ++j) M[j] = fmaxf(M[j], b2f(buf[i].s[j]));
#pragma unroll
  for (int j = 0; j < 8; ++j) S[j] = 0.f;
#pragma unroll
  for (int i = 0; i < RPT; ++i)
#pragma unroll
    for (int j = 0; j < 8; ++j) S[j] += __expf(b2f(buf[i].s[j]) - M[j]);
  const long long pi = (long long)(b * NS + blk) * nsub + rsub;
  float* pmo = pm + pi * C + cslot * 8;
  float* pso = ps + pi * C + cslot * 8;
  *(float4*)pmo = make_float4(M[0], M[1], M[2], M[3]);
  *(float4*)(pmo + 4) = make_float4(M[4], M[5], M[6], M[7]);
  *(float4*)pso = make_float4(S[0], S[1], S[2], S[3]);
  *(float4*)(pso + 4) = make_float4(S[4], S[5], S[6], S[7]);
}

__global__ __launch_bounds__(256) void sm_combine_k(
    const float* __restrict__ pm, const float* __restrict__ ps,
    float* __restrict__ Mf, float* __restrict__ Sinv, int C, int NP) {
  const int b = blockIdx.x, t = threadIdx.x;
  const int cpr = C >> 3;
  if (t >= cpr) return;
  const int c = t * 8;
  const float* pmB = pm + (long long)b * NP * C + c;
  const float* psB = ps + (long long)b * NP * C + c;
  float M[8], S[8];
#pragma unroll
  for (int j = 0; j < 8; ++j) { M[j] = pmB[j]; S[j] = psB[j]; }
  for (int e = 1; e < NP; ++e) {
    const float* pme = pmB + (long long)e * C;
    const float* pse = psB + (long long)e * C;
#pragma unroll
    for (int j = 0; j < 8; ++j) {
      const float m2 = pme[j], s2 = pse[j];
      const float nm = fmaxf(M[j], m2);
      S[j] = S[j] * __expf(M[j] - nm) + s2 * __expf(m2 - nm);
      M[j] = nm;
    }
  }
#pragma unroll
  for (int j = 0; j < 8; ++j) {
    Mf[(long long)b * C + c + j] = M[j];
    Sinv[(long long)b * C + c + j] = 1.0f / S[j];
  }
}

template <int RPT>
__global__ __launch_bounds__(256) void sm_norm_k(
    US* __restrict__ x, const float* __restrict__ Mf,
    const float* __restrict__ Sinv, int R, int C, long long sB, int NS) {
  const int b = blockIdx.y, blk = blockIdx.x;
  const int cpr = C >> 3;
  const int t = threadIdx.x;
  const int cslot = t & (cpr - 1);
  const int rsub = t / cpr;
  const int rowsPerBlock = R / NS;
  const int r0 = blk * rowsPerBlock + rsub * RPT;
  US* p = x + (long long)b * sB + (long long)r0 * C + cslot * 8;
  float M[8], Si[8];
#pragma unroll
  for (int j = 0; j < 8; ++j) {
    M[j] = Mf[(long long)b * C + cslot * 8 + j];
    Si[j] = Sinv[(long long)b * C + cslot * 8 + j];
  }
#pragma unroll
  for (int i = 0; i < RPT; ++i) {
    union { uint4 v; US s[8]; } buf;
    buf.v = *(const uint4*)(p + (long long)i * C);
#pragma unroll
    for (int j = 0; j < 8; ++j)
      buf.s[j] = f2b(__expf(b2f(buf.s[j]) - M[j]) * Si[j]);
    *(uint4*)(p + (long long)i * C) = buf.v;
  }
}

// ---------------- bf16 transpose: src [B][R][C] -> dst [B][C][R] -------------
__global__ __launch_bounds__(256) void transb_k(const US* __restrict__ src,
                                                US* __restrict__ dst, int R,
                                                int C, long long sIn,
                                                long long sOut) {
  __shared__ US L[64][65];
  const int b = blockIdx.z;
  const int r0 = blockIdx.y * 64, c0 = blockIdx.x * 64;
  const int t = threadIdx.x;
  const int lr = t >> 4, lc = (t & 15) * 4;
  const US* s = src + (long long)b * sIn;
#pragma unroll
  for (int i = 0; i < 4; ++i) {
    const int rr = r0 + lr + 16 * i;
    const ushort4 v = *(const ushort4*)&s[(long long)rr * C + c0 + lc];
    L[lr + 16 * i][lc + 0] = v.x;
    L[lr + 16 * i][lc + 1] = v.y;
    L[lr + 16 * i][lc + 2] = v.z;
    L[lr + 16 * i][lc + 3] = v.w;
  }
  __syncthreads();
#pragma unroll
  for (int i = 0; i < 4; ++i) {
    ushort4 o;
    o.x = L[lc + 0][lr + 16 * i];
    o.y = L[lc + 1][lr + 16 * i];
    o.z = L[lc + 2][lr + 16 * i];
    o.w = L[lc + 3][lr + 16 * i];
    *(ushort4*)&dst[(long long)b * sOut + (long long)(c0 + lr + 16 * i) * R + r0 + lc] = o;
  }
}

// ---------------- fused weight transposes ----------------
struct WT { const float* src; US* dst; int R, C, tileOff; };
struct WTab { WT e[11]; };

__global__ __launch_bounds__(256) void wtrans_k(WTab tab) {
  __shared__ US L[64][65];
  const int tile = blockIdx.x;
  int i = 0;
#pragma unroll
  for (int j = 1; j < 11; ++j)
    if (tab.e[j].tileOff <= tile) i = j;
  const WT w = tab.e[i];
  const int lt = tile - w.tileOff;
  const int tc = w.C / 64;
  const int r0 = (lt / tc) * 64, c0 = (lt % tc) * 64;
  const int t = threadIdx.x;
  const int lr = t >> 4, lc = (t & 15) * 4;
#pragma unroll
  for (int k = 0; k < 4; ++k) {
    const int rr = r0 + lr + 16 * k;
    const float4 v = *(const float4*)&w.src[(long long)rr * w.C + c0 + lc];
    L[lr + 16 * k][lc + 0] = f2b(v.x);
    L[lr + 16 * k][lc + 1] = f2b(v.y);
    L[lr + 16 * k][lc + 2] = f2b(v.z);
    L[lr + 16 * k][lc + 3] = f2b(v.w);
  }
  __syncthreads();
#pragma unroll
  for (int k = 0; k < 4; ++k) {
    ushort4 o;
    o.x = L[lc + 0][lr + 16 * k];
    o.y = L[lc + 1][lr + 16 * k];
    o.z = L[lc + 2][lr + 16 * k];
    o.w = L[lc + 3][lr + 16 * k];
    *(ushort4*)&w.dst[(long long)(c0 + lr + 16 * k) * w.R + r0 + lc] = o;
  }
}

// ---------------- reparameterize ----------------
__global__ __launch_bounds__(256) void reparam_k(
    const float* __restrict__ h3, const float* __restrict__ eps,
    float* __restrict__ om, float* __restrict__ olv, US* __restrict__ z,
    int total) {
  const int i = blockIdx.x * 256 + threadIdx.x;
  if (i >= total) return;
  const int j = i & 63;
  const long long r = i >> 6;
  const float m = h3[r * 128 + j];
  const float lv = h3[r * 128 + 64 + j];
  om[i] = m;
  olv[i] = lv;
  z[i] = f2b(m + expf(0.5f * lv) * eps[i]);
}

// ---------------- host dispatch ----------------
static void mm(hipStream_t st, const US* A, const US* B, const float* bias,
               void* C, void* C2, int M, int N, int K, int lda, long long sA,
               long long sB, long long sC, long long sC2, int act, int outm,
               int tn) {
  const int gx = N / tn, gy = M / 128;
  dim3 g(gx * gy * BATCH), blk(256);
#define L(TN, ACT, OUT, HB) \
  mm_k<TN, ACT, OUT, HB><<<g, blk, 0, st>>>(A, B, bias, C, C2, M, N, K, lda, sA, sB, sC, sC2, gx, gy)
  if (tn == 64) {
    if (outm == 0) L(64, 0, 0, false);
    else if (outm == 1) L(64, 0, 1, false);
    else L(64, 2, 2, true);
  } else {
    if (outm == 0) {
      if (act == 1) L(128, 1, 0, true);
      else L(128, 0, 0, false);
    } else if (outm == 1) {
      if (act == 1) L(128, 1, 1, true);
      else L(128, 0, 1, false);
    } else if (outm == 2) L(128, 0, 2, true);
    else L(128, 0, 3, false);
  }
#undef L
}

static void mm256(hipStream_t st, const US* A, const US* B, void* C, void* C2,
                  int M, int N, int K, int lda, long long sA, long long sB,
                  long long sC, long long sC2, int outm) {
  const int gx = N / 256, gy = M / 256;
  dim3 g(gx * gy * BATCH), blk(512);
  if (outm == 0)
    mm256_k<0><<<g, blk, 0, st>>>(A, B, C, C2, M, N, K, lda, sA, sB, sC, sC2, gx, gy);
  else if (outm == 1)
    mm256_k<1><<<g, blk, 0, st>>>(A, B, C, C2, M, N, K, lda, sA, sB, sC, sC2, gx, gy);
  else
    mm256_k<3><<<g, blk, 0, st>>>(A, B, C, C2, M, N, K, lda, sA, sB, sC, sC2, gx, gy);
}

static void mm64(hipStream_t st, const US* A, const US* B, const float* bias,
                 void* C, int M, int N, int K, int lda, long long sA,
                 long long sB, long long sC, int act, int outm) {
  const int gx = N / 64, gy = M / 64;
  dim3 g(gx * gy * BATCH), blk(256);
  if (outm == 0)
    mm64_k<0, 0, false><<<g, blk, 0, st>>>(A, B, nullptr, C, M, N, K, lda, sA, sB, sC, gx, gy);
  else if (outm == 1)
    mm64_k<0, 1, false><<<g, blk, 0, st>>>(A, B, nullptr, C, M, N, K, lda, sA, sB, sC, gx, gy);
  else
    mm64_k<2, 2, true><<<g, blk, 0, st>>>(A, B, bias, C, M, N, K, lda, sA, sB, sC, gx, gy);
}

extern "C" void kernel_launch(void* const* d_in, const int* in_sizes, int n_in,
                              void* d_out, int out_size, void* d_ws, size_t ws_size,
                              hipStream_t stream) {
  const float* x      = (const float*)d_in[0];
  const float* eps    = (const float*)d_in[1];
  const float* adj    = (const float*)d_in[2];
  const float* We1    = (const float*)d_in[3];
  const float* be1    = (const float*)d_in[4];
  const float* Kemb1  = (const float*)d_in[5];
  const float* Kpool1 = (const float*)d_in[6];
  const float* We2    = (const float*)d_in[7];
  const float* be2    = (const float*)d_in[8];
  const float* Kemb2  = (const float*)d_in[9];
  const float* Kpool2 = (const float*)d_in[10];
  const float* We3    = (const float*)d_in[11];
  const float* be3    = (const float*)d_in[12];
  const float* Wd0    = (const float*)d_in[13];
  const float* bd0    = (const float*)d_in[14];
  const float* Wd1    = (const float*)d_in[15];
  const float* bd1    = (const float*)d_in[16];
  const float* Wd2    = (const float*)d_in[17];
  const float* bd2    = (const float*)d_in[18];
  const float* Wdf    = (const float*)d_in[19];
  const float* bdf    = (const float*)d_in[20];
  (void)in_sizes; (void)n_in; (void)ws_size; (void)out_size;

  float* out = (float*)d_out;
  float* out_mean = out + (long long)8 * 2048 * 64;
  float* out_lv = out_mean + (long long)8 * 512 * 64;

  char* base = (char*)d_ws;
  size_t off = 0;
  auto alloc = [&](size_t bytes) {
    char* p = base + off;
    off += (bytes + 255) & ~(size_t)255;
    return p;
  };
  US* Y0   = (US*)alloc(8LL * 2048 * 64 * 2);
  US* h1b  = (US*)alloc(8LL * 2048 * 256 * 2);   // h1 natural [2048][256]
  US* g1   = (US*)alloc(8LL * 2048 * 256 * 2);
  // R1n [8][2048][1280] natural [s1|z1] — dead after transb+spmm1024; its
  // 41,943,040 B are overlaid with pm/ps (stage-2 softmax) + decode temps.
  US* R1n  = (US*)alloc(8LL * 2048 * 1280 * 2);
  float* pm = (float*)R1n;                         //  8 MB
  float* ps = pm + 8LL * 128 * 2048;               //  8 MB
  US* d4    = (US*)(ps + 8LL * 128 * 2048);        //  8 MB [8][2048][256]
  US* t5T   = d4 + 8LL * 2048 * 256;               //  4 MB
  US* d2    = t5T + 8LL * 256 * 1024;              //  4 MB
  US* t3T   = d2 + 8LL * 1024 * 256;               //  2 MB
  US* t4T   = t3T + 8LL * 256 * 512;               //  2 MB
  US* d0    = t4T + 8LL * 256 * 512;               //  2 MB
  US* t6    = d0 + 8LL * 512 * 256;                //  2 MB  (sum = 41,943,040)
  US* R1   = (US*)alloc(8LL * 2304 * 2048 * 2);  // rows [s1T|z1T|AS1T]
  US* AS1  = (US*)alloc(8LL * 2048 * 1024 * 2);
  US* P1o  = (US*)alloc(8LL * 1024 * 1280 * 2);
  US* t1T  = (US*)alloc(8LL * 256 * 1024 * 2);
  US* h2T  = (US*)alloc(8LL * 256 * 1024 * 2);
  US* g2   = (US*)alloc(8LL * 1024 * 256 * 2);
  US* R2   = (US*)alloc(8LL * 1280 * 1024 * 2);
  US* AS2  = (US*)alloc(8LL * 1024 * 512 * 2);
  US* P2o  = (US*)alloc(8LL * 512 * 768 * 2);
  US* t2T  = (US*)alloc(8LL * 128 * 512 * 2);
  float* h3f = (float*)alloc(8LL * 512 * 128 * 4);
  US* zlb  = (US*)alloc(8LL * 512 * 64 * 2);
  float* Mf   = (float*)alloc(8LL * 2048 * 4);
  float* Sinv = (float*)alloc(8LL * 2048 * 4);
  int* rowcnt = (int*)alloc(2048 * 4);
  int* rowptr = (int*)alloc(2049 * 4);
  int* colidx = (int*)alloc(2048LL * 256 * 4);
  float* vals = (float*)alloc(2048LL * 256 * 4);
  int* coloff = (int*)alloc(2048LL * 256 * 4);
  US* We1T  = (US*)alloc(256 * 64 * 2);
  US* KpKe1 = (US*)alloc(1280 * 256 * 2);
  US* We2T  = (US*)alloc(256 * 256 * 2);
  US* KpKe2 = (US*)alloc(768 * 256 * 2);
  US* We3T  = (US*)alloc(128 * 256 * 2);
  US* Wd0T  = (US*)alloc(256 * 64 * 2);
  US* Wd1T  = (US*)alloc(256 * 256 * 2);
  US* Wd2T  = (US*)alloc(256 * 256 * 2);
  US* WdfT  = (US*)alloc(64 * 256 * 2);

  // ---- weight conversions + CSR build ----
  {
    WTab tab;
    int toff = 0, i = 0;
    auto add = [&](const float* s, US* d, int R, int C) {
      tab.e[i++] = WT{s, d, R, C, toff};
      toff += (R / 64) * (C / 64);
    };
    add(We1, We1T, 64, 256);
    add(Kpool1, KpKe1, 256, 1024);
    add(Kemb1, KpKe1 + 1024 * 256, 256, 256);
    add(We2, We2T, 256, 256);
    add(Kpool2, KpKe2, 256, 512);
    add(Kemb2, KpKe2 + 512 * 256, 256, 256);
    add(We3, We3T, 256, 128);
    add(Wd0, Wd0T, 64, 256);
    add(Wd1, Wd1T, 256, 256);
    add(Wd2, Wd2T, 256, 256);
    add(Wdf, WdfT, 256, 64);
    wtrans_k<<<dim3(toff), dim3(256), 0, stream>>>(tab);
  }
  csr_count_k<<<dim3(2048), dim3(256), 0, stream>>>(adj, rowcnt);
  csr_scan_k<<<dim3(1), dim3(256), 0, stream>>>(rowcnt, rowptr);
  csr_fill_k<<<dim3(2048), dim3(256), 0, stream>>>(adj, rowptr, colidx, vals,
                                                   coloff);

  const long long SR1 = 2304LL * 2048, SR2 = 1280LL * 1024;
  const long long SR1n = 2048LL * 1280;
  US* s1T  = R1;
  US* B1   = R1 + 1024 * 2048;           // rows [z1T(256) | AS1T(1024)]
  US* AS1T = R1 + 1280 * 2048;
  US* s2T  = R2;
  US* B2   = R2 + 512 * 1024;
  US* AS2T = R2 + 768 * 1024;
  US* A1c  = P1o + 256;
  US* A2c  = P2o + 256;

  // ---------------- encode ----------------
  // Y0 = adj @ x  (SpMM from f32 x)
  spmm_k<64, true, 0, false, false><<<dim3(2048), dim3(256), 0, stream>>>(
      rowptr, colidx, vals, x, nullptr, Y0);
  // h1 = relu(Y0@We1+b)
  mm(stream, Y0, We1T, be1, h1b, nullptr, 2048, 256, 64, 64, 2048LL * 64, 0,
     2048LL * 256, 0, 1, 0, 128);
  // g1 = adj @ h1  (SpMM)
  spmm_k<256, false, 0, false, false><<<dim3(2048), dim3(256), 0, stream>>>(
      rowptr, colidx, vals, h1b, nullptr, g1);
  // R1n = g1 @ [Kp1|Ke1]  (128^2 engine, grid 1280 — full occupancy at K=256)
  mm(stream, g1, KpKe1, nullptr, R1n, nullptr, 2048, 1280, 256, 256,
     2048LL * 256, 0, SR1n, 0, 0, 0, 128);
  // row softmax over s1 logits (cols 0..1024)
  rowsm_k<<<dim3(16384), dim3(256), 0, stream>>>(R1n, 1280, SR1n);
  // R1 = R1n^T  ([1280][2048]: rows [s1T | z1T])
  transb_k<<<dim3(20, 32, 8), dim3(256), 0, stream>>>(R1n, R1, 2048, 1280,
                                                      SR1n, SR1);
  // AS1 = adj @ s1  (SpMM wide, 16B gathers, scalar metadata)
  spmm1024_k<<<dim3(8192), dim3(256), 0, stream>>>(rowptr, coloff, vals, R1n,
                                                   SR1n, AS1);
  // AS1T into B1 region  (R1n now dead — overlay region reusable)
  transb_k<<<dim3(16, 32, 8), dim3(256), 0, stream>>>(AS1, AS1T, 2048, 1024,
                                                      2048LL * 1024, SR1);
  // P1 = s1^T @ [z1 | AS1] -> [xp1 | A1]  (128^2 engine, grid 640 — full occ)
  mm(stream, s1T, B1, nullptr, P1o, nullptr, 1024, 1280, 2048, 2048, SR1, SR1,
     1024LL * 1280, 0, 0, 0, 128);
  mm(stream, P1o, We2T, nullptr, t1T, nullptr, 1024, 256, 256, 1280, 1024LL * 1280,
     0, 0, 256LL * 1024, 0, 1, 128);
  mm(stream, A1c, t1T, be2, h2T, nullptr, 1024, 256, 1024, 1280, 1024LL * 1280,
     256LL * 1024, 0, 256LL * 1024, 1, 1, 128);
  mm(stream, A1c, h2T, nullptr, g2, nullptr, 1024, 256, 1024, 1280, 1024LL * 1280,
     256LL * 1024, 1024LL * 256, 0, 0, 0, 128);
  mm(stream, g2, KpKe2, nullptr, R2, nullptr, 1024, 768, 256, 256, 1024LL * 256,
     0, 0, SR2, 0, 1, 128);
  sm_partial_k<4><<<dim3(64, 8), dim3(256), 0, stream>>>(s2T, pm, ps, 512, 1024, SR2, 64);
  sm_combine_k<<<dim3(8), dim3(256), 0, stream>>>(pm, ps, Mf, Sinv, 1024, 128);
  sm_norm_k<4><<<dim3(64, 8), dim3(256), 0, stream>>>(s2T, Mf, Sinv, 512, 1024, SR2, 64);
  mm(stream, A1c, s2T, nullptr, AS2, AS2T, 1024, 512, 1024, 1280, 1024LL * 1280,
     SR2, 1024LL * 512, SR2, 0, 3, 128);
  mm(stream, s2T, B2, nullptr, P2o, nullptr, 512, 768, 1024, 1024, SR2, SR2,
     512LL * 768, 0, 0, 0, 128);
  mm(stream, P2o, We3T, nullptr, t2T, nullptr, 512, 128, 256, 768, 512LL * 768,
     0, 0, 128LL * 512, 0, 1, 128);
  mm(stream, A2c, t2T, be3, h3f, nullptr, 512, 128, 512, 768, 512LL * 768,
     128LL * 512, 512LL * 128, 0, 0, 2, 128);
  reparam_k<<<dim3(8 * 512 * 64 / 256), dim3(256), 0, stream>>>(h3f, eps, out_mean,
                                                                out_lv, zlb, 8 * 512 * 64);

  // ---------------- decode ----------------
  mm(stream, zlb, Wd0T, nullptr, t3T, nullptr, 512, 256, 64, 64, 512LL * 64, 0, 0,
     256LL * 512, 0, 1, 128);
  mm(stream, A2c, t3T, bd0, d0, nullptr, 512, 256, 512, 768, 512LL * 768,
     256LL * 512, 512LL * 256, 0, 1, 0, 128);
  mm(stream, d0, Wd1T, nullptr, t4T, nullptr, 512, 256, 256, 256, 512LL * 256, 0,
     0, 256LL * 512, 0, 1, 128);
  mm(stream, AS2, t4T, bd1, d2, nullptr, 1024, 256, 512, 512, 1024LL * 512,
     256LL * 512, 1024LL * 256, 0, 1, 0, 128);
  mm(stream, d2, Wd2T, nullptr, t5T, nullptr, 1024, 256, 256, 256, 1024LL * 256, 0,
     0, 256LL * 1024, 0, 1, 128);
  mm(stream, AS1, t5T, bd2, d4, nullptr, 2048, 256, 1024, 1024, 2048LL * 1024,
     256LL * 1024, 2048LL * 256, 0, 1, 0, 128);
  mm64(stream, d4, WdfT, nullptr, t6, 2048, 64, 256, 256, 2048LL * 256, 0,
       2048LL * 64, 0, 0);
  spmm_k<64, false, 2, true, true><<<dim3(2048), dim3(256), 0, stream>>>(
      rowptr, colidx, vals, t6, bdf, out);
}